// Round 1
// baseline (416.493 us; speedup 1.0000x reference)
//
#include <hip/hip_runtime.h>

typedef float fx4 __attribute__((ext_vector_type(4)));

#define NTOK  1024
#define NHEADS 12
#define HD    64
#define DIMM  768

// ---------------------------------------------------------------------------
// Generic NT GEMM core: C[128x128] tile of A[M,K] @ B[N,K]^T, fp32.
// 256 threads, 8x8 per thread, BK=16.
// ---------------------------------------------------------------------------
__device__ __forceinline__ void gemm_nt_core(
    const float* __restrict__ A, const float* __restrict__ B, int K,
    int row0, int col0, float (&acc)[8][8],
    float (*As)[132], float (*Bs)[132], int tid)
{
  const int lr = tid >> 2, lk = tid & 3;
  const float* ap = A + (size_t)(row0 + lr) * K + lk * 4;
  const float* bp = B + (size_t)(col0 + lr) * K + lk * 4;
  const int m0 = (tid >> 4) * 8, n0 = (tid & 15) * 8;
  for (int kt = 0; kt < K; kt += 16) {
    #pragma unroll
    for (int ii = 0; ii < 2; ii++) {
      fx4 av = *(const fx4*)(ap + (size_t)(ii * 64) * K + kt);
      fx4 bv = *(const fx4*)(bp + (size_t)(ii * 64) * K + kt);
      int r = lr + ii * 64;
      As[lk*4+0][r] = av[0]; As[lk*4+1][r] = av[1];
      As[lk*4+2][r] = av[2]; As[lk*4+3][r] = av[3];
      Bs[lk*4+0][r] = bv[0]; Bs[lk*4+1][r] = bv[1];
      Bs[lk*4+2][r] = bv[2]; Bs[lk*4+3][r] = bv[3];
    }
    __syncthreads();
    #pragma unroll
    for (int kk = 0; kk < 16; kk++) {
      fx4 a0 = *(const fx4*)&As[kk][m0];
      fx4 a1 = *(const fx4*)&As[kk][m0+4];
      fx4 b0 = *(const fx4*)&Bs[kk][n0];
      fx4 b1 = *(const fx4*)&Bs[kk][n0+4];
      float ar[8] = {a0[0],a0[1],a0[2],a0[3],a1[0],a1[1],a1[2],a1[3]};
      float br[8] = {b0[0],b0[1],b0[2],b0[3],b1[0],b1[1],b1[2],b1[3]};
      #pragma unroll
      for (int i = 0; i < 8; i++)
        #pragma unroll
        for (int j = 0; j < 8; j++)
          acc[i][j] = fmaf(ar[i], br[j], acc[i][j]);
    }
    __syncthreads();
  }
}

// ---------------------------------------------------------------------------
// Kernel 1: qkv = x(2048x768) @ qkv_w(2304x768)^T + qkv_b, scattered into
// q/k/v each laid out as [B*NH][NTOK][HD].
// grid = 16 (M tiles) x 18 (N tiles) = 288 blocks of 256 threads.
// ---------------------------------------------------------------------------
__global__ __launch_bounds__(256) void k_qkv(
    const float* __restrict__ x, const float* __restrict__ w,
    const float* __restrict__ bias,
    float* __restrict__ qo, float* __restrict__ ko, float* __restrict__ vo)
{
  __shared__ float As[16][132];
  __shared__ float Bs[16][132];
  float acc[8][8] = {};
  const int tid = threadIdx.x;
  const int bm = blockIdx.x & 15, bn = blockIdx.x >> 4;
  const int row0 = bm * 128, col0 = bn * 128;
  gemm_nt_core(x, w, 768, row0, col0, acc, As, Bs, tid);
  const int m0 = (tid >> 4) * 8, n0 = (tid & 15) * 8;
  #pragma unroll
  for (int i = 0; i < 8; i++) {
    int r = row0 + m0 + i;
    int bb = r >> 10, n = r & 1023;
    #pragma unroll
    for (int jj = 0; jj < 8; jj += 4) {
      int c = col0 + n0 + jj;
      int which = c / 768;
      int rem = c - which * 768;
      int head = rem >> 6, d = rem & 63;
      float* base = (which == 0) ? qo : ((which == 1) ? ko : vo);
      fx4 ov;
      ov[0] = acc[i][jj+0] + bias[c+0];
      ov[1] = acc[i][jj+1] + bias[c+1];
      ov[2] = acc[i][jj+2] + bias[c+2];
      ov[3] = acc[i][jj+3] + bias[c+3];
      *(fx4*)(base + ((size_t)((bb * NHEADS + head) * NTOK + n)) * HD + d) = ov;
    }
  }
}

// ---------------------------------------------------------------------------
// Kernel 2: relh[pair][n][32] = sum_c q[pair][n][c] * rel_pos_h[qh+31-k][c]
//           relw[pair][n][32] = sum_c q[pair][n][c] * rel_pos_w[qw+31-k][c]
// One block per (pair, 32-query row); qh is constant per block.
// grid = 24 * 32 = 768 blocks of 256 threads.
// ---------------------------------------------------------------------------
__global__ __launch_bounds__(256) void k_rel(
    const float* __restrict__ qT, const float* __restrict__ rph,
    const float* __restrict__ rpw,
    float* __restrict__ relh, float* __restrict__ relw)
{
  __shared__ float Qs[32][68];
  __shared__ float RhS[32][68];
  __shared__ float RwS[63][68];
  const int bid = blockIdx.x;
  const int pair = bid >> 5;
  const int nt = bid & 31;          // == qh for every query in this block
  const int nbase = nt * 32;
  const float* qp = qT + (size_t)pair * NTOK * HD + (size_t)nbase * HD;
  const int tid = threadIdx.x;
  #pragma unroll
  for (int ii = 0; ii < 2; ii++) {
    int f = ii * 256 + tid;
    int r = f >> 4, k4 = f & 15;
    *(fx4*)&Qs[r][k4*4]  = *(const fx4*)(qp + (size_t)r * HD + k4 * 4);
    *(fx4*)&RhS[r][k4*4] = *(const fx4*)(rph + (size_t)(nt + r) * 64 + k4 * 4);
  }
  #pragma unroll
  for (int ii = 0; ii < 4; ii++) {
    int f = ii * 256 + tid;
    if (f < 1008) {
      int r = f >> 4, k4 = f & 15;
      *(fx4*)&RwS[r][k4*4] = *(const fx4*)(rpw + (size_t)r * 64 + k4 * 4);
    }
  }
  __syncthreads();
  const int nl = tid >> 3, rem = tid & 7;
  #pragma unroll
  for (int rep = 0; rep < 8; rep++) {
    int kidx = rep * 8 + rem;
    int hw = kidx >> 5;        // 0 = h, 1 = w  (uniform across the wave)
    int k = kidx & 31;
    const float* rrow = hw ? &RwS[nl + 31 - k][0] : &RhS[31 - k][0];
    float sum = 0.f;
    #pragma unroll
    for (int c4 = 0; c4 < 16; c4++) {
      fx4 q = *(const fx4*)&Qs[nl][c4*4];
      fx4 rv = *(const fx4*)&rrow[c4*4];
      sum = fmaf(q[0], rv[0], sum);
      sum = fmaf(q[1], rv[1], sum);
      sum = fmaf(q[2], rv[2], sum);
      sum = fmaf(q[3], rv[3], sum);
    }
    float* dst = (hw ? relw : relh) + (size_t)pair * NTOK * 32 + (size_t)(nbase + nl) * 32 + k;
    *dst = sum;
  }
}

// ---------------------------------------------------------------------------
// Kernel 3: flash attention per (pair, 64-query tile).
// scores = (q.k)*0.125 + relh[q][kh] + relw[q][kw]; online softmax; o = P.V
// grid = 24 * 16 = 384 blocks of 256 threads. LDS = 52 KB -> 3 blocks/CU.
// ---------------------------------------------------------------------------
__global__ __launch_bounds__(256) void k_attn(
    const float* __restrict__ qT, const float* __restrict__ kT,
    const float* __restrict__ vT,
    const float* __restrict__ relh, const float* __restrict__ relw,
    float* __restrict__ out1)
{
  __shared__ float QsT[64][68];   // [c][query]
  __shared__ float KVs[64][68];   // K phase: [c][key]; V phase: [key][d]
  __shared__ float PsT[64][68];   // [key][query]
  const int bid = blockIdx.x;
  const int pair = bid >> 4;
  const int q0 = (bid & 15) * 64;
  const int bb = pair / NHEADS, head = pair % NHEADS;
  const float* qp = qT + (size_t)pair * NTOK * HD;
  const float* kp = kT + (size_t)pair * NTOK * HD;
  const float* vp = vT + (size_t)pair * NTOK * HD;
  const float* rhp = relh + (size_t)pair * NTOK * 32;
  const float* rwp = relw + (size_t)pair * NTOK * 32;
  const int tid = threadIdx.x;
  const int mg = tid >> 4, ng = tid & 15;
  const int m0 = mg * 4, n0 = ng * 4;

  #pragma unroll
  for (int ii = 0; ii < 4; ii++) {
    int f = ii * 256 + tid;
    int r = f >> 4, k4 = f & 15;
    fx4 v = *(const fx4*)(qp + (size_t)(q0 + r) * HD + k4 * 4);
    QsT[k4*4+0][r] = v[0]; QsT[k4*4+1][r] = v[1];
    QsT[k4*4+2][r] = v[2]; QsT[k4*4+3][r] = v[3];
  }

  // rel_w bias is independent of the key-tile index: hoist it.
  float rwreg[4][4];
  #pragma unroll
  for (int i = 0; i < 4; i++) {
    int qi = q0 + m0 + i;
    #pragma unroll
    for (int j = 0; j < 4; j++)
      rwreg[i][j] = rwp[qi * 32 + ((n0 + j) & 31)];
  }

  float o[4][4] = {};
  float mrow[4] = {-3e38f, -3e38f, -3e38f, -3e38f};
  float lrow[4] = {};

  for (int t = 0; t < 16; t++) {
    // --- stage K tile (transposed) ---
    #pragma unroll
    for (int ii = 0; ii < 4; ii++) {
      int f = ii * 256 + tid;
      int r = f >> 4, k4 = f & 15;
      fx4 v = *(const fx4*)(kp + (size_t)(t * 64 + r) * HD + k4 * 4);
      KVs[k4*4+0][r] = v[0]; KVs[k4*4+1][r] = v[1];
      KVs[k4*4+2][r] = v[2]; KVs[k4*4+3][r] = v[3];
    }
    __syncthreads();

    // --- QK^T ---
    float sd[4][4] = {};
    #pragma unroll 8
    for (int c = 0; c < 64; c++) {
      fx4 qv = *(const fx4*)&QsT[c][m0];
      fx4 kv = *(const fx4*)&KVs[c][n0];
      #pragma unroll
      for (int i = 0; i < 4; i++)
        #pragma unroll
        for (int j = 0; j < 4; j++)
          sd[i][j] = fmaf(qv[i], kv[j], sd[i][j]);
    }

    // --- bias + online softmax ---
    const int kh = t * 2 + (n0 >> 5);
    float pm[4];
    #pragma unroll
    for (int i = 0; i < 4; i++) {
      float bh = rhp[(q0 + m0 + i) * 32 + kh];
      float mx = -3e38f;
      #pragma unroll
      for (int j = 0; j < 4; j++) {
        sd[i][j] = fmaf(sd[i][j], 0.125f, bh + rwreg[i][j]);
        mx = fmaxf(mx, sd[i][j]);
      }
      pm[i] = mx;
    }
    #pragma unroll
    for (int off = 1; off < 16; off <<= 1) {
      #pragma unroll
      for (int i = 0; i < 4; i++)
        pm[i] = fmaxf(pm[i], __shfl_xor(pm[i], off));
    }
    float al[4], ps[4];
    #pragma unroll
    for (int i = 0; i < 4; i++) {
      float mnew = fmaxf(mrow[i], pm[i]);
      al[i] = __expf(mrow[i] - mnew);
      mrow[i] = mnew;
      float sum = 0.f;
      #pragma unroll
      for (int j = 0; j < 4; j++) {
        float p = __expf(sd[i][j] - mnew);
        sd[i][j] = p;
        sum += p;
      }
      ps[i] = sum;
    }
    #pragma unroll
    for (int off = 1; off < 16; off <<= 1) {
      #pragma unroll
      for (int i = 0; i < 4; i++)
        ps[i] += __shfl_xor(ps[i], off);
    }
    #pragma unroll
    for (int i = 0; i < 4; i++) {
      lrow[i] = lrow[i] * al[i] + ps[i];
      #pragma unroll
      for (int j = 0; j < 4; j++) o[i][j] *= al[i];
    }
    // write P^T
    #pragma unroll
    for (int j = 0; j < 4; j++) {
      fx4 pv = {sd[0][j], sd[1][j], sd[2][j], sd[3][j]};
      *(fx4*)&PsT[n0 + j][m0] = pv;
    }
    __syncthreads();

    // --- stage V tile (row-major, reuses KVs) ---
    #pragma unroll
    for (int ii = 0; ii < 4; ii++) {
      int f = ii * 256 + tid;
      int r = f >> 4, k4 = f & 15;
      fx4 v = *(const fx4*)(vp + (size_t)(t * 64 + r) * HD + k4 * 4);
      *(fx4*)&KVs[r][k4 * 4] = v;
    }
    __syncthreads();

    // --- P.V ---
    #pragma unroll 8
    for (int jj = 0; jj < 64; jj++) {
      fx4 pv = *(const fx4*)&PsT[jj][m0];
      fx4 vv = *(const fx4*)&KVs[jj][n0];
      #pragma unroll
      for (int i = 0; i < 4; i++)
        #pragma unroll
        for (int j = 0; j < 4; j++)
          o[i][j] = fmaf(pv[i], vv[j], o[i][j]);
    }
    __syncthreads();
  }

  #pragma unroll
  for (int i = 0; i < 4; i++) {
    float inv = 1.0f / lrow[i];
    fx4 ov = {o[i][0]*inv, o[i][1]*inv, o[i][2]*inv, o[i][3]*inv};
    *(fx4*)(out1 + ((size_t)(bb * NTOK + q0 + m0 + i)) * DIMM + head * HD + n0) = ov;
  }
}

// ---------------------------------------------------------------------------
// Kernel 4: out = out1(2048x768) @ proj_w(768x768)^T + proj_b
// grid = 16 x 6 = 96 blocks.
// ---------------------------------------------------------------------------
__global__ __launch_bounds__(256) void k_proj(
    const float* __restrict__ a, const float* __restrict__ w,
    const float* __restrict__ bias, float* __restrict__ out)
{
  __shared__ float As[16][132];
  __shared__ float Bs[16][132];
  float acc[8][8] = {};
  const int tid = threadIdx.x;
  const int bm = blockIdx.x & 15, bn = blockIdx.x >> 4;
  const int row0 = bm * 128, col0 = bn * 128;
  gemm_nt_core(a, w, 768, row0, col0, acc, As, Bs, tid);
  const int m0 = (tid >> 4) * 8, n0 = (tid & 15) * 8;
  #pragma unroll
  for (int i = 0; i < 8; i++) {
    int r = row0 + m0 + i;
    #pragma unroll
    for (int jj = 0; jj < 8; jj += 4) {
      int c = col0 + n0 + jj;
      fx4 ov;
      ov[0] = acc[i][jj+0] + bias[c+0];
      ov[1] = acc[i][jj+1] + bias[c+1];
      ov[2] = acc[i][jj+2] + bias[c+2];
      ov[3] = acc[i][jj+3] + bias[c+3];
      *(fx4*)(out + (size_t)r * 768 + c) = ov;
    }
  }
}

// ---------------------------------------------------------------------------
extern "C" void kernel_launch(void* const* d_in, const int* in_sizes, int n_in,
                              void* d_out, int out_size, void* d_ws, size_t ws_size,
                              hipStream_t stream)
{
  const float* x      = (const float*)d_in[0];
  const float* qkv_w  = (const float*)d_in[1];
  const float* qkv_b  = (const float*)d_in[2];
  const float* proj_w = (const float*)d_in[3];
  const float* proj_b = (const float*)d_in[4];
  const float* rph    = (const float*)d_in[5];
  const float* rpw    = (const float*)d_in[6];
  // d_in[7], d_in[8]: x_h, x_w == 32 (fixed by setup)

  float* ws   = (float*)d_ws;
  float* q    = ws;                    // 24*1024*64 = 1572864
  float* k    = q    + 1572864;
  float* v    = k    + 1572864;
  float* relh = v    + 1572864;        // 24*1024*32 = 786432
  float* relw = relh + 786432;
  float* out1 = relw + 786432;         // 2*1024*768 = 1572864
  float* out  = (float*)d_out;

  k_qkv<<<dim3(288), dim3(256), 0, stream>>>(x, qkv_w, qkv_b, q, k, v);
  k_rel<<<dim3(768), dim3(256), 0, stream>>>(q, rph, rpw, relh, relw);
  k_attn<<<dim3(384), dim3(256), 0, stream>>>(q, k, v, relh, relw, out1);
  k_proj<<<dim3(96), dim3(256), 0, stream>>>(out1, proj_w, proj_b, out);
}

// Round 2
// 247.076 us; speedup vs baseline: 1.6857x; 1.6857x over previous
//
#include <hip/hip_runtime.h>

typedef float fx4 __attribute__((ext_vector_type(4)));
typedef short bfrag __attribute__((ext_vector_type(8)));
typedef float ffrag __attribute__((ext_vector_type(4)));

#define NTOK  1024
#define NHEADS 12
#define HD    64
#define DIMM  768

// ---------------- bf16 helpers (bit-level, RNE) ----------------
__device__ __forceinline__ float b2f(unsigned short u) {
  union { unsigned i; float f; } x; x.i = ((unsigned)u) << 16; return x.f;
}
__device__ __forceinline__ unsigned short f2b(float f) {
  union { float f; unsigned i; } x; x.f = f;
  unsigned r = x.i + 0x7fff + ((x.i >> 16) & 1);
  return (unsigned short)(r >> 16);
}

__device__ __forceinline__ void gload16(const void* g, void* l) {
  __builtin_amdgcn_global_load_lds(
      (const __attribute__((address_space(1))) unsigned*)g,
      (__attribute__((address_space(3))) unsigned*)l, 16, 0, 0);
}

__device__ __forceinline__ ffrag mfma16(bfrag a, bfrag b, ffrag c) {
  return __builtin_amdgcn_mfma_f32_16x16x32_bf16(a, b, c, 0, 0, 0);
}

// ---------------------------------------------------------------------------
// k_cvt: split fp32 -> (hi, lo) bf16 pair. n4 = elements/4.
// ---------------------------------------------------------------------------
__global__ __launch_bounds__(256) void k_cvt(
    const float* __restrict__ src, unsigned short* __restrict__ h,
    unsigned short* __restrict__ l, int n4)
{
  int i = blockIdx.x * 256 + threadIdx.x;
  if (i >= n4) return;
  fx4 v = *(const fx4*)(src + (size_t)i * 4);
  ushort4 hh, ll;
  float t;
  hh.x = f2b(v[0]); t = v[0] - b2f(hh.x); ll.x = f2b(t);
  hh.y = f2b(v[1]); t = v[1] - b2f(hh.y); ll.y = f2b(t);
  hh.z = f2b(v[2]); t = v[2] - b2f(hh.z); ll.z = f2b(t);
  hh.w = f2b(v[3]); t = v[3] - b2f(hh.w); ll.w = f2b(t);
  *(ushort4*)(h + (size_t)i * 4) = hh;
  *(ushort4*)(l + (size_t)i * 4) = ll;
}

// ---------------------------------------------------------------------------
// Shared MFMA NT-GEMM core: C[64x64] = A[M,K] @ B[N,K]^T with bf16x3 split.
// 256 threads = 4 waves in 2x2; each wave owns a 32x32 quadrant (2x2 frags).
// LDS: 16 fragments x 1KB, fragment-linear (ds_read at lane*16, conflict-free).
// ---------------------------------------------------------------------------
__device__ __forceinline__ void mfma_nt_64x64(
    const unsigned short* __restrict__ Ah, const unsigned short* __restrict__ Al,
    const unsigned short* __restrict__ Bh, const unsigned short* __restrict__ Bl,
    int row0, int col0, int K, short* lds, ffrag (&acc)[2][2])
{
  const int tid = threadIdx.x;
  const int lane = tid & 63, w = tid >> 6;
  const int wr = w >> 1, wc = w & 1;
  const int lrow = lane & 15, lk8 = (lane >> 4) * 8;
  // wave w stages A-frag w (rows row0+w*16..+15) and B-frag w.
  const unsigned short* sA_h = Ah + (size_t)(row0 + w * 16 + lrow) * K + lk8;
  const unsigned short* sA_l = Al + (size_t)(row0 + w * 16 + lrow) * K + lk8;
  const unsigned short* sB_h = Bh + (size_t)(col0 + w * 16 + lrow) * K + lk8;
  const unsigned short* sB_l = Bl + (size_t)(col0 + w * 16 + lrow) * K + lk8;
  short* dA_h = lds + (0 * 4 + w) * 512;
  short* dA_l = lds + (1 * 4 + w) * 512;
  short* dB_h = lds + (2 * 4 + w) * 512;
  short* dB_l = lds + (3 * 4 + w) * 512;
  for (int k0 = 0; k0 < K; k0 += 32) {
    gload16(sA_h + k0, dA_h);
    gload16(sA_l + k0, dA_l);
    gload16(sB_h + k0, dB_h);
    gload16(sB_l + k0, dB_l);
    __syncthreads();
    bfrag ah[2], al[2], bh[2], bl[2];
    #pragma unroll
    for (int i = 0; i < 2; i++) {
      ah[i] = *(const bfrag*)(lds + (0 * 4 + wr * 2 + i) * 512 + lane * 8);
      al[i] = *(const bfrag*)(lds + (1 * 4 + wr * 2 + i) * 512 + lane * 8);
      bh[i] = *(const bfrag*)(lds + (2 * 4 + wc * 2 + i) * 512 + lane * 8);
      bl[i] = *(const bfrag*)(lds + (3 * 4 + wc * 2 + i) * 512 + lane * 8);
    }
    #pragma unroll
    for (int mi = 0; mi < 2; mi++)
      #pragma unroll
      for (int ni = 0; ni < 2; ni++) {
        acc[mi][ni] = mfma16(ah[mi], bh[ni], acc[mi][ni]);
        acc[mi][ni] = mfma16(ah[mi], bl[ni], acc[mi][ni]);
        acc[mi][ni] = mfma16(al[mi], bh[ni], acc[mi][ni]);
      }
    __syncthreads();
  }
}

// ---------------------------------------------------------------------------
// Kernel: qkv GEMM (M=2048, N=2304, K=768), scatter to q/k/v bf16 buffers
// laid out [B*NH][NTOK][HD]. grid = 32 x 36 = 1152 blocks.
// ---------------------------------------------------------------------------
__global__ __launch_bounds__(256) void k_qkv_mfma(
    const unsigned short* __restrict__ xh, const unsigned short* __restrict__ xl,
    const unsigned short* __restrict__ wh, const unsigned short* __restrict__ wl,
    const float* __restrict__ bias,
    unsigned short* __restrict__ qo, unsigned short* __restrict__ ko,
    unsigned short* __restrict__ vo)
{
  __shared__ short lds[16 * 512];
  const int bm = blockIdx.x & 31, bn = blockIdx.x >> 5;
  const int row0 = bm * 64, col0 = bn * 64;
  ffrag acc[2][2] = {};
  mfma_nt_64x64(xh, xl, wh, wl, row0, col0, 768, lds, acc);

  const int tid = threadIdx.x;
  const int lane = tid & 63, w = tid >> 6;
  const int wr = w >> 1, wc = w & 1;
  const int lrow = lane & 15;
  const int which = col0 / 768;                 // uniform per block
  const int head  = (col0 % 768) >> 6;          // uniform per block
  unsigned short* base = which == 0 ? qo : (which == 1 ? ko : vo);
  #pragma unroll
  for (int mi = 0; mi < 2; mi++)
    #pragma unroll
    for (int ni = 0; ni < 2; ni++) {
      int d = wc * 32 + ni * 16 + lrow;          // 0..63 within head
      float bv = bias[col0 + d];
      #pragma unroll
      for (int r = 0; r < 4; r++) {
        int row = row0 + wr * 32 + mi * 16 + (lane >> 4) * 4 + r;
        int bb = row >> 10, n = row & 1023;
        float val = acc[mi][ni][r] + bv;
        base[((size_t)(bb * NHEADS + head) * NTOK + n) * HD + d] = f2b(val);
      }
    }
}

// ---------------------------------------------------------------------------
// Kernel: proj GEMM (M=2048, N=768, K=768) from bf16 h/l attention output.
// grid = 32 x 12 = 384 blocks. Output fp32 with bias.
// ---------------------------------------------------------------------------
__global__ __launch_bounds__(256) void k_proj_mfma(
    const unsigned short* __restrict__ ah, const unsigned short* __restrict__ al,
    const unsigned short* __restrict__ bh, const unsigned short* __restrict__ bl,
    const float* __restrict__ bias, float* __restrict__ out)
{
  __shared__ short lds[16 * 512];
  const int bm = blockIdx.x & 31, bn = blockIdx.x >> 5;
  const int row0 = bm * 64, col0 = bn * 64;
  ffrag acc[2][2] = {};
  mfma_nt_64x64(ah, al, bh, bl, row0, col0, 768, lds, acc);

  const int tid = threadIdx.x;
  const int lane = tid & 63, w = tid >> 6;
  const int wr = w >> 1, wc = w & 1;
  const int lrow = lane & 15;
  #pragma unroll
  for (int mi = 0; mi < 2; mi++)
    #pragma unroll
    for (int ni = 0; ni < 2; ni++) {
      int col = col0 + wc * 32 + ni * 16 + lrow;
      float bv = bias[col];
      #pragma unroll
      for (int r = 0; r < 4; r++) {
        int row = row0 + wr * 32 + mi * 16 + (lane >> 4) * 4 + r;
        out[(size_t)row * 768 + col] = acc[mi][ni][r] + bv;
      }
    }
}

// ---------------------------------------------------------------------------
// Kernel: rel-pos bias precompute (q now bf16).
// ---------------------------------------------------------------------------
__global__ __launch_bounds__(256) void k_rel(
    const unsigned short* __restrict__ qT, const float* __restrict__ rph,
    const float* __restrict__ rpw,
    float* __restrict__ relh, float* __restrict__ relw)
{
  __shared__ float Qs[32][68];
  __shared__ float RhS[32][68];
  __shared__ float RwS[63][68];
  const int bid = blockIdx.x;
  const int pair = bid >> 5;
  const int nt = bid & 31;          // == qh for every query in this block
  const int nbase = nt * 32;
  const unsigned short* qp = qT + (size_t)pair * NTOK * HD + (size_t)nbase * HD;
  const int tid = threadIdx.x;
  #pragma unroll
  for (int ii = 0; ii < 2; ii++) {
    int f = ii * 256 + tid;
    int r = f >> 4, k4 = f & 15;
    ushort4 t = *(const ushort4*)(qp + (size_t)r * HD + k4 * 4);
    Qs[r][k4*4+0] = b2f(t.x); Qs[r][k4*4+1] = b2f(t.y);
    Qs[r][k4*4+2] = b2f(t.z); Qs[r][k4*4+3] = b2f(t.w);
    *(fx4*)&RhS[r][k4*4] = *(const fx4*)(rph + (size_t)(nt + r) * 64 + k4 * 4);
  }
  #pragma unroll
  for (int ii = 0; ii < 4; ii++) {
    int f = ii * 256 + tid;
    if (f < 1008) {
      int r = f >> 4, k4 = f & 15;
      *(fx4*)&RwS[r][k4*4] = *(const fx4*)(rpw + (size_t)r * 64 + k4 * 4);
    }
  }
  __syncthreads();
  const int nl = tid >> 3, rem = tid & 7;
  #pragma unroll
  for (int rep = 0; rep < 8; rep++) {
    int kidx = rep * 8 + rem;
    int hw = kidx >> 5;        // 0 = h, 1 = w  (uniform across the wave)
    int k = kidx & 31;
    const float* rrow = hw ? &RwS[nl + 31 - k][0] : &RhS[31 - k][0];
    float sum = 0.f;
    #pragma unroll
    for (int c4 = 0; c4 < 16; c4++) {
      fx4 q = *(const fx4*)&Qs[nl][c4*4];
      fx4 rv = *(const fx4*)&rrow[c4*4];
      sum = fmaf(q[0], rv[0], sum);
      sum = fmaf(q[1], rv[1], sum);
      sum = fmaf(q[2], rv[2], sum);
      sum = fmaf(q[3], rv[3], sum);
    }
    float* dst = (hw ? relw : relh) + (size_t)pair * NTOK * 32 + (size_t)(nbase + nl) * 32 + k;
    *dst = sum;
  }
}

// ---------------------------------------------------------------------------
// Kernel: flash attention per (pair, 64-query tile), fp32 compute on bf16
// q/k/v. Epilogue writes bf16 hi/lo pair for the proj MFMA.
// grid = 24 * 16 = 384 blocks of 256 threads.
// ---------------------------------------------------------------------------
__global__ __launch_bounds__(256) void k_attn(
    const unsigned short* __restrict__ qT, const unsigned short* __restrict__ kT,
    const unsigned short* __restrict__ vT,
    const float* __restrict__ relh, const float* __restrict__ relw,
    unsigned short* __restrict__ o1h, unsigned short* __restrict__ o1l)
{
  __shared__ float QsT[64][68];   // [c][query]
  __shared__ float KVs[64][68];   // K phase: [c][key]; V phase: [key][d]
  __shared__ float PsT[64][68];   // [key][query]
  const int bid = blockIdx.x;
  const int pair = bid >> 4;
  const int q0 = (bid & 15) * 64;
  const int bb = pair / NHEADS, head = pair % NHEADS;
  const unsigned short* qp = qT + (size_t)pair * NTOK * HD;
  const unsigned short* kp = kT + (size_t)pair * NTOK * HD;
  const unsigned short* vp = vT + (size_t)pair * NTOK * HD;
  const float* rhp = relh + (size_t)pair * NTOK * 32;
  const float* rwp = relw + (size_t)pair * NTOK * 32;
  const int tid = threadIdx.x;
  const int mg = tid >> 4, ng = tid & 15;
  const int m0 = mg * 4, n0 = ng * 4;

  #pragma unroll
  for (int ii = 0; ii < 4; ii++) {
    int f = ii * 256 + tid;
    int r = f >> 4, k4 = f & 15;
    ushort4 t = *(const ushort4*)(qp + (size_t)(q0 + r) * HD + k4 * 4);
    QsT[k4*4+0][r] = b2f(t.x); QsT[k4*4+1][r] = b2f(t.y);
    QsT[k4*4+2][r] = b2f(t.z); QsT[k4*4+3][r] = b2f(t.w);
  }

  // rel_w bias is independent of the key-tile index: hoist it.
  float rwreg[4][4];
  #pragma unroll
  for (int i = 0; i < 4; i++) {
    int qi = q0 + m0 + i;
    #pragma unroll
    for (int j = 0; j < 4; j++)
      rwreg[i][j] = rwp[qi * 32 + ((n0 + j) & 31)];
  }

  float o[4][4] = {};
  float mrow[4] = {-3e38f, -3e38f, -3e38f, -3e38f};
  float lrow[4] = {};

  for (int t = 0; t < 16; t++) {
    // --- stage K tile (transposed) ---
    #pragma unroll
    for (int ii = 0; ii < 4; ii++) {
      int f = ii * 256 + tid;
      int r = f >> 4, k4 = f & 15;
      ushort4 tt = *(const ushort4*)(kp + (size_t)(t * 64 + r) * HD + k4 * 4);
      KVs[k4*4+0][r] = b2f(tt.x); KVs[k4*4+1][r] = b2f(tt.y);
      KVs[k4*4+2][r] = b2f(tt.z); KVs[k4*4+3][r] = b2f(tt.w);
    }
    __syncthreads();

    // --- QK^T ---
    float sd[4][4] = {};
    #pragma unroll 8
    for (int c = 0; c < 64; c++) {
      fx4 qv = *(const fx4*)&QsT[c][m0];
      fx4 kv = *(const fx4*)&KVs[c][n0];
      #pragma unroll
      for (int i = 0; i < 4; i++)
        #pragma unroll
        for (int j = 0; j < 4; j++)
          sd[i][j] = fmaf(qv[i], kv[j], sd[i][j]);
    }

    // --- bias + online softmax ---
    const int kh = t * 2 + (n0 >> 5);
    float pm[4];
    #pragma unroll
    for (int i = 0; i < 4; i++) {
      float bh = rhp[(q0 + m0 + i) * 32 + kh];
      float mx = -3e38f;
      #pragma unroll
      for (int j = 0; j < 4; j++) {
        sd[i][j] = fmaf(sd[i][j], 0.125f, bh + rwreg[i][j]);
        mx = fmaxf(mx, sd[i][j]);
      }
      pm[i] = mx;
    }
    #pragma unroll
    for (int off = 1; off < 16; off <<= 1) {
      #pragma unroll
      for (int i = 0; i < 4; i++)
        pm[i] = fmaxf(pm[i], __shfl_xor(pm[i], off));
    }
    float al[4], ps[4];
    #pragma unroll
    for (int i = 0; i < 4; i++) {
      float mnew = fmaxf(mrow[i], pm[i]);
      al[i] = __expf(mrow[i] - mnew);
      mrow[i] = mnew;
      float sum = 0.f;
      #pragma unroll
      for (int j = 0; j < 4; j++) {
        float p = __expf(sd[i][j] - mnew);
        sd[i][j] = p;
        sum += p;
      }
      ps[i] = sum;
    }
    #pragma unroll
    for (int off = 1; off < 16; off <<= 1) {
      #pragma unroll
      for (int i = 0; i < 4; i++)
        ps[i] += __shfl_xor(ps[i], off);
    }
    #pragma unroll
    for (int i = 0; i < 4; i++) {
      lrow[i] = lrow[i] * al[i] + ps[i];
      #pragma unroll
      for (int j = 0; j < 4; j++) o[i][j] *= al[i];
    }
    // write P^T
    #pragma unroll
    for (int j = 0; j < 4; j++) {
      fx4 pv = {sd[0][j], sd[1][j], sd[2][j], sd[3][j]};
      *(fx4*)&PsT[n0 + j][m0] = pv;
    }
    __syncthreads();

    // --- stage V tile (row-major, reuses KVs) ---
    #pragma unroll
    for (int ii = 0; ii < 4; ii++) {
      int f = ii * 256 + tid;
      int r = f >> 4, k4 = f & 15;
      ushort4 tt = *(const ushort4*)(vp + (size_t)(t * 64 + r) * HD + k4 * 4);
      fx4 vv = {b2f(tt.x), b2f(tt.y), b2f(tt.z), b2f(tt.w)};
      *(fx4*)&KVs[r][k4 * 4] = vv;
    }
    __syncthreads();

    // --- P.V ---
    #pragma unroll 8
    for (int jj = 0; jj < 64; jj++) {
      fx4 pv = *(const fx4*)&PsT[jj][m0];
      fx4 vv = *(const fx4*)&KVs[jj][n0];
      #pragma unroll
      for (int i = 0; i < 4; i++)
        #pragma unroll
        for (int j = 0; j < 4; j++)
          o[i][j] = fmaf(pv[i], vv[j], o[i][j]);
    }
    __syncthreads();
  }

  #pragma unroll
  for (int i = 0; i < 4; i++) {
    float inv = 1.0f / lrow[i];
    ushort4 uh, ul;
    float v0 = o[i][0]*inv, v1 = o[i][1]*inv, v2 = o[i][2]*inv, v3 = o[i][3]*inv;
    uh.x = f2b(v0); ul.x = f2b(v0 - b2f(uh.x));
    uh.y = f2b(v1); ul.y = f2b(v1 - b2f(uh.y));
    uh.z = f2b(v2); ul.z = f2b(v2 - b2f(uh.z));
    uh.w = f2b(v3); ul.w = f2b(v3 - b2f(uh.w));
    size_t idx = ((size_t)(bb * NTOK + q0 + m0 + i)) * DIMM + head * HD + n0;
    *(ushort4*)(o1h + idx) = uh;
    *(ushort4*)(o1l + idx) = ul;
  }
}

// ---------------------------------------------------------------------------
extern "C" void kernel_launch(void* const* d_in, const int* in_sizes, int n_in,
                              void* d_out, int out_size, void* d_ws, size_t ws_size,
                              hipStream_t stream)
{
  const float* x      = (const float*)d_in[0];
  const float* qkv_w  = (const float*)d_in[1];
  const float* qkv_b  = (const float*)d_in[2];
  const float* proj_w = (const float*)d_in[3];
  const float* proj_b = (const float*)d_in[4];
  const float* rph    = (const float*)d_in[5];
  const float* rpw    = (const float*)d_in[6];

  char* p = (char*)d_ws;
  unsigned short* xh  = (unsigned short*)p; p += 3145728;   // 2048*768*2
  unsigned short* xl  = (unsigned short*)p; p += 3145728;
  unsigned short* wh  = (unsigned short*)p; p += 3538944;   // 2304*768*2
  unsigned short* wl  = (unsigned short*)p; p += 3538944;
  unsigned short* pwh = (unsigned short*)p; p += 1179648;   // 768*768*2
  unsigned short* pwl = (unsigned short*)p; p += 1179648;
  unsigned short* qb  = (unsigned short*)p; p += 3145728;   // 24*1024*64*2
  unsigned short* kb  = (unsigned short*)p; p += 3145728;
  unsigned short* vb  = (unsigned short*)p; p += 3145728;
  float* relh = (float*)p; p += 3145728;                    // 24*1024*32*4
  float* relw = (float*)p; p += 3145728;
  // xh/xl are dead after k_qkv_mfma -> reuse for attention output hi/lo.
  unsigned short* o1h = xh;
  unsigned short* o1l = xl;
  float* out = (float*)d_out;

  k_cvt<<<dim3(1536), dim3(256), 0, stream>>>(x,      xh,  xl,  393216);
  k_cvt<<<dim3(1728), dim3(256), 0, stream>>>(qkv_w,  wh,  wl,  442368);
  k_cvt<<<dim3(576),  dim3(256), 0, stream>>>(proj_w, pwh, pwl, 147456);
  k_qkv_mfma<<<dim3(1152), dim3(256), 0, stream>>>(xh, xl, wh, wl, qkv_b, qb, kb, vb);
  k_rel<<<dim3(768), dim3(256), 0, stream>>>(qb, rph, rpw, relh, relw);
  k_attn<<<dim3(384), dim3(256), 0, stream>>>(qb, kb, vb, relh, relw, o1h, o1l);
  k_proj_mfma<<<dim3(384), dim3(256), 0, stream>>>(o1h, o1l, pwh, pwl, proj_b, out);
}

// Round 3
// 161.068 us; speedup vs baseline: 2.5858x; 1.5340x over previous
//
#include <hip/hip_runtime.h>

typedef float fx4 __attribute__((ext_vector_type(4)));
typedef float fx2 __attribute__((ext_vector_type(2)));
typedef short bfrag __attribute__((ext_vector_type(8)));
typedef float ffrag __attribute__((ext_vector_type(4)));

#define NTOK  1024
#define NHEADS 12
#define HD    64
#define DIMM  768

// ---------------- bf16 helpers (bit-level, RNE) ----------------
__device__ __forceinline__ float b2f(unsigned short u) {
  union { unsigned i; float f; } x; x.i = ((unsigned)u) << 16; return x.f;
}
__device__ __forceinline__ unsigned short f2b(float f) {
  union { float f; unsigned i; } x; x.f = f;
  unsigned r = x.i + 0x7fff + ((x.i >> 16) & 1);
  return (unsigned short)(r >> 16);
}

__device__ __forceinline__ void gload16(const void* g, void* l) {
  __builtin_amdgcn_global_load_lds(
      (const __attribute__((address_space(1))) unsigned*)g,
      (__attribute__((address_space(3))) unsigned*)l, 16, 0, 0);
}

__device__ __forceinline__ ffrag mfma16(bfrag a, bfrag b, ffrag c) {
  return __builtin_amdgcn_mfma_f32_16x16x32_bf16(a, b, c, 0, 0, 0);
}

// XOR-swizzled byte address within a [rows][128B] LDS tile (G4 fix).
__device__ __forceinline__ int swz(int row, int b) {
  return row * 128 + (b ^ ((row & 7) << 4));
}

// ---------------------------------------------------------------------------
// k_cvt: split fp32 -> (hi, lo) bf16 pair. n4 = elements/4.
// ---------------------------------------------------------------------------
__global__ __launch_bounds__(256) void k_cvt(
    const float* __restrict__ src, unsigned short* __restrict__ h,
    unsigned short* __restrict__ l, int n4)
{
  int i = blockIdx.x * 256 + threadIdx.x;
  if (i >= n4) return;
  fx4 v = *(const fx4*)(src + (size_t)i * 4);
  ushort4 hh, ll;
  float t;
  hh.x = f2b(v[0]); t = v[0] - b2f(hh.x); ll.x = f2b(t);
  hh.y = f2b(v[1]); t = v[1] - b2f(hh.y); ll.y = f2b(t);
  hh.z = f2b(v[2]); t = v[2] - b2f(hh.z); ll.z = f2b(t);
  hh.w = f2b(v[3]); t = v[3] - b2f(hh.w); ll.w = f2b(t);
  *(ushort4*)(h + (size_t)i * 4) = hh;
  *(ushort4*)(l + (size_t)i * 4) = ll;
}

// ---------------------------------------------------------------------------
// Shared MFMA NT-GEMM core: C[64x64] = A[M,K] @ B[N,K]^T with bf16x3 split.
// ---------------------------------------------------------------------------
__device__ __forceinline__ void mfma_nt_64x64(
    const unsigned short* __restrict__ Ah, const unsigned short* __restrict__ Al,
    const unsigned short* __restrict__ Bh, const unsigned short* __restrict__ Bl,
    int row0, int col0, int K, short* lds, ffrag (&acc)[2][2])
{
  const int tid = threadIdx.x;
  const int lane = tid & 63, w = tid >> 6;
  const int wr = w >> 1, wc = w & 1;
  const int lrow = lane & 15, lk8 = (lane >> 4) * 8;
  const unsigned short* sA_h = Ah + (size_t)(row0 + w * 16 + lrow) * K + lk8;
  const unsigned short* sA_l = Al + (size_t)(row0 + w * 16 + lrow) * K + lk8;
  const unsigned short* sB_h = Bh + (size_t)(col0 + w * 16 + lrow) * K + lk8;
  const unsigned short* sB_l = Bl + (size_t)(col0 + w * 16 + lrow) * K + lk8;
  short* dA_h = lds + (0 * 4 + w) * 512;
  short* dA_l = lds + (1 * 4 + w) * 512;
  short* dB_h = lds + (2 * 4 + w) * 512;
  short* dB_l = lds + (3 * 4 + w) * 512;
  for (int k0 = 0; k0 < K; k0 += 32) {
    gload16(sA_h + k0, dA_h);
    gload16(sA_l + k0, dA_l);
    gload16(sB_h + k0, dB_h);
    gload16(sB_l + k0, dB_l);
    __syncthreads();
    bfrag ah[2], al[2], bh[2], bl[2];
    #pragma unroll
    for (int i = 0; i < 2; i++) {
      ah[i] = *(const bfrag*)(lds + (0 * 4 + wr * 2 + i) * 512 + lane * 8);
      al[i] = *(const bfrag*)(lds + (1 * 4 + wr * 2 + i) * 512 + lane * 8);
      bh[i] = *(const bfrag*)(lds + (2 * 4 + wc * 2 + i) * 512 + lane * 8);
      bl[i] = *(const bfrag*)(lds + (3 * 4 + wc * 2 + i) * 512 + lane * 8);
    }
    #pragma unroll
    for (int mi = 0; mi < 2; mi++)
      #pragma unroll
      for (int ni = 0; ni < 2; ni++) {
        acc[mi][ni] = mfma16(ah[mi], bh[ni], acc[mi][ni]);
        acc[mi][ni] = mfma16(ah[mi], bl[ni], acc[mi][ni]);
        acc[mi][ni] = mfma16(al[mi], bh[ni], acc[mi][ni]);
      }
    __syncthreads();
  }
}

// ---------------------------------------------------------------------------
__global__ __launch_bounds__(256) void k_qkv_mfma(
    const unsigned short* __restrict__ xh, const unsigned short* __restrict__ xl,
    const unsigned short* __restrict__ wh, const unsigned short* __restrict__ wl,
    const float* __restrict__ bias,
    unsigned short* __restrict__ qo, unsigned short* __restrict__ ko,
    unsigned short* __restrict__ vo)
{
  __shared__ short lds[16 * 512];
  const int bm = blockIdx.x & 31, bn = blockIdx.x >> 5;
  const int row0 = bm * 64, col0 = bn * 64;
  ffrag acc[2][2] = {};
  mfma_nt_64x64(xh, xl, wh, wl, row0, col0, 768, lds, acc);

  const int tid = threadIdx.x;
  const int lane = tid & 63, w = tid >> 6;
  const int wr = w >> 1, wc = w & 1;
  const int lrow = lane & 15;
  const int which = col0 / 768;
  const int head  = (col0 % 768) >> 6;
  unsigned short* base = which == 0 ? qo : (which == 1 ? ko : vo);
  #pragma unroll
  for (int mi = 0; mi < 2; mi++)
    #pragma unroll
    for (int ni = 0; ni < 2; ni++) {
      int d = wc * 32 + ni * 16 + lrow;
      float bv = bias[col0 + d];
      #pragma unroll
      for (int r = 0; r < 4; r++) {
        int row = row0 + wr * 32 + mi * 16 + (lane >> 4) * 4 + r;
        int bb = row >> 10, n = row & 1023;
        float val = acc[mi][ni][r] + bv;
        base[((size_t)(bb * NHEADS + head) * NTOK + n) * HD + d] = f2b(val);
      }
    }
}

// ---------------------------------------------------------------------------
__global__ __launch_bounds__(256) void k_proj_mfma(
    const unsigned short* __restrict__ ah, const unsigned short* __restrict__ al,
    const unsigned short* __restrict__ bh, const unsigned short* __restrict__ bl,
    const float* __restrict__ bias, float* __restrict__ out)
{
  __shared__ short lds[16 * 512];
  const int bm = blockIdx.x & 31, bn = blockIdx.x >> 5;
  const int row0 = bm * 64, col0 = bn * 64;
  ffrag acc[2][2] = {};
  mfma_nt_64x64(ah, al, bh, bl, row0, col0, 768, lds, acc);

  const int tid = threadIdx.x;
  const int lane = tid & 63, w = tid >> 6;
  const int wr = w >> 1, wc = w & 1;
  const int lrow = lane & 15;
  #pragma unroll
  for (int mi = 0; mi < 2; mi++)
    #pragma unroll
    for (int ni = 0; ni < 2; ni++) {
      int col = col0 + wc * 32 + ni * 16 + lrow;
      float bv = bias[col];
      #pragma unroll
      for (int r = 0; r < 4; r++) {
        int row = row0 + wr * 32 + mi * 16 + (lane >> 4) * 4 + r;
        out[(size_t)row * 768 + col] = acc[mi][ni][r] + bv;
      }
    }
}

// ---------------------------------------------------------------------------
// Kernel: rel-pos bias precompute (q bf16).
// ---------------------------------------------------------------------------
__global__ __launch_bounds__(256) void k_rel(
    const unsigned short* __restrict__ qT, const float* __restrict__ rph,
    const float* __restrict__ rpw,
    float* __restrict__ relh, float* __restrict__ relw)
{
  __shared__ float Qs[32][68];
  __shared__ float RhS[32][68];
  __shared__ float RwS[63][68];
  const int bid = blockIdx.x;
  const int pair = bid >> 5;
  const int nt = bid & 31;
  const int nbase = nt * 32;
  const unsigned short* qp = qT + (size_t)pair * NTOK * HD + (size_t)nbase * HD;
  const int tid = threadIdx.x;
  #pragma unroll
  for (int ii = 0; ii < 2; ii++) {
    int f = ii * 256 + tid;
    int r = f >> 4, k4 = f & 15;
    ushort4 t = *(const ushort4*)(qp + (size_t)r * HD + k4 * 4);
    Qs[r][k4*4+0] = b2f(t.x); Qs[r][k4*4+1] = b2f(t.y);
    Qs[r][k4*4+2] = b2f(t.z); Qs[r][k4*4+3] = b2f(t.w);
    *(fx4*)&RhS[r][k4*4] = *(const fx4*)(rph + (size_t)(nt + r) * 64 + k4 * 4);
  }
  #pragma unroll
  for (int ii = 0; ii < 4; ii++) {
    int f = ii * 256 + tid;
    if (f < 1008) {
      int r = f >> 4, k4 = f & 15;
      *(fx4*)&RwS[r][k4*4] = *(const fx4*)(rpw + (size_t)r * 64 + k4 * 4);
    }
  }
  __syncthreads();
  const int nl = tid >> 3, rem = tid & 7;
  #pragma unroll
  for (int rep = 0; rep < 8; rep++) {
    int kidx = rep * 8 + rem;
    int hw = kidx >> 5;
    int k = kidx & 31;
    const float* rrow = hw ? &RwS[nl + 31 - k][0] : &RhS[31 - k][0];
    float sum = 0.f;
    #pragma unroll
    for (int c4 = 0; c4 < 16; c4++) {
      fx4 q = *(const fx4*)&Qs[nl][c4*4];
      fx4 rv = *(const fx4*)&rrow[c4*4];
      sum = fmaf(q[0], rv[0], sum);
      sum = fmaf(q[1], rv[1], sum);
      sum = fmaf(q[2], rv[2], sum);
      sum = fmaf(q[3], rv[3], sum);
    }
    float* dst = (hw ? relw : relh) + (size_t)pair * NTOK * 32 + (size_t)(nbase + nl) * 32 + k;
    *dst = sum;
  }
}

// ---------------------------------------------------------------------------
// Kernel: MFMA flash attention. Block = 4 waves, 64 queries (16/wave).
// 64-key tiles; K staged fragment-linear via global_load_lds; V transposed
// and P round-tripped through XOR-swizzled LDS. Online softmax in MFMA
// D-layout (row=(lane>>4)*4+reg, col=lane&15). P split hi/lo bf16 for PV.
// grid = 24 * 16 = 384 blocks of 256 threads.
// ---------------------------------------------------------------------------
__global__ __launch_bounds__(256) void k_attn_mfma(
    const unsigned short* __restrict__ qT, const unsigned short* __restrict__ kT,
    const unsigned short* __restrict__ vT,
    const float* __restrict__ relh, const float* __restrict__ relw,
    unsigned short* __restrict__ o1h, unsigned short* __restrict__ o1l)
{
  __shared__ short Kf[8 * 512];     // 8 fragment-linear K buffers (1KB each)
  __shared__ char VTb[8192];        // V^T [64 d][64 k] bf16, XOR-swizzled rows
  __shared__ char Phb[8192];        // P hi [64 q][64 k] bf16, swizzled
  __shared__ char Plb[8192];        // P lo
  __shared__ float RhS[64][36];     // relh rows for this q-tile

  const int bid = blockIdx.x;
  const int pair = bid >> 4;
  const int q0 = (bid & 15) * 64;
  const int bb = pair / NHEADS, head = pair % NHEADS;
  const unsigned short* qp = qT + (size_t)pair * NTOK * HD;
  const unsigned short* kp = kT + (size_t)pair * NTOK * HD;
  const unsigned short* vp = vT + (size_t)pair * NTOK * HD;
  const float* rhp = relh + (size_t)pair * NTOK * 32;
  const float* rwp = relw + (size_t)pair * NTOK * 32;

  const int tid = threadIdx.x;
  const int lane = tid & 63, w = tid >> 6;
  const int l15 = lane & 15, l4 = lane >> 4;
  const int wq = w * 16;            // wave's q-row base within the 64-tile

  // stage relh rows q0..q0+63 (contiguous 8KB) into padded LDS
  {
    int row = tid >> 2, seg = tid & 3;
    const float* src = rhp + (size_t)(q0 + row) * 32 + seg * 8;
    *(fx4*)&RhS[row][seg * 8]     = *(const fx4*)src;
    *(fx4*)&RhS[row][seg * 8 + 4] = *(const fx4*)(src + 4);
  }

  // Q fragments live in registers for the whole kernel
  bfrag qf[2];
  qf[0] = *(const bfrag*)(qp + (size_t)(q0 + wq + l15) * HD + l4 * 8);
  qf[1] = *(const bfrag*)(qp + (size_t)(q0 + wq + l15) * HD + 32 + l4 * 8);

  // relw bias: independent of key tile -> 8 registers
  float rw[4][2];
  #pragma unroll
  for (int r = 0; r < 4; r++)
    #pragma unroll
    for (int h = 0; h < 2; h++)
      rw[r][h] = rwp[(size_t)(q0 + wq + l4 * 4 + r) * 32 + h * 16 + l15];

  ffrag o[4] = {};
  float mrow[4] = {-3e38f, -3e38f, -3e38f, -3e38f};
  float lrow[4] = {};

  for (int t = 0; t < 16; t++) {
    const int k0 = t * 64;
    __syncthreads();                       // prev tile's K/VT reads done
    // --- stage K fragments: wave w stages keys k0+w*16..+15, both K-chunks
    {
      const unsigned short* s0 = kp + (size_t)(k0 + wq + l15) * HD + l4 * 8;
      gload16(s0,      Kf + (w * 2 + 0) * 512);
      gload16(s0 + 32, Kf + (w * 2 + 1) * 512);
    }
    // --- stage V transposed: VT[d][k]
    {
      const int kv = tid & 63, db = tid >> 6;
      #pragma unroll
      for (int j = 0; j < 4; j++) {
        ushort4 a = *(const ushort4*)(vp + (size_t)(k0 + kv) * HD + db * 16 + j * 4);
        int d0 = db * 16 + j * 4;
        *(unsigned short*)(VTb + swz(d0 + 0, 2 * kv)) = a.x;
        *(unsigned short*)(VTb + swz(d0 + 1, 2 * kv)) = a.y;
        *(unsigned short*)(VTb + swz(d0 + 2, 2 * kv)) = a.z;
        *(unsigned short*)(VTb + swz(d0 + 3, 2 * kv)) = a.w;
      }
    }
    __syncthreads();                       // staging visible (incl. vmcnt drain)

    // --- QK^T: S[16q x 64k] per wave, 8 MFMA
    ffrag s[4] = {};
    #pragma unroll
    for (int kf = 0; kf < 4; kf++) {
      bfrag kf0 = *(const bfrag*)(Kf + (kf * 2 + 0) * 512 + lane * 8);
      bfrag kf1 = *(const bfrag*)(Kf + (kf * 2 + 1) * 512 + lane * 8);
      s[kf] = mfma16(qf[0], kf0, s[kf]);
      s[kf] = mfma16(qf[1], kf1, s[kf]);
    }

    // --- bias + online softmax (16-lane shfl reduce per q-row)
    fx2 rh2[4];
    #pragma unroll
    for (int r = 0; r < 4; r++)
      rh2[r] = *(const fx2*)&RhS[wq + l4 * 4 + r][2 * t];
    float pm[4] = {-3e38f, -3e38f, -3e38f, -3e38f};
    #pragma unroll
    for (int kf = 0; kf < 4; kf++)
      #pragma unroll
      for (int r = 0; r < 4; r++) {
        float sc = fmaf(s[kf][r], 0.125f, rh2[r][kf >> 1] + rw[r][kf & 1]);
        s[kf][r] = sc;
        pm[r] = fmaxf(pm[r], sc);
      }
    #pragma unroll
    for (int off = 1; off < 16; off <<= 1)
      #pragma unroll
      for (int r = 0; r < 4; r++)
        pm[r] = fmaxf(pm[r], __shfl_xor(pm[r], off));
    float al[4], ps[4] = {0.f, 0.f, 0.f, 0.f};
    #pragma unroll
    for (int r = 0; r < 4; r++) {
      float mnew = fmaxf(mrow[r], pm[r]);
      al[r] = __expf(mrow[r] - mnew);
      mrow[r] = mnew;
    }
    #pragma unroll
    for (int kf = 0; kf < 4; kf++)
      #pragma unroll
      for (int r = 0; r < 4; r++) {
        float p = __expf(s[kf][r] - mrow[r]);
        s[kf][r] = p;
        ps[r] += p;
      }
    #pragma unroll
    for (int off = 1; off < 16; off <<= 1)
      #pragma unroll
      for (int r = 0; r < 4; r++)
        ps[r] += __shfl_xor(ps[r], off);
    #pragma unroll
    for (int r = 0; r < 4; r++)
      lrow[r] = fmaf(lrow[r], al[r], ps[r]);

    // --- P -> bf16 hi/lo into per-wave LDS rows (intra-wave use only)
    #pragma unroll
    for (int kf = 0; kf < 4; kf++)
      #pragma unroll
      for (int r = 0; r < 4; r++) {
        unsigned short hi = f2b(s[kf][r]);
        float lo = s[kf][r] - b2f(hi);
        int a = swz(wq + l4 * 4 + r, kf * 32 + 2 * l15);
        *(unsigned short*)(Phb + a) = hi;
        *(unsigned short*)(Plb + a) = f2b(lo);
      }
    // --- rescale running output
    #pragma unroll
    for (int df = 0; df < 4; df++)
      #pragma unroll
      for (int r = 0; r < 4; r++)
        o[df][r] *= al[r];

    // --- PV: out[16q x 64d] += P[16q x 64k] . V[64k x 64d]
    bfrag ph[2], pl[2];
    #pragma unroll
    for (int kc = 0; kc < 2; kc++) {
      int a = swz(wq + l15, kc * 64 + l4 * 16);
      ph[kc] = *(const bfrag*)(Phb + a);
      pl[kc] = *(const bfrag*)(Plb + a);
    }
    #pragma unroll
    for (int df = 0; df < 4; df++)
      #pragma unroll
      for (int kc = 0; kc < 2; kc++) {
        bfrag vf = *(const bfrag*)(VTb + swz(df * 16 + l15, kc * 64 + l4 * 16));
        o[df] = mfma16(ph[kc], vf, o[df]);
        o[df] = mfma16(pl[kc], vf, o[df]);
      }
  }

  // --- epilogue: normalize, write bf16 hi/lo for proj GEMM
  float inv[4];
  #pragma unroll
  for (int r = 0; r < 4; r++) inv[r] = 1.0f / lrow[r];
  #pragma unroll
  for (int df = 0; df < 4; df++)
    #pragma unroll
    for (int r = 0; r < 4; r++) {
      float val = o[df][r] * inv[r];
      int row = q0 + wq + l4 * 4 + r;
      size_t idx = ((size_t)(bb * NTOK + row)) * DIMM + head * HD + df * 16 + l15;
      unsigned short hi = f2b(val);
      o1h[idx] = hi;
      o1l[idx] = f2b(val - b2f(hi));
    }
}

// ---------------------------------------------------------------------------
extern "C" void kernel_launch(void* const* d_in, const int* in_sizes, int n_in,
                              void* d_out, int out_size, void* d_ws, size_t ws_size,
                              hipStream_t stream)
{
  const float* x      = (const float*)d_in[0];
  const float* qkv_w  = (const float*)d_in[1];
  const float* qkv_b  = (const float*)d_in[2];
  const float* proj_w = (const float*)d_in[3];
  const float* proj_b = (const float*)d_in[4];
  const float* rph    = (const float*)d_in[5];
  const float* rpw    = (const float*)d_in[6];

  char* p = (char*)d_ws;
  unsigned short* xh  = (unsigned short*)p; p += 3145728;   // 2048*768*2
  unsigned short* xl  = (unsigned short*)p; p += 3145728;
  unsigned short* wh  = (unsigned short*)p; p += 3538944;   // 2304*768*2
  unsigned short* wl  = (unsigned short*)p; p += 3538944;
  unsigned short* pwh = (unsigned short*)p; p += 1179648;   // 768*768*2
  unsigned short* pwl = (unsigned short*)p; p += 1179648;
  unsigned short* qb  = (unsigned short*)p; p += 3145728;   // 24*1024*64*2
  unsigned short* kb  = (unsigned short*)p; p += 3145728;
  unsigned short* vb  = (unsigned short*)p; p += 3145728;
  float* relh = (float*)p; p += 3145728;                    // 24*1024*32*4
  float* relw = (float*)p; p += 3145728;
  unsigned short* o1h = xh;   // xh/xl dead after k_qkv_mfma
  unsigned short* o1l = xl;
  float* out = (float*)d_out;

  k_cvt<<<dim3(1536), dim3(256), 0, stream>>>(x,      xh,  xl,  393216);
  k_cvt<<<dim3(1728), dim3(256), 0, stream>>>(qkv_w,  wh,  wl,  442368);
  k_cvt<<<dim3(576),  dim3(256), 0, stream>>>(proj_w, pwh, pwl, 147456);
  k_qkv_mfma<<<dim3(1152), dim3(256), 0, stream>>>(xh, xl, wh, wl, qkv_b, qb, kb, vb);
  k_rel<<<dim3(768), dim3(256), 0, stream>>>(qb, rph, rpw, relh, relw);
  k_attn_mfma<<<dim3(384), dim3(256), 0, stream>>>(qb, kb, vb, relh, relw, o1h, o1l);
  k_proj_mfma<<<dim3(384), dim3(256), 0, stream>>>(o1h, o1l, pwh, pwl, proj_b, out);
}

// Round 4
// 154.426 us; speedup vs baseline: 2.6970x; 1.0430x over previous
//
#include <hip/hip_runtime.h>

typedef float fx4 __attribute__((ext_vector_type(4)));
typedef float fx2 __attribute__((ext_vector_type(2)));
typedef short bfrag __attribute__((ext_vector_type(8)));
typedef float ffrag __attribute__((ext_vector_type(4)));

#define NTOK  1024
#define NHEADS 12
#define HD    64
#define DIMM  768

// ---------------- bf16 helpers (bit-level, RNE) ----------------
__device__ __forceinline__ float b2f(unsigned short u) {
  union { unsigned i; float f; } x; x.i = ((unsigned)u) << 16; return x.f;
}
__device__ __forceinline__ unsigned short f2b(float f) {
  union { float f; unsigned i; } x; x.f = f;
  unsigned r = x.i + 0x7fff + ((x.i >> 16) & 1);
  return (unsigned short)(r >> 16);
}

__device__ __forceinline__ void gload16(const void* g, void* l) {
  __builtin_amdgcn_global_load_lds(
      (const __attribute__((address_space(1))) unsigned*)g,
      (__attribute__((address_space(3))) unsigned*)l, 16, 0, 0);
}

__device__ __forceinline__ ffrag mfma16(bfrag a, bfrag b, ffrag c) {
  return __builtin_amdgcn_mfma_f32_16x16x32_bf16(a, b, c, 0, 0, 0);
}

// XOR-swizzled byte address within a [rows][128B] LDS tile (G4 fix).
__device__ __forceinline__ int swz(int row, int b) {
  return row * 128 + (b ^ ((row & 7) << 4));
}

// ---------------------------------------------------------------------------
// k_cvt3: fused fp32 -> (hi,lo) bf16 split for x, qkv_w, proj_w in ONE launch.
// Quad counts: x 393216, w 442368, pw 147456 -> 983040 quads, 3840 blocks.
// ---------------------------------------------------------------------------
__global__ __launch_bounds__(256) void k_cvt3(
    const float* __restrict__ x, const float* __restrict__ w,
    const float* __restrict__ pw,
    unsigned short* __restrict__ xh, unsigned short* __restrict__ xl,
    unsigned short* __restrict__ wh, unsigned short* __restrict__ wl,
    unsigned short* __restrict__ pwh, unsigned short* __restrict__ pwl)
{
  int i = blockIdx.x * 256 + threadIdx.x;
  const float* src; unsigned short *h, *l; int off;
  if (i < 393216)      { src = x;  h = xh;  l = xl;  off = i; }
  else if (i < 835584) { src = w;  h = wh;  l = wl;  off = i - 393216; }
  else                 { src = pw; h = pwh; l = pwl; off = i - 835584; }
  fx4 v = *(const fx4*)(src + (size_t)off * 4);
  ushort4 hh, ll;
  float t;
  hh.x = f2b(v[0]); t = v[0] - b2f(hh.x); ll.x = f2b(t);
  hh.y = f2b(v[1]); t = v[1] - b2f(hh.y); ll.y = f2b(t);
  hh.z = f2b(v[2]); t = v[2] - b2f(hh.z); ll.z = f2b(t);
  hh.w = f2b(v[3]); t = v[3] - b2f(hh.w); ll.w = f2b(t);
  *(ushort4*)(h + (size_t)off * 4) = hh;
  *(ushort4*)(l + (size_t)off * 4) = ll;
}

// ---------------------------------------------------------------------------
// 2-phase pipelined bf16x3 NT-GEMM core (T3 minimum recipe).
// Block tile (2*MR*16) x (2*NR*16), BK=32, 4 waves in 2x2.
// LDS: double-buffered fragment-linear 1KB frags:
//   buffer layout [Ah(2MR) | Al(2MR) | Bh(2NR) | Bl(2NR)] x 512 shorts.
// Per iteration: issue next tile's global_load_lds, compute current, ONE
// __syncthreads() (vmcnt+lgkm drain + barrier) per K-step.
// ---------------------------------------------------------------------------
template<int MR, int NR>
__device__ __forceinline__ void gemm_pipe(
    const unsigned short* __restrict__ Ah, const unsigned short* __restrict__ Al,
    const unsigned short* __restrict__ Bh, const unsigned short* __restrict__ Bl,
    int row0, int col0, int K, short* lds, ffrag (&acc)[MR][NR])
{
  constexpr int F = 4 * MR + 4 * NR;     // 1KB frags per buffer
  const int tid = threadIdx.x;
  const int lane = tid & 63, w = tid >> 6;
  const int wr = w >> 1, wc = w & 1;
  const int l15 = lane & 15, l8 = (lane >> 4) * 8;

  auto stage = [&](short* buf, int k0) {
    #pragma unroll
    for (int i = 0; i < F / 4; i++) {
      int f = i * 4 + w;                 // section boundaries are mult of 4
      const unsigned short* src;
      if (f < 2 * MR)
        src = Ah + (size_t)(row0 + f * 16 + l15) * K + k0 + l8;
      else if (f < 4 * MR)
        src = Al + (size_t)(row0 + (f - 2 * MR) * 16 + l15) * K + k0 + l8;
      else if (f < 4 * MR + 2 * NR)
        src = Bh + (size_t)(col0 + (f - 4 * MR) * 16 + l15) * K + k0 + l8;
      else
        src = Bl + (size_t)(col0 + (f - 4 * MR - 2 * NR) * 16 + l15) * K + k0 + l8;
      gload16(src, buf + f * 512);
    }
  };

  auto step = [&](const short* buf) {
    bfrag ah[MR], al[MR], bh[NR], bl[NR];
    #pragma unroll
    for (int i = 0; i < MR; i++) {
      ah[i] = *(const bfrag*)(buf + (wr * MR + i) * 512 + lane * 8);
      al[i] = *(const bfrag*)(buf + (2 * MR + wr * MR + i) * 512 + lane * 8);
    }
    #pragma unroll
    for (int j = 0; j < NR; j++) {
      bh[j] = *(const bfrag*)(buf + (4 * MR + wc * NR + j) * 512 + lane * 8);
      bl[j] = *(const bfrag*)(buf + (4 * MR + 2 * NR + wc * NR + j) * 512 + lane * 8);
    }
    #pragma unroll
    for (int i = 0; i < MR; i++)
      #pragma unroll
      for (int j = 0; j < NR; j++) {
        acc[i][j] = mfma16(ah[i], bh[j], acc[i][j]);
        acc[i][j] = mfma16(ah[i], bl[j], acc[i][j]);
        acc[i][j] = mfma16(al[i], bh[j], acc[i][j]);
      }
  };

  short* cur = lds;
  short* nxt = lds + F * 512;
  stage(cur, 0);
  __syncthreads();
  const int nt = K / 32;
  for (int t = 0; t < nt - 1; t++) {
    stage(nxt, (t + 1) * 32);            // prefetch issue BEFORE compute
    step(cur);
    __syncthreads();                     // one drain+barrier per K-step
    short* tmp = cur; cur = nxt; nxt = tmp;
  }
  step(cur);
}

// ---------------------------------------------------------------------------
// qkv GEMM: M=2048, N=2304, K=768; tile 128x64; grid 16x36=576 (XCD-swizzled).
// Scatter epilogue to q/k/v bf16 [B*NH][NTOK][HD].
// ---------------------------------------------------------------------------
__global__ __launch_bounds__(256) void k_qkv_mfma(
    const unsigned short* __restrict__ xh, const unsigned short* __restrict__ xl,
    const unsigned short* __restrict__ wh, const unsigned short* __restrict__ wl,
    const float* __restrict__ bias,
    unsigned short* __restrict__ qo, unsigned short* __restrict__ ko,
    unsigned short* __restrict__ vo)
{
  __shared__ short lds[2 * 24 * 512];    // 48 KB
  const int orig = blockIdx.x;
  const int bid = (orig & 7) * 72 + (orig >> 3);   // 576 = 8 * 72, bijective
  const int bm = bid & 15, bn = bid >> 4;          // 16 M-tiles x 36 N-tiles
  const int row0 = bm * 128, col0 = bn * 64;
  ffrag acc[4][2] = {};
  gemm_pipe<4, 2>(xh, xl, wh, wl, row0, col0, 768, lds, acc);

  const int tid = threadIdx.x, lane = tid & 63, w = tid >> 6;
  const int wr = w >> 1, wc = w & 1;
  const int l15 = lane & 15, l4 = lane >> 4;
  const int which = col0 / 768;                    // uniform per block
  const int head  = (col0 % 768) >> 6;
  unsigned short* base = which == 0 ? qo : (which == 1 ? ko : vo);
  #pragma unroll
  for (int mi = 0; mi < 4; mi++)
    #pragma unroll
    for (int ni = 0; ni < 2; ni++) {
      int d = wc * 32 + ni * 16 + l15;             // 0..63 within head
      float bv = bias[col0 + d];
      #pragma unroll
      for (int r = 0; r < 4; r++) {
        int row = row0 + wr * 64 + mi * 16 + l4 * 4 + r;
        int bb = row >> 10, n = row & 1023;
        base[((size_t)(bb * NHEADS + head) * NTOK + n) * HD + d] =
            f2b(acc[mi][ni][r] + bv);
      }
    }
}

// ---------------------------------------------------------------------------
// proj GEMM: M=2048, N=768, K=768; tile 64x64; grid 32x12=384 (XCD-swizzled).
// ---------------------------------------------------------------------------
__global__ __launch_bounds__(256) void k_proj_mfma(
    const unsigned short* __restrict__ ah, const unsigned short* __restrict__ al,
    const unsigned short* __restrict__ bh, const unsigned short* __restrict__ bl,
    const float* __restrict__ bias, float* __restrict__ out)
{
  __shared__ short lds[2 * 16 * 512];    // 32 KB
  const int orig = blockIdx.x;
  const int bid = (orig & 7) * 48 + (orig >> 3);   // 384 = 8 * 48, bijective
  const int bm = bid & 31, bn = bid >> 5;          // 32 M-tiles x 12 N-tiles
  const int row0 = bm * 64, col0 = bn * 64;
  ffrag acc[2][2] = {};
  gemm_pipe<2, 2>(ah, al, bh, bl, row0, col0, 768, lds, acc);

  const int tid = threadIdx.x, lane = tid & 63, w = tid >> 6;
  const int wr = w >> 1, wc = w & 1;
  const int l15 = lane & 15, l4 = lane >> 4;
  #pragma unroll
  for (int mi = 0; mi < 2; mi++)
    #pragma unroll
    for (int ni = 0; ni < 2; ni++) {
      int col = col0 + wc * 32 + ni * 16 + l15;
      float bv = bias[col];
      #pragma unroll
      for (int r = 0; r < 4; r++) {
        int row = row0 + wr * 32 + mi * 16 + l4 * 4 + r;
        out[(size_t)row * 768 + col] = acc[mi][ni][r] + bv;
      }
    }
}

// ---------------------------------------------------------------------------
// Kernel: rel-pos bias precompute (q bf16).
// ---------------------------------------------------------------------------
__global__ __launch_bounds__(256) void k_rel(
    const unsigned short* __restrict__ qT, const float* __restrict__ rph,
    const float* __restrict__ rpw,
    float* __restrict__ relh, float* __restrict__ relw)
{
  __shared__ float Qs[32][68];
  __shared__ float RhS[32][68];
  __shared__ float RwS[63][68];
  const int bid = blockIdx.x;
  const int pair = bid >> 5;
  const int nt = bid & 31;
  const int nbase = nt * 32;
  const unsigned short* qp = qT + (size_t)pair * NTOK * HD + (size_t)nbase * HD;
  const int tid = threadIdx.x;
  #pragma unroll
  for (int ii = 0; ii < 2; ii++) {
    int f = ii * 256 + tid;
    int r = f >> 4, k4 = f & 15;
    ushort4 t = *(const ushort4*)(qp + (size_t)r * HD + k4 * 4);
    Qs[r][k4*4+0] = b2f(t.x); Qs[r][k4*4+1] = b2f(t.y);
    Qs[r][k4*4+2] = b2f(t.z); Qs[r][k4*4+3] = b2f(t.w);
    *(fx4*)&RhS[r][k4*4] = *(const fx4*)(rph + (size_t)(nt + r) * 64 + k4 * 4);
  }
  #pragma unroll
  for (int ii = 0; ii < 4; ii++) {
    int f = ii * 256 + tid;
    if (f < 1008) {
      int r = f >> 4, k4 = f & 15;
      *(fx4*)&RwS[r][k4*4] = *(const fx4*)(rpw + (size_t)r * 64 + k4 * 4);
    }
  }
  __syncthreads();
  const int nl = tid >> 3, rem = tid & 7;
  #pragma unroll
  for (int rep = 0; rep < 8; rep++) {
    int kidx = rep * 8 + rem;
    int hw = kidx >> 5;
    int k = kidx & 31;
    const float* rrow = hw ? &RwS[nl + 31 - k][0] : &RhS[31 - k][0];
    float sum = 0.f;
    #pragma unroll
    for (int c4 = 0; c4 < 16; c4++) {
      fx4 q = *(const fx4*)&Qs[nl][c4*4];
      fx4 rv = *(const fx4*)&rrow[c4*4];
      sum = fmaf(q[0], rv[0], sum);
      sum = fmaf(q[1], rv[1], sum);
      sum = fmaf(q[2], rv[2], sum);
      sum = fmaf(q[3], rv[3], sum);
    }
    float* dst = (hw ? relw : relh) + (size_t)pair * NTOK * 32 + (size_t)(nbase + nl) * 32 + k;
    *dst = sum;
  }
}

// ---------------------------------------------------------------------------
// Kernel: MFMA flash attention (unchanged from round 3).
// ---------------------------------------------------------------------------
__global__ __launch_bounds__(256) void k_attn_mfma(
    const unsigned short* __restrict__ qT, const unsigned short* __restrict__ kT,
    const unsigned short* __restrict__ vT,
    const float* __restrict__ relh, const float* __restrict__ relw,
    unsigned short* __restrict__ o1h, unsigned short* __restrict__ o1l)
{
  __shared__ short Kf[8 * 512];     // 8 fragment-linear K buffers (1KB each)
  __shared__ char VTb[8192];        // V^T [64 d][64 k] bf16, XOR-swizzled rows
  __shared__ char Phb[8192];        // P hi [64 q][64 k] bf16, swizzled
  __shared__ char Plb[8192];        // P lo
  __shared__ float RhS[64][36];     // relh rows for this q-tile

  const int bid = blockIdx.x;
  const int pair = bid >> 4;
  const int q0 = (bid & 15) * 64;
  const int bb = pair / NHEADS, head = pair % NHEADS;
  const unsigned short* qp = qT + (size_t)pair * NTOK * HD;
  const unsigned short* kp = kT + (size_t)pair * NTOK * HD;
  const unsigned short* vp = vT + (size_t)pair * NTOK * HD;
  const float* rhp = relh + (size_t)pair * NTOK * 32;
  const float* rwp = relw + (size_t)pair * NTOK * 32;

  const int tid = threadIdx.x;
  const int lane = tid & 63, w = tid >> 6;
  const int l15 = lane & 15, l4 = lane >> 4;
  const int wq = w * 16;            // wave's q-row base within the 64-tile

  {
    int row = tid >> 2, seg = tid & 3;
    const float* src = rhp + (size_t)(q0 + row) * 32 + seg * 8;
    *(fx4*)&RhS[row][seg * 8]     = *(const fx4*)src;
    *(fx4*)&RhS[row][seg * 8 + 4] = *(const fx4*)(src + 4);
  }

  bfrag qf[2];
  qf[0] = *(const bfrag*)(qp + (size_t)(q0 + wq + l15) * HD + l4 * 8);
  qf[1] = *(const bfrag*)(qp + (size_t)(q0 + wq + l15) * HD + 32 + l4 * 8);

  float rw[4][2];
  #pragma unroll
  for (int r = 0; r < 4; r++)
    #pragma unroll
    for (int h = 0; h < 2; h++)
      rw[r][h] = rwp[(size_t)(q0 + wq + l4 * 4 + r) * 32 + h * 16 + l15];

  ffrag o[4] = {};
  float mrow[4] = {-3e38f, -3e38f, -3e38f, -3e38f};
  float lrow[4] = {};

  for (int t = 0; t < 16; t++) {
    const int k0 = t * 64;
    __syncthreads();
    {
      const unsigned short* s0 = kp + (size_t)(k0 + wq + l15) * HD + l4 * 8;
      gload16(s0,      Kf + (w * 2 + 0) * 512);
      gload16(s0 + 32, Kf + (w * 2 + 1) * 512);
    }
    {
      const int kv = tid & 63, db = tid >> 6;
      #pragma unroll
      for (int j = 0; j < 4; j++) {
        ushort4 a = *(const ushort4*)(vp + (size_t)(k0 + kv) * HD + db * 16 + j * 4);
        int d0 = db * 16 + j * 4;
        *(unsigned short*)(VTb + swz(d0 + 0, 2 * kv)) = a.x;
        *(unsigned short*)(VTb + swz(d0 + 1, 2 * kv)) = a.y;
        *(unsigned short*)(VTb + swz(d0 + 2, 2 * kv)) = a.z;
        *(unsigned short*)(VTb + swz(d0 + 3, 2 * kv)) = a.w;
      }
    }
    __syncthreads();

    ffrag s[4] = {};
    #pragma unroll
    for (int kf = 0; kf < 4; kf++) {
      bfrag kf0 = *(const bfrag*)(Kf + (kf * 2 + 0) * 512 + lane * 8);
      bfrag kf1 = *(const bfrag*)(Kf + (kf * 2 + 1) * 512 + lane * 8);
      s[kf] = mfma16(qf[0], kf0, s[kf]);
      s[kf] = mfma16(qf[1], kf1, s[kf]);
    }

    fx2 rh2[4];
    #pragma unroll
    for (int r = 0; r < 4; r++)
      rh2[r] = *(const fx2*)&RhS[wq + l4 * 4 + r][2 * t];
    float pm[4] = {-3e38f, -3e38f, -3e38f, -3e38f};
    #pragma unroll
    for (int kf = 0; kf < 4; kf++)
      #pragma unroll
      for (int r = 0; r < 4; r++) {
        float sc = fmaf(s[kf][r], 0.125f, rh2[r][kf >> 1] + rw[r][kf & 1]);
        s[kf][r] = sc;
        pm[r] = fmaxf(pm[r], sc);
      }
    #pragma unroll
    for (int off = 1; off < 16; off <<= 1)
      #pragma unroll
      for (int r = 0; r < 4; r++)
        pm[r] = fmaxf(pm[r], __shfl_xor(pm[r], off));
    float al[4], ps[4] = {0.f, 0.f, 0.f, 0.f};
    #pragma unroll
    for (int r = 0; r < 4; r++) {
      float mnew = fmaxf(mrow[r], pm[r]);
      al[r] = __expf(mrow[r] - mnew);
      mrow[r] = mnew;
    }
    #pragma unroll
    for (int kf = 0; kf < 4; kf++)
      #pragma unroll
      for (int r = 0; r < 4; r++) {
        float p = __expf(s[kf][r] - mrow[r]);
        s[kf][r] = p;
        ps[r] += p;
      }
    #pragma unroll
    for (int off = 1; off < 16; off <<= 1)
      #pragma unroll
      for (int r = 0; r < 4; r++)
        ps[r] += __shfl_xor(ps[r], off);
    #pragma unroll
    for (int r = 0; r < 4; r++)
      lrow[r] = fmaf(lrow[r], al[r], ps[r]);

    #pragma unroll
    for (int kf = 0; kf < 4; kf++)
      #pragma unroll
      for (int r = 0; r < 4; r++) {
        unsigned short hi = f2b(s[kf][r]);
        float lo = s[kf][r] - b2f(hi);
        int a = swz(wq + l4 * 4 + r, kf * 32 + 2 * l15);
        *(unsigned short*)(Phb + a) = hi;
        *(unsigned short*)(Plb + a) = f2b(lo);
      }
    #pragma unroll
    for (int df = 0; df < 4; df++)
      #pragma unroll
      for (int r = 0; r < 4; r++)
        o[df][r] *= al[r];

    bfrag ph[2], pl[2];
    #pragma unroll
    for (int kc = 0; kc < 2; kc++) {
      int a = swz(wq + l15, kc * 64 + l4 * 16);
      ph[kc] = *(const bfrag*)(Phb + a);
      pl[kc] = *(const bfrag*)(Plb + a);
    }
    #pragma unroll
    for (int df = 0; df < 4; df++)
      #pragma unroll
      for (int kc = 0; kc < 2; kc++) {
        bfrag vf = *(const bfrag*)(VTb + swz(df * 16 + l15, kc * 64 + l4 * 16));
        o[df] = mfma16(ph[kc], vf, o[df]);
        o[df] = mfma16(pl[kc], vf, o[df]);
      }
  }

  float inv[4];
  #pragma unroll
  for (int r = 0; r < 4; r++) inv[r] = 1.0f / lrow[r];
  #pragma unroll
  for (int df = 0; df < 4; df++)
    #pragma unroll
    for (int r = 0; r < 4; r++) {
      float val = o[df][r] * inv[r];
      int row = q0 + wq + l4 * 4 + r;
      size_t idx = ((size_t)(bb * NTOK + row)) * DIMM + head * HD + df * 16 + l15;
      unsigned short hi = f2b(val);
      o1h[idx] = hi;
      o1l[idx] = f2b(val - b2f(hi));
    }
}

// ---------------------------------------------------------------------------
extern "C" void kernel_launch(void* const* d_in, const int* in_sizes, int n_in,
                              void* d_out, int out_size, void* d_ws, size_t ws_size,
                              hipStream_t stream)
{
  const float* x      = (const float*)d_in[0];
  const float* qkv_w  = (const float*)d_in[1];
  const float* qkv_b  = (const float*)d_in[2];
  const float* proj_w = (const float*)d_in[3];
  const float* proj_b = (const float*)d_in[4];
  const float* rph    = (const float*)d_in[5];
  const float* rpw    = (const float*)d_in[6];

  char* p = (char*)d_ws;
  unsigned short* xh  = (unsigned short*)p; p += 3145728;   // 2048*768*2
  unsigned short* xl  = (unsigned short*)p; p += 3145728;
  unsigned short* wh  = (unsigned short*)p; p += 3538944;   // 2304*768*2
  unsigned short* wl  = (unsigned short*)p; p += 3538944;
  unsigned short* pwh = (unsigned short*)p; p += 1179648;   // 768*768*2
  unsigned short* pwl = (unsigned short*)p; p += 1179648;
  unsigned short* qb  = (unsigned short*)p; p += 3145728;   // 24*1024*64*2
  unsigned short* kb  = (unsigned short*)p; p += 3145728;
  unsigned short* vb  = (unsigned short*)p; p += 3145728;
  float* relh = (float*)p; p += 3145728;                    // 24*1024*32*4
  float* relw = (float*)p; p += 3145728;
  unsigned short* o1h = xh;   // xh/xl dead after k_qkv_mfma
  unsigned short* o1l = xl;
  float* out = (float*)d_out;

  k_cvt3<<<dim3(3840), dim3(256), 0, stream>>>(x, qkv_w, proj_w,
                                               xh, xl, wh, wl, pwh, pwl);
  k_qkv_mfma<<<dim3(576), dim3(256), 0, stream>>>(xh, xl, wh, wl, qkv_b, qb, kb, vb);
  k_rel<<<dim3(768), dim3(256), 0, stream>>>(qb, rph, rpw, relh, relw);
  k_attn_mfma<<<dim3(384), dim3(256), 0, stream>>>(qb, kb, vb, relh, relw, o1h, o1l);
  k_proj_mfma<<<dim3(384), dim3(256), 0, stream>>>(o1h, o1l, pwh, pwl, proj_b, out);
}

// Round 5
// 151.012 us; speedup vs baseline: 2.7580x; 1.0226x over previous
//
#include <hip/hip_runtime.h>

typedef float fx4 __attribute__((ext_vector_type(4)));
typedef float fx2 __attribute__((ext_vector_type(2)));
typedef short bfrag __attribute__((ext_vector_type(8)));
typedef float ffrag __attribute__((ext_vector_type(4)));
typedef unsigned short ush;

#define NTOK  1024
#define NHEADS 12
#define HD    64
#define DIMM  768

// ---------------- bf16 helpers (bit-level, RNE) ----------------
__device__ __forceinline__ float b2f(ush u) {
  union { unsigned i; float f; } x; x.i = ((unsigned)u) << 16; return x.f;
}
__device__ __forceinline__ ush f2b(float f) {
  union { float f; unsigned i; } x; x.f = f;
  unsigned r = x.i + 0x7fff + ((x.i >> 16) & 1);
  return (ush)(r >> 16);
}

__device__ __forceinline__ void gload16(const void* g, void* l) {
  __builtin_amdgcn_global_load_lds(
      (const __attribute__((address_space(1))) unsigned*)g,
      (__attribute__((address_space(3))) unsigned*)l, 16, 0, 0);
}

__device__ __forceinline__ ffrag mfma16(bfrag a, bfrag b, ffrag c) {
  return __builtin_amdgcn_mfma_f32_16x16x32_bf16(a, b, c, 0, 0, 0);
}

// counted vmcnt wait (T4). N = outstanding VMEM ops allowed to remain.
template<int N> __device__ __forceinline__ void vwait() {
  if constexpr (N == 0)      asm volatile("s_waitcnt vmcnt(0)" ::: "memory");
  else if constexpr (N == 2) asm volatile("s_waitcnt vmcnt(2)" ::: "memory");
  else if constexpr (N == 4) asm volatile("s_waitcnt vmcnt(4)" ::: "memory");
  else if constexpr (N == 6) asm volatile("s_waitcnt vmcnt(6)" ::: "memory");
  else if constexpr (N == 8) asm volatile("s_waitcnt vmcnt(8)" ::: "memory");
  else                       asm volatile("s_waitcnt vmcnt(12)" ::: "memory");
}
// raw barrier (no vmcnt drain) with compiler memory fences
__device__ __forceinline__ void bar() {
  asm volatile("" ::: "memory");
  __builtin_amdgcn_s_barrier();
  asm volatile("" ::: "memory");
}
// barrier that first drains own LDS ops (for ds_write -> cross-wave read)
__device__ __forceinline__ void barL() {
  asm volatile("s_waitcnt lgkmcnt(0)" ::: "memory");
  __builtin_amdgcn_s_barrier();
  asm volatile("" ::: "memory");
}

// XOR-swizzled byte address within a [rows][128B] LDS tile (G4 fix).
__device__ __forceinline__ int swz(int row, int b) {
  return row * 128 + (b ^ ((row & 7) << 4));
}

// ---------------------------------------------------------------------------
// k_cvt3: fused fp32 -> (hi,lo) bf16 split for x, qkv_w, proj_w in ONE launch.
// ---------------------------------------------------------------------------
__global__ __launch_bounds__(256) void k_cvt3(
    const float* __restrict__ x, const float* __restrict__ w,
    const float* __restrict__ pw,
    ush* __restrict__ xh, ush* __restrict__ xl,
    ush* __restrict__ wh, ush* __restrict__ wl,
    ush* __restrict__ pwh, ush* __restrict__ pwl)
{
  int i = blockIdx.x * 256 + threadIdx.x;
  const float* src; ush *h, *l; int off;
  if (i < 393216)      { src = x;  h = xh;  l = xl;  off = i; }
  else if (i < 835584) { src = w;  h = wh;  l = wl;  off = i - 393216; }
  else                 { src = pw; h = pwh; l = pwl; off = i - 835584; }
  fx4 v = *(const fx4*)(src + (size_t)off * 4);
  ushort4 hh, ll;
  float t;
  hh.x = f2b(v[0]); t = v[0] - b2f(hh.x); ll.x = f2b(t);
  hh.y = f2b(v[1]); t = v[1] - b2f(hh.y); ll.y = f2b(t);
  hh.z = f2b(v[2]); t = v[2] - b2f(hh.z); ll.z = f2b(t);
  hh.w = f2b(v[3]); t = v[3] - b2f(hh.w); ll.w = f2b(t);
  *(ushort4*)(h + (size_t)off * 4) = hh;
  *(ushort4*)(l + (size_t)off * 4) = ll;
}

// ---------------------------------------------------------------------------
// Counted-vmcnt TRIPLE-buffered bf16x3 NT-GEMM core (T3+T4).
// Per K-step: vwait<LPS> (stage t done, t+1/t+2 stay in flight) -> barrier ->
// issue stage(t+2) -> compute(t). One barrier per K-step.
// ---------------------------------------------------------------------------
template<int MR, int NR>
__device__ __forceinline__ void gemm_pipe(
    const ush* __restrict__ Ah, const ush* __restrict__ Al,
    const ush* __restrict__ Bh, const ush* __restrict__ Bl,
    int row0, int col0, int K, short* lds, ffrag (&acc)[MR][NR])
{
  constexpr int F = 4 * MR + 4 * NR;     // 1KB frags per K-tile buffer
  constexpr int LPS = F / 4;             // gload16 per thread per stage
  const int tid = threadIdx.x;
  const int lane = tid & 63, w = tid >> 6;
  const int wr = w >> 1, wc = w & 1;
  const int l15 = lane & 15, l8 = (lane >> 4) * 8;

  auto stage = [&](short* buf, int k0) {
    #pragma unroll
    for (int i = 0; i < LPS; i++) {
      int f = i * 4 + w;
      const ush* src;
      if (f < 2 * MR)
        src = Ah + (size_t)(row0 + f * 16 + l15) * K + k0 + l8;
      else if (f < 4 * MR)
        src = Al + (size_t)(row0 + (f - 2 * MR) * 16 + l15) * K + k0 + l8;
      else if (f < 4 * MR + 2 * NR)
        src = Bh + (size_t)(col0 + (f - 4 * MR) * 16 + l15) * K + k0 + l8;
      else
        src = Bl + (size_t)(col0 + (f - 4 * MR - 2 * NR) * 16 + l15) * K + k0 + l8;
      gload16(src, buf + f * 512);
    }
  };

  auto step = [&](const short* buf) {
    bfrag ah[MR], al[MR], bh[NR], bl[NR];
    #pragma unroll
    for (int i = 0; i < MR; i++) {
      ah[i] = *(const bfrag*)(buf + (wr * MR + i) * 512 + lane * 8);
      al[i] = *(const bfrag*)(buf + (2 * MR + wr * MR + i) * 512 + lane * 8);
    }
    #pragma unroll
    for (int j = 0; j < NR; j++) {
      bh[j] = *(const bfrag*)(buf + (4 * MR + wc * NR + j) * 512 + lane * 8);
      bl[j] = *(const bfrag*)(buf + (4 * MR + 2 * NR + wc * NR + j) * 512 + lane * 8);
    }
    #pragma unroll
    for (int i = 0; i < MR; i++)
      #pragma unroll
      for (int j = 0; j < NR; j++) {
        acc[i][j] = mfma16(ah[i], bh[j], acc[i][j]);
        acc[i][j] = mfma16(ah[i], bl[j], acc[i][j]);
        acc[i][j] = mfma16(al[i], bh[j], acc[i][j]);
      }
  };

  const int nt = K / 32;
  stage(lds + 0 * F * 512, 0);
  stage(lds + 1 * F * 512, 32);
  for (int t = 0; t < nt; t++) {
    if (t < nt - 1) vwait<LPS>(); else vwait<0>();
    bar();
    if (t + 2 < nt) stage(lds + ((t + 2) % 3) * F * 512, (t + 2) * 32);
    step(lds + (t % 3) * F * 512);
  }
}

// ---------------------------------------------------------------------------
// qkv GEMM: M=2048, N=2304, K=768; tile 128x64; grid 16x36=576 (XCD-swizzled).
// ---------------------------------------------------------------------------
__global__ __launch_bounds__(256) void k_qkv_mfma(
    const ush* __restrict__ xh, const ush* __restrict__ xl,
    const ush* __restrict__ wh, const ush* __restrict__ wl,
    const float* __restrict__ bias,
    ush* __restrict__ qo, ush* __restrict__ ko, ush* __restrict__ vo)
{
  __shared__ short lds[3 * 24 * 512];    // 72 KB triple buffer
  const int orig = blockIdx.x;
  const int bid = (orig & 7) * 72 + (orig >> 3);   // 576 = 8 * 72, bijective
  const int bm = bid & 15, bn = bid >> 4;
  const int row0 = bm * 128, col0 = bn * 64;
  ffrag acc[4][2] = {};
  gemm_pipe<4, 2>(xh, xl, wh, wl, row0, col0, 768, lds, acc);

  const int tid = threadIdx.x, lane = tid & 63, w = tid >> 6;
  const int wr = w >> 1, wc = w & 1;
  const int l15 = lane & 15, l4 = lane >> 4;
  const int which = col0 / 768;
  const int head  = (col0 % 768) >> 6;
  ush* base = which == 0 ? qo : (which == 1 ? ko : vo);
  #pragma unroll
  for (int mi = 0; mi < 4; mi++)
    #pragma unroll
    for (int ni = 0; ni < 2; ni++) {
      int d = wc * 32 + ni * 16 + l15;
      float bv = bias[col0 + d];
      #pragma unroll
      for (int r = 0; r < 4; r++) {
        int row = row0 + wr * 64 + mi * 16 + l4 * 4 + r;
        int bb = row >> 10, n = row & 1023;
        base[((size_t)(bb * NHEADS + head) * NTOK + n) * HD + d] =
            f2b(acc[mi][ni][r] + bv);
      }
    }
}

// ---------------------------------------------------------------------------
// proj GEMM: M=2048, N=768, K=768; tile 64x64; grid 32x12=384 (XCD-swizzled).
// ---------------------------------------------------------------------------
__global__ __launch_bounds__(256) void k_proj_mfma(
    const ush* __restrict__ ah, const ush* __restrict__ al,
    const ush* __restrict__ bh, const ush* __restrict__ bl,
    const float* __restrict__ bias, float* __restrict__ out)
{
  __shared__ short lds[3 * 16 * 512];    // 48 KB triple buffer
  const int orig = blockIdx.x;
  const int bid = (orig & 7) * 48 + (orig >> 3);   // 384 = 8 * 48, bijective
  const int bm = bid & 31, bn = bid >> 5;
  const int row0 = bm * 64, col0 = bn * 64;
  ffrag acc[2][2] = {};
  gemm_pipe<2, 2>(ah, al, bh, bl, row0, col0, 768, lds, acc);

  const int tid = threadIdx.x, lane = tid & 63, w = tid >> 6;
  const int wr = w >> 1, wc = w & 1;
  const int l15 = lane & 15, l4 = lane >> 4;
  #pragma unroll
  for (int mi = 0; mi < 2; mi++)
    #pragma unroll
    for (int ni = 0; ni < 2; ni++) {
      int col = col0 + wc * 32 + ni * 16 + l15;
      float bv = bias[col];
      #pragma unroll
      for (int r = 0; r < 4; r++) {
        int row = row0 + wr * 32 + mi * 16 + l4 * 4 + r;
        out[(size_t)row * 768 + col] = acc[mi][ni][r] + bv;
      }
    }
}

// ---------------------------------------------------------------------------
// Kernel: rel-pos bias precompute (q bf16). Unchanged.
// ---------------------------------------------------------------------------
__global__ __launch_bounds__(256) void k_rel(
    const ush* __restrict__ qT, const float* __restrict__ rph,
    const float* __restrict__ rpw,
    float* __restrict__ relh, float* __restrict__ relw)
{
  __shared__ float Qs[32][68];
  __shared__ float RhS[32][68];
  __shared__ float RwS[63][68];
  const int bid = blockIdx.x;
  const int pair = bid >> 5;
  const int nt = bid & 31;
  const int nbase = nt * 32;
  const ush* qp = qT + (size_t)pair * NTOK * HD + (size_t)nbase * HD;
  const int tid = threadIdx.x;
  #pragma unroll
  for (int ii = 0; ii < 2; ii++) {
    int f = ii * 256 + tid;
    int r = f >> 4, k4 = f & 15;
    ushort4 t = *(const ushort4*)(qp + (size_t)r * HD + k4 * 4);
    Qs[r][k4*4+0] = b2f(t.x); Qs[r][k4*4+1] = b2f(t.y);
    Qs[r][k4*4+2] = b2f(t.z); Qs[r][k4*4+3] = b2f(t.w);
    *(fx4*)&RhS[r][k4*4] = *(const fx4*)(rph + (size_t)(nt + r) * 64 + k4 * 4);
  }
  #pragma unroll
  for (int ii = 0; ii < 4; ii++) {
    int f = ii * 256 + tid;
    if (f < 1008) {
      int r = f >> 4, k4 = f & 15;
      *(fx4*)&RwS[r][k4*4] = *(const fx4*)(rpw + (size_t)r * 64 + k4 * 4);
    }
  }
  __syncthreads();
  const int nl = tid >> 3, rem = tid & 7;
  #pragma unroll
  for (int rep = 0; rep < 8; rep++) {
    int kidx = rep * 8 + rem;
    int hw = kidx >> 5;
    int k = kidx & 31;
    const float* rrow = hw ? &RwS[nl + 31 - k][0] : &RhS[31 - k][0];
    float sum = 0.f;
    #pragma unroll
    for (int c4 = 0; c4 < 16; c4++) {
      fx4 q = *(const fx4*)&Qs[nl][c4*4];
      fx4 rv = *(const fx4*)&rrow[c4*4];
      sum = fmaf(q[0], rv[0], sum);
      sum = fmaf(q[1], rv[1], sum);
      sum = fmaf(q[2], rv[2], sum);
      sum = fmaf(q[3], rv[3], sum);
    }
    float* dst = (hw ? relw : relh) + (size_t)pair * NTOK * 32 + (size_t)(nbase + nl) * 32 + k;
    *dst = sum;
  }
}

// ---------------------------------------------------------------------------
// MFMA flash attention with counted-vmcnt pipeline:
//  - K tiles: triple-buffered LDS via global_load_lds, issued 2 tiles ahead
//  - V tiles: 2-deep register prefetch (T14), written to swizzled VT in LDS
// Per iteration: vwait<6> (K/V of tile t landed; t+1,t+2 stay in flight),
// barL, VT-write + refill issues, QK^T, softmax, P-write, barL, PV.
// grid = 384 blocks (XCD-chunked so blocks of one head share an XCD L2).
// ---------------------------------------------------------------------------
__global__ __launch_bounds__(256) void k_attn_mfma(
    const ush* __restrict__ qT, const ush* __restrict__ kT,
    const ush* __restrict__ vT,
    const float* __restrict__ relh, const float* __restrict__ relw,
    ush* __restrict__ o1h, ush* __restrict__ o1l)
{
  __shared__ short Kf[3 * 8 * 512]; // 3 K-tile buffers, 8 fragment-linear KB each
  __shared__ char VTb[8192];        // V^T [64 d][64 k] bf16, XOR-swizzled rows
  __shared__ char Phb[8192];        // P hi [64 q][64 k] bf16, swizzled
  __shared__ char Plb[8192];        // P lo
  __shared__ float RhS[64][36];     // relh rows for this q-tile

  const int orig = blockIdx.x;
  const int bid = (orig & 7) * 48 + (orig >> 3);   // 384 = 8 * 48, bijective
  const int pair = bid >> 4;
  const int q0 = (bid & 15) * 64;
  const int bb = pair / NHEADS, head = pair % NHEADS;
  const ush* qp = qT + (size_t)pair * NTOK * HD;
  const ush* kp = kT + (size_t)pair * NTOK * HD;
  const ush* vp = vT + (size_t)pair * NTOK * HD;
  const float* rhp = relh + (size_t)pair * NTOK * 32;
  const float* rwp = relw + (size_t)pair * NTOK * 32;

  const int tid = threadIdx.x;
  const int lane = tid & 63, w = tid >> 6;
  const int l15 = lane & 15, l4 = lane >> 4;
  const int wq = w * 16;
  const int kv = tid & 63, db = tid >> 6;

  auto issueK = [&](int t) {
    const ush* s0 = kp + (size_t)(t * 64 + wq + l15) * HD + l4 * 8;
    short* dst = Kf + (t % 3) * 4096 + (w * 2) * 512;
    gload16(s0, dst);
    gload16(s0 + 32, dst + 512);
  };
  auto issueV = [&](int t, ushort4 (&vr)[4]) {
    #pragma unroll
    for (int j = 0; j < 4; j++)
      vr[j] = *(const ushort4*)(vp + (size_t)(t * 64 + kv) * HD + db * 16 + j * 4);
  };
  auto writeVT = [&](ushort4 (&vr)[4]) {
    #pragma unroll
    for (int j = 0; j < 4; j++) {
      int d0 = db * 16 + j * 4;
      *(ush*)(VTb + swz(d0 + 0, 2 * kv)) = vr[j].x;
      *(ush*)(VTb + swz(d0 + 1, 2 * kv)) = vr[j].y;
      *(ush*)(VTb + swz(d0 + 2, 2 * kv)) = vr[j].z;
      *(ush*)(VTb + swz(d0 + 3, 2 * kv)) = vr[j].w;
    }
  };

  // ---- prologue: block-local data first, then pipeline issues ----
  {
    int row = tid >> 2, seg = tid & 3;
    const float* src = rhp + (size_t)(q0 + row) * 32 + seg * 8;
    *(fx4*)&RhS[row][seg * 8]     = *(const fx4*)src;
    *(fx4*)&RhS[row][seg * 8 + 4] = *(const fx4*)(src + 4);
  }
  bfrag qf[2];
  qf[0] = *(const bfrag*)(qp + (size_t)(q0 + wq + l15) * HD + l4 * 8);
  qf[1] = *(const bfrag*)(qp + (size_t)(q0 + wq + l15) * HD + 32 + l4 * 8);
  float rw[4][2];
  #pragma unroll
  for (int r = 0; r < 4; r++)
    #pragma unroll
    for (int h = 0; h < 2; h++)
      rw[r][h] = rwp[(size_t)(q0 + wq + l4 * 4 + r) * 32 + h * 16 + l15];

  asm volatile("" ::: "memory");   // fix VMEM issue order: prologue before pipeline
  ushort4 vrA[4], vrB[4];
  issueK(0); issueV(0, vrA);
  issueK(1); issueV(1, vrB);

  ffrag o[4] = {};
  float mrow[4] = {-3e38f, -3e38f, -3e38f, -3e38f};
  float lrow[4] = {};

  for (int t = 0; t < 16; t++) {
    // K(t) landed in Kf[t%3], V(t) regs arrived; t+1 (and t+2 soon) in flight
    if (t < 15) vwait<6>(); else vwait<0>();
    barL();   // Kf[t%3] visible; all waves past PV(t-1) -> VT writable

    if ((t & 1) == 0) {
      writeVT(vrA);
      if (t < 14) { issueK(t + 2); issueV(t + 2, vrA); }
    } else {
      writeVT(vrB);
      if (t < 14) { issueK(t + 2); issueV(t + 2, vrB); }
    }

    // --- QK^T from Kf[t%3]
    const short* kbuf = Kf + (t % 3) * 4096;
    ffrag s[4] = {};
    #pragma unroll
    for (int kf = 0; kf < 4; kf++) {
      bfrag kf0 = *(const bfrag*)(kbuf + (kf * 2 + 0) * 512 + lane * 8);
      bfrag kf1 = *(const bfrag*)(kbuf + (kf * 2 + 1) * 512 + lane * 8);
      s[kf] = mfma16(qf[0], kf0, s[kf]);
      s[kf] = mfma16(qf[1], kf1, s[kf]);
    }

    // --- bias + online softmax
    fx2 rh2[4];
    #pragma unroll
    for (int r = 0; r < 4; r++)
      rh2[r] = *(const fx2*)&RhS[wq + l4 * 4 + r][2 * t];
    float pm[4] = {-3e38f, -3e38f, -3e38f, -3e38f};
    #pragma unroll
    for (int kf = 0; kf < 4; kf++)
      #pragma unroll
      for (int r = 0; r < 4; r++) {
        float sc = fmaf(s[kf][r], 0.125f, rh2[r][kf >> 1] + rw[r][kf & 1]);
        s[kf][r] = sc;
        pm[r] = fmaxf(pm[r], sc);
      }
    #pragma unroll
    for (int off = 1; off < 16; off <<= 1)
      #pragma unroll
      for (int r = 0; r < 4; r++)
        pm[r] = fmaxf(pm[r], __shfl_xor(pm[r], off));
    float al[4], ps[4] = {0.f, 0.f, 0.f, 0.f};
    #pragma unroll
    for (int r = 0; r < 4; r++) {
      float mnew = fmaxf(mrow[r], pm[r]);
      al[r] = __expf(mrow[r] - mnew);
      mrow[r] = mnew;
    }
    #pragma unroll
    for (int kf = 0; kf < 4; kf++)
      #pragma unroll
      for (int r = 0; r < 4; r++) {
        float p = __expf(s[kf][r] - mrow[r]);
        s[kf][r] = p;
        ps[r] += p;
      }
    #pragma unroll
    for (int off = 1; off < 16; off <<= 1)
      #pragma unroll
      for (int r = 0; r < 4; r++)
        ps[r] += __shfl_xor(ps[r], off);
    #pragma unroll
    for (int r = 0; r < 4; r++)
      lrow[r] = fmaf(lrow[r], al[r], ps[r]);

    // --- P -> bf16 hi/lo (intra-wave LDS rows)
    #pragma unroll
    for (int kf = 0; kf < 4; kf++)
      #pragma unroll
      for (int r = 0; r < 4; r++) {
        ush hi = f2b(s[kf][r]);
        float lo = s[kf][r] - b2f(hi);
        int a = swz(wq + l4 * 4 + r, kf * 32 + 2 * l15);
        *(ush*)(Phb + a) = hi;
        *(ush*)(Plb + a) = f2b(lo);
      }
    #pragma unroll
    for (int df = 0; df < 4; df++)
      #pragma unroll
      for (int r = 0; r < 4; r++)
        o[df][r] *= al[r];

    barL();   // VT writes visible to all waves before PV

    // --- PV
    bfrag ph[2], pl[2];
    #pragma unroll
    for (int kc = 0; kc < 2; kc++) {
      int a = swz(wq + l15, kc * 64 + l4 * 16);
      ph[kc] = *(const bfrag*)(Phb + a);
      pl[kc] = *(const bfrag*)(Plb + a);
    }
    #pragma unroll
    for (int df = 0; df < 4; df++)
      #pragma unroll
      for (int kc = 0; kc < 2; kc++) {
        bfrag vf = *(const bfrag*)(VTb + swz(df * 16 + l15, kc * 64 + l4 * 16));
        o[df] = mfma16(ph[kc], vf, o[df]);
        o[df] = mfma16(pl[kc], vf, o[df]);
      }
  }

  // --- epilogue
  float inv[4];
  #pragma unroll
  for (int r = 0; r < 4; r++) inv[r] = 1.0f / lrow[r];
  #pragma unroll
  for (int df = 0; df < 4; df++)
    #pragma unroll
    for (int r = 0; r < 4; r++) {
      float val = o[df][r] * inv[r];
      int row = q0 + wq + l4 * 4 + r;
      size_t idx = ((size_t)(bb * NTOK + row)) * DIMM + head * HD + df * 16 + l15;
      ush hi = f2b(val);
      o1h[idx] = hi;
      o1l[idx] = f2b(val - b2f(hi));
    }
}

// ---------------------------------------------------------------------------
extern "C" void kernel_launch(void* const* d_in, const int* in_sizes, int n_in,
                              void* d_out, int out_size, void* d_ws, size_t ws_size,
                              hipStream_t stream)
{
  const float* x      = (const float*)d_in[0];
  const float* qkv_w  = (const float*)d_in[1];
  const float* qkv_b  = (const float*)d_in[2];
  const float* proj_w = (const float*)d_in[3];
  const float* proj_b = (const float*)d_in[4];
  const float* rph    = (const float*)d_in[5];
  const float* rpw    = (const float*)d_in[6];

  char* p = (char*)d_ws;
  ush* xh  = (ush*)p; p += 3145728;   // 2048*768*2
  ush* xl  = (ush*)p; p += 3145728;
  ush* wh  = (ush*)p; p += 3538944;   // 2304*768*2
  ush* wl  = (ush*)p; p += 3538944;
  ush* pwh = (ush*)p; p += 1179648;   // 768*768*2
  ush* pwl = (ush*)p; p += 1179648;
  ush* qb  = (ush*)p; p += 3145728;   // 24*1024*64*2
  ush* kb  = (ush*)p; p += 3145728;
  ush* vb  = (ush*)p; p += 3145728;
  float* relh = (float*)p; p += 3145728;   // 24*1024*32*4
  float* relw = (float*)p; p += 3145728;
  ush* o1h = xh;   // xh/xl dead after k_qkv_mfma
  ush* o1l = xl;
  float* out = (float*)d_out;

  k_cvt3<<<dim3(3840), dim3(256), 0, stream>>>(x, qkv_w, proj_w,
                                               xh, xl, wh, wl, pwh, pwl);
  k_qkv_mfma<<<dim3(576), dim3(256), 0, stream>>>(xh, xl, wh, wl, qkv_b, qb, kb, vb);
  k_rel<<<dim3(768), dim3(256), 0, stream>>>(qb, rph, rpw, relh, relw);
  k_attn_mfma<<<dim3(384), dim3(256), 0, stream>>>(qb, kb, vb, relh, relw, o1h, o1l);
  k_proj_mfma<<<dim3(384), dim3(256), 0, stream>>>(o1h, o1l, pwh, pwl, proj_b, out);
}

// Round 6
// 145.244 us; speedup vs baseline: 2.8675x; 1.0397x over previous
//
#include <hip/hip_runtime.h>

typedef float fx4 __attribute__((ext_vector_type(4)));
typedef float fx2 __attribute__((ext_vector_type(2)));
typedef short bfrag __attribute__((ext_vector_type(8)));
typedef float ffrag __attribute__((ext_vector_type(4)));
typedef unsigned short ush;

#define NTOK  1024
#define NHEADS 12
#define HD    64
#define DIMM  768

// ---------------- bf16 helpers (bit-level, RNE) ----------------
__device__ __forceinline__ float b2f(ush u) {
  union { unsigned i; float f; } x; x.i = ((unsigned)u) << 16; return x.f;
}
__device__ __forceinline__ ush f2b(float f) {
  union { float f; unsigned i; } x; x.f = f;
  unsigned r = x.i + 0x7fff + ((x.i >> 16) & 1);
  return (ush)(r >> 16);
}

__device__ __forceinline__ void gload16(const void* g, void* l) {
  __builtin_amdgcn_global_load_lds(
      (const __attribute__((address_space(1))) unsigned*)g,
      (__attribute__((address_space(3))) unsigned*)l, 16, 0, 0);
}

__device__ __forceinline__ ffrag mfma16(bfrag a, bfrag b, ffrag c) {
  return __builtin_amdgcn_mfma_f32_16x16x32_bf16(a, b, c, 0, 0, 0);
}

// counted vmcnt wait (T4). N = outstanding VMEM ops allowed to remain.
template<int N> __device__ __forceinline__ void vwait() {
  if constexpr (N == 0)      asm volatile("s_waitcnt vmcnt(0)" ::: "memory");
  else if constexpr (N == 2) asm volatile("s_waitcnt vmcnt(2)" ::: "memory");
  else if constexpr (N == 4) asm volatile("s_waitcnt vmcnt(4)" ::: "memory");
  else if constexpr (N == 6) asm volatile("s_waitcnt vmcnt(6)" ::: "memory");
  else if constexpr (N == 8) asm volatile("s_waitcnt vmcnt(8)" ::: "memory");
  else                       asm volatile("s_waitcnt vmcnt(12)" ::: "memory");
}
// raw barrier (no vmcnt drain) with compiler memory fences
__device__ __forceinline__ void bar() {
  asm volatile("" ::: "memory");
  __builtin_amdgcn_s_barrier();
  asm volatile("" ::: "memory");
}
// barrier that first drains own LDS ops (for ds_write -> cross-wave read)
__device__ __forceinline__ void barL() {
  asm volatile("s_waitcnt lgkmcnt(0)" ::: "memory");
  __builtin_amdgcn_s_barrier();
  asm volatile("" ::: "memory");
}

// XOR-swizzled byte address within a [rows][128B] LDS tile (G4 fix).
__device__ __forceinline__ int swz(int row, int b) {
  return row * 128 + (b ^ ((row & 7) << 4));
}

// ---------------------------------------------------------------------------
// k_cvt3: fused fp32 -> (hi,lo) bf16 split for x, qkv_w, proj_w in ONE launch.
// ---------------------------------------------------------------------------
__global__ __launch_bounds__(256) void k_cvt3(
    const float* __restrict__ x, const float* __restrict__ w,
    const float* __restrict__ pw,
    ush* __restrict__ xh, ush* __restrict__ xl,
    ush* __restrict__ wh, ush* __restrict__ wl,
    ush* __restrict__ pwh, ush* __restrict__ pwl)
{
  int i = blockIdx.x * 256 + threadIdx.x;
  const float* src; ush *h, *l; int off;
  if (i < 393216)      { src = x;  h = xh;  l = xl;  off = i; }
  else if (i < 835584) { src = w;  h = wh;  l = wl;  off = i - 393216; }
  else                 { src = pw; h = pwh; l = pwl; off = i - 835584; }
  fx4 v = *(const fx4*)(src + (size_t)off * 4);
  ushort4 hh, ll;
  float t;
  hh.x = f2b(v[0]); t = v[0] - b2f(hh.x); ll.x = f2b(t);
  hh.y = f2b(v[1]); t = v[1] - b2f(hh.y); ll.y = f2b(t);
  hh.z = f2b(v[2]); t = v[2] - b2f(hh.z); ll.z = f2b(t);
  hh.w = f2b(v[3]); t = v[3] - b2f(hh.w); ll.w = f2b(t);
  *(ushort4*)(h + (size_t)off * 4) = hh;
  *(ushort4*)(l + (size_t)off * 4) = ll;
}

// ---------------------------------------------------------------------------
// 2-buffer counted-vmcnt bf16x3 NT-GEMM core.
// Wave tile (MR*16) x (NR*16); block tile = 2x2 waves.
// Per K-step: bar -> issue stage(t+1) -> vwait<LPS> (stage t done, t+1 in
// flight across the barrier) -> bar -> step(t). Issue-to-wait distance = one
// full K-step of MFMA+ds_read.
// ---------------------------------------------------------------------------
template<int MR, int NR>
__device__ __forceinline__ void gemm_pipe(
    const ush* __restrict__ Ah, const ush* __restrict__ Al,
    const ush* __restrict__ Bh, const ush* __restrict__ Bl,
    int row0, int col0, int K, short* lds, ffrag (&acc)[MR][NR])
{
  constexpr int F = 4 * (MR + NR);       // 1KB frags per K-tile buffer
  constexpr int LPS = F / 4;             // gload16 per thread per stage
  const int tid = threadIdx.x;
  const int lane = tid & 63, w = tid >> 6;
  const int wr = w >> 1, wc = w & 1;
  const int l15 = lane & 15, l8 = (lane >> 4) * 8;

  auto stage = [&](short* buf, int k0) {
    #pragma unroll
    for (int i = 0; i < LPS; i++) {
      int f = i * 4 + w;                 // section boundaries are mult of 4
      const ush* src;
      if (f < 2 * MR)
        src = Ah + (size_t)(row0 + f * 16 + l15) * K + k0 + l8;
      else if (f < 4 * MR)
        src = Al + (size_t)(row0 + (f - 2 * MR) * 16 + l15) * K + k0 + l8;
      else if (f < 4 * MR + 2 * NR)
        src = Bh + (size_t)(col0 + (f - 4 * MR) * 16 + l15) * K + k0 + l8;
      else
        src = Bl + (size_t)(col0 + (f - 4 * MR - 2 * NR) * 16 + l15) * K + k0 + l8;
      gload16(src, buf + f * 512);
    }
  };

  auto step = [&](const short* buf) {
    bfrag ah[MR], al[MR], bh[NR], bl[NR];
    #pragma unroll
    for (int i = 0; i < MR; i++) {
      ah[i] = *(const bfrag*)(buf + (wr * MR + i) * 512 + lane * 8);
      al[i] = *(const bfrag*)(buf + (2 * MR + wr * MR + i) * 512 + lane * 8);
    }
    #pragma unroll
    for (int j = 0; j < NR; j++) {
      bh[j] = *(const bfrag*)(buf + (4 * MR + wc * NR + j) * 512 + lane * 8);
      bl[j] = *(const bfrag*)(buf + (4 * MR + 2 * NR + wc * NR + j) * 512 + lane * 8);
    }
    #pragma unroll
    for (int i = 0; i < MR; i++)
      #pragma unroll
      for (int j = 0; j < NR; j++) {
        acc[i][j] = mfma16(ah[i], bh[j], acc[i][j]);
        acc[i][j] = mfma16(ah[i], bl[j], acc[i][j]);
        acc[i][j] = mfma16(al[i], bh[j], acc[i][j]);
      }
  };

  const int nt = K / 32;
  stage(lds, 0);
  for (int t = 0; t < nt; t++) {
    bar();                               // all waves done reading victim buf
    if (t + 1 < nt) {
      stage(lds + ((t + 1) & 1) * F * 512, (t + 1) * 32);
      vwait<LPS>();                      // stage(t) landed; t+1 in flight
    } else {
      vwait<0>();
    }
    bar();                               // stage(t) visible to all waves
    step(lds + (t & 1) * F * 512);
  }
}

// ---------------------------------------------------------------------------
// qkv GEMM: M=2048, N=2304, K=768; tile 128x128, wave tile 64x64 (MR=NR=4).
// grid 16x18 = 288 (8x36 XCD-swizzle); LDS 64KB dbuf -> 2 blocks/CU.
// A 128-col tile spans two 64-dim heads: head = base_head + wc.
// ---------------------------------------------------------------------------
__global__ __launch_bounds__(256, 2) void k_qkv_mfma(
    const ush* __restrict__ xh, const ush* __restrict__ xl,
    const ush* __restrict__ wh, const ush* __restrict__ wl,
    const float* __restrict__ bias,
    ush* __restrict__ qo, ush* __restrict__ ko, ush* __restrict__ vo)
{
  __shared__ short lds[2 * 32 * 512];    // 64 KB double buffer
  const int orig = blockIdx.x;
  const int bid = (orig & 7) * 36 + (orig >> 3);   // 288 = 8*36, bijective
  const int bm = bid & 15, bn = bid >> 4;          // 16 M-tiles x 18 N-tiles
  const int row0 = bm * 128, col0 = bn * 128;
  ffrag acc[4][4] = {};
  gemm_pipe<4, 4>(xh, xl, wh, wl, row0, col0, 768, lds, acc);

  const int tid = threadIdx.x, lane = tid & 63, w = tid >> 6;
  const int wr = w >> 1, wc = w & 1;
  const int l15 = lane & 15, l4 = lane >> 4;
  const int which = col0 / 768;                    // uniform per block
  const int base_head = (col0 - which * 768) >> 6;
  const int head = base_head + wc;                 // uniform per wave
  ush* base = which == 0 ? qo : (which == 1 ? ko : vo);
  #pragma unroll
  for (int mi = 0; mi < 4; mi++)
    #pragma unroll
    for (int ni = 0; ni < 4; ni++) {
      int d = ni * 16 + l15;                       // 0..63 within head
      float bv = bias[col0 + wc * 64 + d];
      #pragma unroll
      for (int r = 0; r < 4; r++) {
        int row = row0 + wr * 64 + mi * 16 + l4 * 4 + r;
        int bb = row >> 10, n = row & 1023;
        base[((size_t)(bb * NHEADS + head) * NTOK + n) * HD + d] =
            f2b(acc[mi][ni][r] + bv);
      }
    }
}

// ---------------------------------------------------------------------------
// proj GEMM: M=2048, N=768, K=768; tile 64x64 (MR=NR=2); grid 32x12=384.
// ---------------------------------------------------------------------------
__global__ __launch_bounds__(256) void k_proj_mfma(
    const ush* __restrict__ ah, const ush* __restrict__ al,
    const ush* __restrict__ bh, const ush* __restrict__ bl,
    const float* __restrict__ bias, float* __restrict__ out)
{
  __shared__ short lds[2 * 16 * 512];    // 32 KB double buffer
  const int orig = blockIdx.x;
  const int bid = (orig & 7) * 48 + (orig >> 3);   // 384 = 8*48, bijective
  const int bm = bid & 31, bn = bid >> 5;
  const int row0 = bm * 64, col0 = bn * 64;
  ffrag acc[2][2] = {};
  gemm_pipe<2, 2>(ah, al, bh, bl, row0, col0, 768, lds, acc);

  const int tid = threadIdx.x, lane = tid & 63, w = tid >> 6;
  const int wr = w >> 1, wc = w & 1;
  const int l15 = lane & 15, l4 = lane >> 4;
  #pragma unroll
  for (int mi = 0; mi < 2; mi++)
    #pragma unroll
    for (int ni = 0; ni < 2; ni++) {
      int col = col0 + wc * 32 + ni * 16 + l15;
      float bv = bias[col];
      #pragma unroll
      for (int r = 0; r < 4; r++) {
        int row = row0 + wr * 32 + mi * 16 + l4 * 4 + r;
        out[(size_t)row * 768 + col] = acc[mi][ni][r] + bv;
      }
    }
}

// ---------------------------------------------------------------------------
// Kernel: rel-pos bias precompute (q bf16). Unchanged.
// ---------------------------------------------------------------------------
__global__ __launch_bounds__(256) void k_rel(
    const ush* __restrict__ qT, const float* __restrict__ rph,
    const float* __restrict__ rpw,
    float* __restrict__ relh, float* __restrict__ relw)
{
  __shared__ float Qs[32][68];
  __shared__ float RhS[32][68];
  __shared__ float RwS[63][68];
  const int bid = blockIdx.x;
  const int pair = bid >> 5;
  const int nt = bid & 31;
  const int nbase = nt * 32;
  const ush* qp = qT + (size_t)pair * NTOK * HD + (size_t)nbase * HD;
  const int tid = threadIdx.x;
  #pragma unroll
  for (int ii = 0; ii < 2; ii++) {
    int f = ii * 256 + tid;
    int r = f >> 4, k4 = f & 15;
    ushort4 t = *(const ushort4*)(qp + (size_t)r * HD + k4 * 4);
    Qs[r][k4*4+0] = b2f(t.x); Qs[r][k4*4+1] = b2f(t.y);
    Qs[r][k4*4+2] = b2f(t.z); Qs[r][k4*4+3] = b2f(t.w);
    *(fx4*)&RhS[r][k4*4] = *(const fx4*)(rph + (size_t)(nt + r) * 64 + k4 * 4);
  }
  #pragma unroll
  for (int ii = 0; ii < 4; ii++) {
    int f = ii * 256 + tid;
    if (f < 1008) {
      int r = f >> 4, k4 = f & 15;
      *(fx4*)&RwS[r][k4*4] = *(const fx4*)(rpw + (size_t)r * 64 + k4 * 4);
    }
  }
  __syncthreads();
  const int nl = tid >> 3, rem = tid & 7;
  #pragma unroll
  for (int rep = 0; rep < 8; rep++) {
    int kidx = rep * 8 + rem;
    int hw = kidx >> 5;
    int k = kidx & 31;
    const float* rrow = hw ? &RwS[nl + 31 - k][0] : &RhS[31 - k][0];
    float sum = 0.f;
    #pragma unroll
    for (int c4 = 0; c4 < 16; c4++) {
      fx4 q = *(const fx4*)&Qs[nl][c4*4];
      fx4 rv = *(const fx4*)&rrow[c4*4];
      sum = fmaf(q[0], rv[0], sum);
      sum = fmaf(q[1], rv[1], sum);
      sum = fmaf(q[2], rv[2], sum);
      sum = fmaf(q[3], rv[3], sum);
    }
    float* dst = (hw ? relw : relh) + (size_t)pair * NTOK * 32 + (size_t)(nbase + nl) * 32 + k;
    *dst = sum;
  }
}

// ---------------------------------------------------------------------------
// MFMA flash attention with counted-vmcnt pipeline (unchanged from round 5).
// ---------------------------------------------------------------------------
__global__ __launch_bounds__(256) void k_attn_mfma(
    const ush* __restrict__ qT, const ush* __restrict__ kT,
    const ush* __restrict__ vT,
    const float* __restrict__ relh, const float* __restrict__ relw,
    ush* __restrict__ o1h, ush* __restrict__ o1l)
{
  __shared__ short Kf[3 * 8 * 512]; // 3 K-tile buffers, 8 fragment-linear KB each
  __shared__ char VTb[8192];        // V^T [64 d][64 k] bf16, XOR-swizzled rows
  __shared__ char Phb[8192];        // P hi [64 q][64 k] bf16, swizzled
  __shared__ char Plb[8192];        // P lo
  __shared__ float RhS[64][36];     // relh rows for this q-tile

  const int orig = blockIdx.x;
  const int bid = (orig & 7) * 48 + (orig >> 3);   // 384 = 8 * 48, bijective
  const int pair = bid >> 4;
  const int q0 = (bid & 15) * 64;
  const int bb = pair / NHEADS, head = pair % NHEADS;
  const ush* qp = qT + (size_t)pair * NTOK * HD;
  const ush* kp = kT + (size_t)pair * NTOK * HD;
  const ush* vp = vT + (size_t)pair * NTOK * HD;
  const float* rhp = relh + (size_t)pair * NTOK * 32;
  const float* rwp = relw + (size_t)pair * NTOK * 32;

  const int tid = threadIdx.x;
  const int lane = tid & 63, w = tid >> 6;
  const int l15 = lane & 15, l4 = lane >> 4;
  const int wq = w * 16;
  const int kv = tid & 63, db = tid >> 6;

  auto issueK = [&](int t) {
    const ush* s0 = kp + (size_t)(t * 64 + wq + l15) * HD + l4 * 8;
    short* dst = Kf + (t % 3) * 4096 + (w * 2) * 512;
    gload16(s0, dst);
    gload16(s0 + 32, dst + 512);
  };
  auto issueV = [&](int t, ushort4 (&vr)[4]) {
    #pragma unroll
    for (int j = 0; j < 4; j++)
      vr[j] = *(const ushort4*)(vp + (size_t)(t * 64 + kv) * HD + db * 16 + j * 4);
  };
  auto writeVT = [&](ushort4 (&vr)[4]) {
    #pragma unroll
    for (int j = 0; j < 4; j++) {
      int d0 = db * 16 + j * 4;
      *(ush*)(VTb + swz(d0 + 0, 2 * kv)) = vr[j].x;
      *(ush*)(VTb + swz(d0 + 1, 2 * kv)) = vr[j].y;
      *(ush*)(VTb + swz(d0 + 2, 2 * kv)) = vr[j].z;
      *(ush*)(VTb + swz(d0 + 3, 2 * kv)) = vr[j].w;
    }
  };

  // ---- prologue: block-local data first, then pipeline issues ----
  {
    int row = tid >> 2, seg = tid & 3;
    const float* src = rhp + (size_t)(q0 + row) * 32 + seg * 8;
    *(fx4*)&RhS[row][seg * 8]     = *(const fx4*)src;
    *(fx4*)&RhS[row][seg * 8 + 4] = *(const fx4*)(src + 4);
  }
  bfrag qf[2];
  qf[0] = *(const bfrag*)(qp + (size_t)(q0 + wq + l15) * HD + l4 * 8);
  qf[1] = *(const bfrag*)(qp + (size_t)(q0 + wq + l15) * HD + 32 + l4 * 8);
  float rw[4][2];
  #pragma unroll
  for (int r = 0; r < 4; r++)
    #pragma unroll
    for (int h = 0; h < 2; h++)
      rw[r][h] = rwp[(size_t)(q0 + wq + l4 * 4 + r) * 32 + h * 16 + l15];

  asm volatile("" ::: "memory");   // fix VMEM issue order: prologue before pipeline
  ushort4 vrA[4], vrB[4];
  issueK(0); issueV(0, vrA);
  issueK(1); issueV(1, vrB);

  ffrag o[4] = {};
  float mrow[4] = {-3e38f, -3e38f, -3e38f, -3e38f};
  float lrow[4] = {};

  for (int t = 0; t < 16; t++) {
    // K(t) landed in Kf[t%3], V(t) regs arrived; t+1 (and t+2 soon) in flight
    if (t < 15) vwait<6>(); else vwait<0>();
    barL();   // Kf[t%3] visible; all waves past PV(t-1) -> VT writable

    if ((t & 1) == 0) {
      writeVT(vrA);
      if (t < 14) { issueK(t + 2); issueV(t + 2, vrA); }
    } else {
      writeVT(vrB);
      if (t < 14) { issueK(t + 2); issueV(t + 2, vrB); }
    }

    // --- QK^T from Kf[t%3]
    const short* kbuf = Kf + (t % 3) * 4096;
    ffrag s[4] = {};
    #pragma unroll
    for (int kf = 0; kf < 4; kf++) {
      bfrag kf0 = *(const bfrag*)(kbuf + (kf * 2 + 0) * 512 + lane * 8);
      bfrag kf1 = *(const bfrag*)(kbuf + (kf * 2 + 1) * 512 + lane * 8);
      s[kf] = mfma16(qf[0], kf0, s[kf]);
      s[kf] = mfma16(qf[1], kf1, s[kf]);
    }

    // --- bias + online softmax
    fx2 rh2[4];
    #pragma unroll
    for (int r = 0; r < 4; r++)
      rh2[r] = *(const fx2*)&RhS[wq + l4 * 4 + r][2 * t];
    float pm[4] = {-3e38f, -3e38f, -3e38f, -3e38f};
    #pragma unroll
    for (int kf = 0; kf < 4; kf++)
      #pragma unroll
      for (int r = 0; r < 4; r++) {
        float sc = fmaf(s[kf][r], 0.125f, rh2[r][kf >> 1] + rw[r][kf & 1]);
        s[kf][r] = sc;
        pm[r] = fmaxf(pm[r], sc);
      }
    #pragma unroll
    for (int off = 1; off < 16; off <<= 1)
      #pragma unroll
      for (int r = 0; r < 4; r++)
        pm[r] = fmaxf(pm[r], __shfl_xor(pm[r], off));
    float al[4], ps[4] = {0.f, 0.f, 0.f, 0.f};
    #pragma unroll
    for (int r = 0; r < 4; r++) {
      float mnew = fmaxf(mrow[r], pm[r]);
      al[r] = __expf(mrow[r] - mnew);
      mrow[r] = mnew;
    }
    #pragma unroll
    for (int kf = 0; kf < 4; kf++)
      #pragma unroll
      for (int r = 0; r < 4; r++) {
        float p = __expf(s[kf][r] - mrow[r]);
        s[kf][r] = p;
        ps[r] += p;
      }
    #pragma unroll
    for (int off = 1; off < 16; off <<= 1)
      #pragma unroll
      for (int r = 0; r < 4; r++)
        ps[r] += __shfl_xor(ps[r], off);
    #pragma unroll
    for (int r = 0; r < 4; r++)
      lrow[r] = fmaf(lrow[r], al[r], ps[r]);

    // --- P -> bf16 hi/lo (intra-wave LDS rows)
    #pragma unroll
    for (int kf = 0; kf < 4; kf++)
      #pragma unroll
      for (int r = 0; r < 4; r++) {
        ush hi = f2b(s[kf][r]);
        float lo = s[kf][r] - b2f(hi);
        int a = swz(wq + l4 * 4 + r, kf * 32 + 2 * l15);
        *(ush*)(Phb + a) = hi;
        *(ush*)(Plb + a) = f2b(lo);
      }
    #pragma unroll
    for (int df = 0; df < 4; df++)
      #pragma unroll
      for (int r = 0; r < 4; r++)
        o[df][r] *= al[r];

    barL();   // VT writes visible to all waves before PV

    // --- PV
    bfrag ph[2], pl[2];
    #pragma unroll
    for (int kc = 0; kc < 2; kc++) {
      int a = swz(wq + l15, kc * 64 + l4 * 16);
      ph[kc] = *(const bfrag*)(Phb + a);
      pl[kc] = *(const bfrag*)(Plb + a);
    }
    #pragma unroll
    for (int df = 0; df < 4; df++)
      #pragma unroll
      for (int kc = 0; kc < 2; kc++) {
        bfrag vf = *(const bfrag*)(VTb + swz(df * 16 + l15, kc * 64 + l4 * 16));
        o[df] = mfma16(ph[kc], vf, o[df]);
        o[df] = mfma16(pl[kc], vf, o[df]);
      }
  }

  // --- epilogue
  float inv[4];
  #pragma unroll
  for (int r = 0; r < 4; r++) inv[r] = 1.0f / lrow[r];
  #pragma unroll
  for (int df = 0; df < 4; df++)
    #pragma unroll
    for (int r = 0; r < 4; r++) {
      float val = o[df][r] * inv[r];
      int row = q0 + wq + l4 * 4 + r;
      size_t idx = ((size_t)(bb * NTOK + row)) * DIMM + head * HD + df * 16 + l15;
      ush hi = f2b(val);
      o1h[idx] = hi;
      o1l[idx] = f2b(val - b2f(hi));
    }
}

// ---------------------------------------------------------------------------
extern "C" void kernel_launch(void* const* d_in, const int* in_sizes, int n_in,
                              void* d_out, int out_size, void* d_ws, size_t ws_size,
                              hipStream_t stream)
{
  const float* x      = (const float*)d_in[0];
  const float* qkv_w  = (const float*)d_in[1];
  const float* qkv_b  = (const float*)d_in[2];
  const float* proj_w = (const float*)d_in[3];
  const float* proj_b = (const float*)d_in[4];
  const float* rph    = (const float*)d_in[5];
  const float* rpw    = (const float*)d_in[6];

  char* p = (char*)d_ws;
  ush* xh  = (ush*)p; p += 3145728;   // 2048*768*2
  ush* xl  = (ush*)p; p += 3145728;
  ush* wh  = (ush*)p; p += 3538944;   // 2304*768*2
  ush* wl  = (ush*)p; p += 3538944;
  ush* pwh = (ush*)p; p += 1179648;   // 768*768*2
  ush* pwl = (ush*)p; p += 1179648;
  ush* qb  = (ush*)p; p += 3145728;   // 24*1024*64*2
  ush* kb  = (ush*)p; p += 3145728;
  ush* vb  = (ush*)p; p += 3145728;
  float* relh = (float*)p; p += 3145728;   // 24*1024*32*4
  float* relw = (float*)p; p += 3145728;
  ush* o1h = xh;   // xh/xl dead after k_qkv_mfma
  ush* o1l = xl;
  float* out = (float*)d_out;

  k_cvt3<<<dim3(3840), dim3(256), 0, stream>>>(x, qkv_w, proj_w,
                                               xh, xl, wh, wl, pwh, pwl);
  k_qkv_mfma<<<dim3(288), dim3(256), 0, stream>>>(xh, xl, wh, wl, qkv_b, qb, kb, vb);
  k_rel<<<dim3(768), dim3(256), 0, stream>>>(qb, rph, rpw, relh, relw);
  k_attn_mfma<<<dim3(384), dim3(256), 0, stream>>>(qb, kb, vb, relh, relw, o1h, o1l);
  k_proj_mfma<<<dim3(384), dim3(256), 0, stream>>>(o1h, o1l, pwh, pwl, proj_b, out);
}

// Round 8
// 131.515 us; speedup vs baseline: 3.1669x; 1.1044x over previous
//
#include <hip/hip_runtime.h>

typedef float fx4 __attribute__((ext_vector_type(4)));
typedef float fx2 __attribute__((ext_vector_type(2)));
typedef short bfrag __attribute__((ext_vector_type(8)));
typedef float ffrag __attribute__((ext_vector_type(4)));
typedef unsigned short ush;

#define NTOK  1024
#define NHEADS 12
#define HD    64
#define DIMM  768

// ---------------- bf16 helpers (bit-level, RNE) ----------------
__device__ __forceinline__ float b2f(ush u) {
  union { unsigned i; float f; } x; x.i = ((unsigned)u) << 16; return x.f;
}
__device__ __forceinline__ ush f2b(float f) {
  union { float f; unsigned i; } x; x.f = f;
  unsigned r = x.i + 0x7fff + ((x.i >> 16) & 1);
  return (ush)(r >> 16);
}

__device__ __forceinline__ void gload16(const void* g, void* l) {
  __builtin_amdgcn_global_load_lds(
      (const __attribute__((address_space(1))) unsigned*)g,
      (__attribute__((address_space(3))) unsigned*)l, 16, 0, 0);
}

__device__ __forceinline__ ffrag mfma16(bfrag a, bfrag b, ffrag c) {
  return __builtin_amdgcn_mfma_f32_16x16x32_bf16(a, b, c, 0, 0, 0);
}

// counted vmcnt wait (T4). N = outstanding VMEM ops allowed to remain.
template<int N> __device__ __forceinline__ void vwait() {
  if constexpr (N == 0)      asm volatile("s_waitcnt vmcnt(0)" ::: "memory");
  else if constexpr (N == 2) asm volatile("s_waitcnt vmcnt(2)" ::: "memory");
  else if constexpr (N == 4) asm volatile("s_waitcnt vmcnt(4)" ::: "memory");
  else if constexpr (N == 6) asm volatile("s_waitcnt vmcnt(6)" ::: "memory");
  else if constexpr (N == 8) asm volatile("s_waitcnt vmcnt(8)" ::: "memory");
  else                       asm volatile("s_waitcnt vmcnt(12)" ::: "memory");
}
// raw barrier (no vmcnt drain) with compiler memory fences
__device__ __forceinline__ void bar() {
  asm volatile("" ::: "memory");
  __builtin_amdgcn_s_barrier();
  asm volatile("" ::: "memory");
}
// barrier that first drains own LDS ops (for ds_write -> cross-wave read)
__device__ __forceinline__ void barL() {
  asm volatile("s_waitcnt lgkmcnt(0)" ::: "memory");
  __builtin_amdgcn_s_barrier();
  asm volatile("" ::: "memory");
}

// XOR-swizzled byte address within a [rows][128B] LDS tile (G4 fix).
__device__ __forceinline__ int swz(int row, int b) {
  return row * 128 + (b ^ ((row & 7) << 4));
}

// ---------------------------------------------------------------------------
// k_cvt3: fused fp32 -> (hi,lo) bf16 split for x, qkv_w, proj_w in ONE launch.
// ---------------------------------------------------------------------------
__global__ __launch_bounds__(256) void k_cvt3(
    const float* __restrict__ x, const float* __restrict__ w,
    const float* __restrict__ pw,
    ush* __restrict__ xh, ush* __restrict__ xl,
    ush* __restrict__ wh, ush* __restrict__ wl,
    ush* __restrict__ pwh, ush* __restrict__ pwl)
{
  int i = blockIdx.x * 256 + threadIdx.x;
  const float* src; ush *h, *l; int off;
  if (i < 393216)      { src = x;  h = xh;  l = xl;  off = i; }
  else if (i < 835584) { src = w;  h = wh;  l = wl;  off = i - 393216; }
  else                 { src = pw; h = pwh; l = pwl; off = i - 835584; }
  fx4 v = *(const fx4*)(src + (size_t)off * 4);
  ushort4 hh, ll;
  float t;
  hh.x = f2b(v[0]); t = v[0] - b2f(hh.x); ll.x = f2b(t);
  hh.y = f2b(v[1]); t = v[1] - b2f(hh.y); ll.y = f2b(t);
  hh.z = f2b(v[2]); t = v[2] - b2f(hh.z); ll.z = f2b(t);
  hh.w = f2b(v[3]); t = v[3] - b2f(hh.w); ll.w = f2b(t);
  *(ushort4*)(h + (size_t)off * 4) = hh;
  *(ushort4*)(l + (size_t)off * 4) = ll;
}

// ---------------------------------------------------------------------------
// 2-buffer counted-vmcnt bf16x3 NT-GEMM core (unchanged).
// ---------------------------------------------------------------------------
template<int MR, int NR>
__device__ __forceinline__ void gemm_pipe(
    const ush* __restrict__ Ah, const ush* __restrict__ Al,
    const ush* __restrict__ Bh, const ush* __restrict__ Bl,
    int row0, int col0, int K, short* lds, ffrag (&acc)[MR][NR])
{
  constexpr int F = 4 * (MR + NR);       // 1KB frags per K-tile buffer
  constexpr int LPS = F / 4;             // gload16 per thread per stage
  const int tid = threadIdx.x;
  const int lane = tid & 63, w = tid >> 6;
  const int wr = w >> 1, wc = w & 1;
  const int l15 = lane & 15, l8 = (lane >> 4) * 8;

  auto stage = [&](short* buf, int k0) {
    #pragma unroll
    for (int i = 0; i < LPS; i++) {
      int f = i * 4 + w;
      const ush* src;
      if (f < 2 * MR)
        src = Ah + (size_t)(row0 + f * 16 + l15) * K + k0 + l8;
      else if (f < 4 * MR)
        src = Al + (size_t)(row0 + (f - 2 * MR) * 16 + l15) * K + k0 + l8;
      else if (f < 4 * MR + 2 * NR)
        src = Bh + (size_t)(col0 + (f - 4 * MR) * 16 + l15) * K + k0 + l8;
      else
        src = Bl + (size_t)(col0 + (f - 4 * MR - 2 * NR) * 16 + l15) * K + k0 + l8;
      gload16(src, buf + f * 512);
    }
  };

  auto step = [&](const short* buf) {
    bfrag ah[MR], al[MR], bh[NR], bl[NR];
    #pragma unroll
    for (int i = 0; i < MR; i++) {
      ah[i] = *(const bfrag*)(buf + (wr * MR + i) * 512 + lane * 8);
      al[i] = *(const bfrag*)(buf + (2 * MR + wr * MR + i) * 512 + lane * 8);
    }
    #pragma unroll
    for (int j = 0; j < NR; j++) {
      bh[j] = *(const bfrag*)(buf + (4 * MR + wc * NR + j) * 512 + lane * 8);
      bl[j] = *(const bfrag*)(buf + (4 * MR + 2 * NR + wc * NR + j) * 512 + lane * 8);
    }
    #pragma unroll
    for (int i = 0; i < MR; i++)
      #pragma unroll
      for (int j = 0; j < NR; j++) {
        acc[i][j] = mfma16(ah[i], bh[j], acc[i][j]);
        acc[i][j] = mfma16(ah[i], bl[j], acc[i][j]);
        acc[i][j] = mfma16(al[i], bh[j], acc[i][j]);
      }
  };

  const int nt = K / 32;
  stage(lds, 0);
  for (int t = 0; t < nt; t++) {
    bar();
    if (t + 1 < nt) {
      stage(lds + ((t + 1) & 1) * F * 512, (t + 1) * 32);
      vwait<LPS>();
    } else {
      vwait<0>();
    }
    bar();
    step(lds + (t & 1) * F * 512);
  }
}

// ---------------------------------------------------------------------------
// qkv GEMM: tile 128x128, wave tile 64x64; grid 288 (8x36 XCD-swizzle).
// ---------------------------------------------------------------------------
__global__ __launch_bounds__(256, 2) void k_qkv_mfma(
    const ush* __restrict__ xh, const ush* __restrict__ xl,
    const ush* __restrict__ wh, const ush* __restrict__ wl,
    const float* __restrict__ bias,
    ush* __restrict__ qo, ush* __restrict__ ko, ush* __restrict__ vo)
{
  __shared__ short lds[2 * 32 * 512];    // 64 KB double buffer
  const int orig = blockIdx.x;
  const int bid = (orig & 7) * 36 + (orig >> 3);   // 288 = 8*36, bijective
  const int bm = bid & 15, bn = bid >> 4;
  const int row0 = bm * 128, col0 = bn * 128;
  ffrag acc[4][4] = {};
  gemm_pipe<4, 4>(xh, xl, wh, wl, row0, col0, 768, lds, acc);

  const int tid = threadIdx.x, lane = tid & 63, w = tid >> 6;
  const int wr = w >> 1, wc = w & 1;
  const int l15 = lane & 15, l4 = lane >> 4;
  const int which = col0 / 768;
  const int base_head = (col0 - which * 768) >> 6;
  const int head = base_head + wc;
  ush* base = which == 0 ? qo : (which == 1 ? ko : vo);
  #pragma unroll
  for (int mi = 0; mi < 4; mi++)
    #pragma unroll
    for (int ni = 0; ni < 4; ni++) {
      int d = ni * 16 + l15;
      float bv = bias[col0 + wc * 64 + d];
      #pragma unroll
      for (int r = 0; r < 4; r++) {
        int row = row0 + wr * 64 + mi * 16 + l4 * 4 + r;
        int bb = row >> 10, n = row & 1023;
        base[((size_t)(bb * NHEADS + head) * NTOK + n) * HD + d] =
            f2b(acc[mi][ni][r] + bv);
      }
    }
}

// ---------------------------------------------------------------------------
// proj GEMM: tile 64x64; grid 384 (8x48 XCD-swizzle).
// ---------------------------------------------------------------------------
__global__ __launch_bounds__(256) void k_proj_mfma(
    const ush* __restrict__ ah, const ush* __restrict__ al,
    const ush* __restrict__ bh, const ush* __restrict__ bl,
    const float* __restrict__ bias, float* __restrict__ out)
{
  __shared__ short lds[2 * 16 * 512];    // 32 KB double buffer
  const int orig = blockIdx.x;
  const int bid = (orig & 7) * 48 + (orig >> 3);
  const int bm = bid & 31, bn = bid >> 5;
  const int row0 = bm * 64, col0 = bn * 64;
  ffrag acc[2][2] = {};
  gemm_pipe<2, 2>(ah, al, bh, bl, row0, col0, 768, lds, acc);

  const int tid = threadIdx.x, lane = tid & 63, w = tid >> 6;
  const int wr = w >> 1, wc = w & 1;
  const int l15 = lane & 15, l4 = lane >> 4;
  #pragma unroll
  for (int mi = 0; mi < 2; mi++)
    #pragma unroll
    for (int ni = 0; ni < 2; ni++) {
      int col = col0 + wc * 32 + ni * 16 + l15;
      float bv = bias[col];
      #pragma unroll
      for (int r = 0; r < 4; r++) {
        int row = row0 + wr * 32 + mi * 16 + l4 * 4 + r;
        out[(size_t)row * 768 + col] = acc[mi][ni][r] + bv;
      }
    }
}

// ---------------------------------------------------------------------------
// Kernel: rel-pos bias precompute (q bf16). Unchanged.
// ---------------------------------------------------------------------------
__global__ __launch_bounds__(256) void k_rel(
    const ush* __restrict__ qT, const float* __restrict__ rph,
    const float* __restrict__ rpw,
    float* __restrict__ relh, float* __restrict__ relw)
{
  __shared__ float Qs[32][68];
  __shared__ float RhS[32][68];
  __shared__ float RwS[63][68];
  const int bid = blockIdx.x;
  const int pair = bid >> 5;
  const int nt = bid & 31;
  const int nbase = nt * 32;
  const ush* qp = qT + (size_t)pair * NTOK * HD + (size_t)nbase * HD;
  const int tid = threadIdx.x;
  #pragma unroll
  for (int ii = 0; ii < 2; ii++) {
    int f = ii * 256 + tid;
    int r = f >> 4, k4 = f & 15;
    ushort4 t = *(const ushort4*)(qp + (size_t)r * HD + k4 * 4);
    Qs[r][k4*4+0] = b2f(t.x); Qs[r][k4*4+1] = b2f(t.y);
    Qs[r][k4*4+2] = b2f(t.z); Qs[r][k4*4+3] = b2f(t.w);
    *(fx4*)&RhS[r][k4*4] = *(const fx4*)(rph + (size_t)(nt + r) * 64 + k4 * 4);
  }
  #pragma unroll
  for (int ii = 0; ii < 4; ii++) {
    int f = ii * 256 + tid;
    if (f < 1008) {
      int r = f >> 4, k4 = f & 15;
      *(fx4*)&RwS[r][k4*4] = *(const fx4*)(rpw + (size_t)r * 64 + k4 * 4);
    }
  }
  __syncthreads();
  const int nl = tid >> 3, rem = tid & 7;
  #pragma unroll
  for (int rep = 0; rep < 8; rep++) {
    int kidx = rep * 8 + rem;
    int hw = kidx >> 5;
    int k = kidx & 31;
    const float* rrow = hw ? &RwS[nl + 31 - k][0] : &RhS[31 - k][0];
    float sum = 0.f;
    #pragma unroll
    for (int c4 = 0; c4 < 16; c4++) {
      fx4 q = *(const fx4*)&Qs[nl][c4*4];
      fx4 rv = *(const fx4*)&rrow[c4*4];
      sum = fmaf(q[0], rv[0], sum);
      sum = fmaf(q[1], rv[1], sum);
      sum = fmaf(q[2], rv[2], sum);
      sum = fmaf(q[3], rv[3], sum);
    }
    float* dst = (hw ? relw : relh) + (size_t)pair * NTOK * 32 + (size_t)(nbase + nl) * 32 + k;
    *dst = sum;
  }
}

// ---------------------------------------------------------------------------
// MFMA flash attention, SPLIT-KV (2 blocks per (pair,q-tile), 8 tiles each).
// Writes unnormalized partial O (bf16 hi/lo) + per-row (m,l) to workspace.
// grid = 768 blocks; LDS 49KB -> 3 blocks/CU; entire grid co-resident.
// ---------------------------------------------------------------------------
__global__ __launch_bounds__(256, 3) void k_attn_mfma(
    const ush* __restrict__ qT, const ush* __restrict__ kT,
    const ush* __restrict__ vT,
    const float* __restrict__ relh, const float* __restrict__ relw,
    ush* __restrict__ oph, ush* __restrict__ opl, float* __restrict__ ml)
{
  __shared__ short Kf[2 * 8 * 512]; // double-buffered K tiles (8KB each)
  __shared__ char VTb[8192];        // V^T [64 d][64 k] bf16, XOR-swizzled rows
  __shared__ char Phb[8192];        // P hi [64 q][64 k] bf16, swizzled
  __shared__ char Plb[8192];        // P lo
  __shared__ float RhS[64][36];     // relh rows for this q-tile

  const int orig = blockIdx.x;
  const int bid = (orig & 7) * 96 + (orig >> 3);   // 768 = 8*96, bijective
  const int ks   = bid & 1;                        // KV half
  const int qt   = (bid >> 1) & 15;
  const int pair = bid >> 5;
  const int q0 = qt * 64;
  const ush* qp = qT + (size_t)pair * NTOK * HD;
  const ush* kp = kT + (size_t)pair * NTOK * HD;
  const ush* vp = vT + (size_t)pair * NTOK * HD;
  const float* rhp = relh + (size_t)pair * NTOK * 32;
  const float* rwp = relw + (size_t)pair * NTOK * 32;

  const int tid = threadIdx.x;
  const int lane = tid & 63, w = tid >> 6;
  const int l15 = lane & 15, l4 = lane >> 4;
  const int wq = w * 16;
  const int kv = tid & 63, db = tid >> 6;

  auto issueK = [&](int tt) {
    const int gt = ks * 8 + tt;
    const ush* s0 = kp + (size_t)(gt * 64 + wq + l15) * HD + l4 * 8;
    short* dst = Kf + (tt & 1) * 4096 + (w * 2) * 512;
    gload16(s0, dst);
    gload16(s0 + 32, dst + 512);
  };
  auto issueV = [&](int tt, ushort4 (&vr)[4]) {
    const int gt = ks * 8 + tt;
    #pragma unroll
    for (int j = 0; j < 4; j++)
      vr[j] = *(const ushort4*)(vp + (size_t)(gt * 64 + kv) * HD + db * 16 + j * 4);
  };
  auto writeVT = [&](ushort4 (&vr)[4]) {
    #pragma unroll
    for (int j = 0; j < 4; j++) {
      int d0 = db * 16 + j * 4;
      *(ush*)(VTb + swz(d0 + 0, 2 * kv)) = vr[j].x;
      *(ush*)(VTb + swz(d0 + 1, 2 * kv)) = vr[j].y;
      *(ush*)(VTb + swz(d0 + 2, 2 * kv)) = vr[j].z;
      *(ush*)(VTb + swz(d0 + 3, 2 * kv)) = vr[j].w;
    }
  };

  // ---- prologue ----
  {
    int row = tid >> 2, seg = tid & 3;
    const float* src = rhp + (size_t)(q0 + row) * 32 + seg * 8;
    *(fx4*)&RhS[row][seg * 8]     = *(const fx4*)src;
    *(fx4*)&RhS[row][seg * 8 + 4] = *(const fx4*)(src + 4);
  }
  bfrag qf[2];
  qf[0] = *(const bfrag*)(qp + (size_t)(q0 + wq + l15) * HD + l4 * 8);
  qf[1] = *(const bfrag*)(qp + (size_t)(q0 + wq + l15) * HD + 32 + l4 * 8);
  float rw[4][2];
  #pragma unroll
  for (int r = 0; r < 4; r++)
    #pragma unroll
    for (int h = 0; h < 2; h++)
      rw[r][h] = rwp[(size_t)(q0 + wq + l4 * 4 + r) * 32 + h * 16 + l15];

  asm volatile("" ::: "memory");
  ushort4 vrA[4], vrB[4];
  issueK(0); issueV(0, vrA); issueV(1, vrB);

  ffrag o[4] = {};
  float mrow[4] = {-3e38f, -3e38f, -3e38f, -3e38f};
  float lrow[4] = {};

  for (int tt = 0; tt < 8; tt++) {
    const int t = ks * 8 + tt;                 // global tile index (for bias)
    if (tt < 7) vwait<4>(); else vwait<0>();
    barL();   // K(tt) visible; all waves finished iteration tt-1 entirely

    if ((tt & 1) == 0) {
      writeVT(vrA);
      if (tt < 7) issueK(tt + 1);
      if (tt < 6) issueV(tt + 2, vrA);
    } else {
      writeVT(vrB);
      if (tt < 7) issueK(tt + 1);
      if (tt < 6) issueV(tt + 2, vrB);
    }

    // --- QK^T from Kf[tt&1]
    const short* kbuf = Kf + (tt & 1) * 4096;
    ffrag s[4] = {};
    #pragma unroll
    for (int kf = 0; kf < 4; kf++) {
      bfrag kf0 = *(const bfrag*)(kbuf + (kf * 2 + 0) * 512 + lane * 8);
      bfrag kf1 = *(const bfrag*)(kbuf + (kf * 2 + 1) * 512 + lane * 8);
      s[kf] = mfma16(qf[0], kf0, s[kf]);
      s[kf] = mfma16(qf[1], kf1, s[kf]);
    }

    // --- bias + online softmax
    fx2 rh2[4];
    #pragma unroll
    for (int r = 0; r < 4; r++)
      rh2[r] = *(const fx2*)&RhS[wq + l4 * 4 + r][2 * t];
    float pm[4] = {-3e38f, -3e38f, -3e38f, -3e38f};
    #pragma unroll
    for (int kf = 0; kf < 4; kf++)
      #pragma unroll
      for (int r = 0; r < 4; r++) {
        float sc = fmaf(s[kf][r], 0.125f, rh2[r][kf >> 1] + rw[r][kf & 1]);
        s[kf][r] = sc;
        pm[r] = fmaxf(pm[r], sc);
      }
    #pragma unroll
    for (int off = 1; off < 16; off <<= 1)
      #pragma unroll
      for (int r = 0; r < 4; r++)
        pm[r] = fmaxf(pm[r], __shfl_xor(pm[r], off));
    float al[4], ps[4] = {0.f, 0.f, 0.f, 0.f};
    #pragma unroll
    for (int r = 0; r < 4; r++) {
      float mnew = fmaxf(mrow[r], pm[r]);
      al[r] = __expf(mrow[r] - mnew);
      mrow[r] = mnew;
    }
    #pragma unroll
    for (int kf = 0; kf < 4; kf++)
      #pragma unroll
      for (int r = 0; r < 4; r++) {
        float p = __expf(s[kf][r] - mrow[r]);
        s[kf][r] = p;
        ps[r] += p;
      }
    #pragma unroll
    for (int off = 1; off < 16; off <<= 1)
      #pragma unroll
      for (int r = 0; r < 4; r++)
        ps[r] += __shfl_xor(ps[r], off);
    #pragma unroll
    for (int r = 0; r < 4; r++)
      lrow[r] = fmaf(lrow[r], al[r], ps[r]);

    // --- P -> bf16 hi/lo
    #pragma unroll
    for (int kf = 0; kf < 4; kf++)
      #pragma unroll
      for (int r = 0; r < 4; r++) {
        ush hi = f2b(s[kf][r]);
        float lo = s[kf][r] - b2f(hi);
        int a = swz(wq + l4 * 4 + r, kf * 32 + 2 * l15);
        *(ush*)(Phb + a) = hi;
        *(ush*)(Plb + a) = f2b(lo);
      }
    #pragma unroll
    for (int df = 0; df < 4; df++)
      #pragma unroll
      for (int r = 0; r < 4; r++)
        o[df][r] *= al[r];

    barL();   // VT + P writes visible before PV

    // --- PV
    bfrag ph[2], pl[2];
    #pragma unroll
    for (int kc = 0; kc < 2; kc++) {
      int a = swz(wq + l15, kc * 64 + l4 * 16);
      ph[kc] = *(const bfrag*)(Phb + a);
      pl[kc] = *(const bfrag*)(Plb + a);
    }
    #pragma unroll
    for (int df = 0; df < 4; df++)
      #pragma unroll
      for (int kc = 0; kc < 2; kc++) {
        bfrag vf = *(const bfrag*)(VTb + swz(df * 16 + l15, kc * 64 + l4 * 16));
        o[df] = mfma16(ph[kc], vf, o[df]);
        o[df] = mfma16(pl[kc], vf, o[df]);
      }
  }

  // --- epilogue: write UNNORMALIZED partial o + (m,l)
  const int part = ((pair << 4) | qt) * 2 + ks;
  if (l15 == 0) {
    float* mlp = ml + (size_t)part * 128;
    #pragma unroll
    for (int r = 0; r < 4; r++) {
      int row = wq + l4 * 4 + r;
      mlp[row] = mrow[r];
      mlp[64 + row] = lrow[r];
    }
  }
  const size_t pbase = (size_t)part * 4096;
  #pragma unroll
  for (int df = 0; df < 4; df++)
    #pragma unroll
    for (int r = 0; r < 4; r++) {
      float val = o[df][r];
      int row = wq + l4 * 4 + r;
      size_t idx = pbase + (size_t)row * 64 + df * 16 + l15;
      ush hi = f2b(val);
      oph[idx] = hi;
      opl[idx] = f2b(val - b2f(hi));
    }
}

// ---------------------------------------------------------------------------
// Merge the two KV-halves: standard online-softmax combine, write o1 hi/lo.
// grid = 384 blocks of 256 threads; ushort4-vectorized.
// ---------------------------------------------------------------------------
__global__ __launch_bounds__(256) void k_attn_merge(
    const ush* __restrict__ oph, const ush* __restrict__ opl,
    const float* __restrict__ ml,
    ush* __restrict__ o1h, ush* __restrict__ o1l)
{
  const int pq = blockIdx.x;              // (pair, qtile)
  const int pair = pq >> 4, qt = pq & 15;
  const int bb = pair / NHEADS, head = pair % NHEADS;
  __shared__ float M0[64], L0[64], M1[64], L1[64];
  const int tid = threadIdx.x;
  const float* mlp = ml + (size_t)pq * 256;
  if (tid < 64) {
    M0[tid] = mlp[tid];        L0[tid] = mlp[64 + tid];
    M1[tid] = mlp[128 + tid];  L1[tid] = mlp[192 + tid];
  }
  __syncthreads();
  const size_t b0 = (size_t)(pq * 2) * 4096;
  const size_t b1 = b0 + 4096;
  #pragma unroll
  for (int e = 0; e < 4; e++) {
    int q4 = e * 256 + tid;               // ushort4 index within 64x64 tile
    int row = q4 >> 4;
    int d4 = (q4 & 15) * 4;
    float m0 = M0[row], l0v = L0[row], m1 = M1[row], l1v = L1[row];
    float m = fmaxf(m0, m1);
    float a0 = __expf(m0 - m), a1 = __expf(m1 - m);
    float inv = 1.0f / (l0v * a0 + l1v * a1);
    ushort4 h0 = *(const ushort4*)(oph + b0 + (size_t)q4 * 4);
    ushort4 g0 = *(const ushort4*)(opl + b0 + (size_t)q4 * 4);
    ushort4 h1 = *(const ushort4*)(oph + b1 + (size_t)q4 * 4);
    ushort4 g1 = *(const ushort4*)(opl + b1 + (size_t)q4 * 4);
    float v0 = ((b2f(h0.x)+b2f(g0.x))*a0 + (b2f(h1.x)+b2f(g1.x))*a1) * inv;
    float v1 = ((b2f(h0.y)+b2f(g0.y))*a0 + (b2f(h1.y)+b2f(g1.y))*a1) * inv;
    float v2 = ((b2f(h0.z)+b2f(g0.z))*a0 + (b2f(h1.z)+b2f(g1.z))*a1) * inv;
    float v3 = ((b2f(h0.w)+b2f(g0.w))*a0 + (b2f(h1.w)+b2f(g1.w))*a1) * inv;
    size_t gidx = ((size_t)(bb * NTOK + qt * 64 + row)) * DIMM + head * HD + d4;
    ushort4 oh, ol;
    oh.x = f2b(v0); ol.x = f2b(v0 - b2f(oh.x));
    oh.y = f2b(v1); ol.y = f2b(v1 - b2f(oh.y));
    oh.z = f2b(v2); ol.z = f2b(v2 - b2f(oh.z));
    oh.w = f2b(v3); ol.w = f2b(v3 - b2f(oh.w));
    *(ushort4*)(o1h + gidx) = oh;
    *(ushort4*)(o1l + gidx) = ol;
  }
}

// ---------------------------------------------------------------------------
extern "C" void kernel_launch(void* const* d_in, const int* in_sizes, int n_in,
                              void* d_out, int out_size, void* d_ws, size_t ws_size,
                              hipStream_t stream)
{
  const float* x      = (const float*)d_in[0];
  const float* qkv_w  = (const float*)d_in[1];
  const float* qkv_b  = (const float*)d_in[2];
  const float* proj_w = (const float*)d_in[3];
  const float* proj_b = (const float*)d_in[4];
  const float* rph    = (const float*)d_in[5];
  const float* rpw    = (const float*)d_in[6];

  char* p = (char*)d_ws;
  ush* xh  = (ush*)p; p += 3145728;   // 2048*768*2   (xh+xl contiguous)
  ush* xl  = (ush*)p; p += 3145728;
  ush* wh  = (ush*)p; p += 3538944;   // 2304*768*2   (wh+wl contiguous)
  ush* wl  = (ush*)p; p += 3538944;
  ush* pwh = (ush*)p; p += 1179648;   // 768*768*2
  ush* pwl = (ush*)p; p += 1179648;
  ush* qb  = (ush*)p; p += 3145728;   // 24*1024*64*2
  ush* kb  = (ush*)p; p += 3145728;
  ush* vb  = (ush*)p; p += 3145728;
  float* relh = (float*)p; p += 3145728;   // 24*1024*32*4
  float* relw = (float*)p; p += 3145728;
  float* ml   = (float*)p; p += 393216;    // 768*128*4
  // Partial O needs 768*4096 = 3,145,728 ush PER buffer (6.29 MB).
  // (Round-7 bug: oph=wh alone is only 1.77M ush -> overflow into opl.)
  // Fix: oph spans xh+xl (exactly 3,145,728 ush); opl spans wh+wl (3.54M ush).
  // All four are dead after k_qkv_mfma.
  ush* oph = xh;
  ush* opl = wh;
  // Merge output overlays qb/kb (dead after k_attn_mfma; exact fit).
  ush* o1h = qb;
  ush* o1l = kb;
  float* out = (float*)d_out;

  k_cvt3<<<dim3(3840), dim3(256), 0, stream>>>(x, qkv_w, proj_w,
                                               xh, xl, wh, wl, pwh, pwl);
  k_qkv_mfma<<<dim3(288), dim3(256), 0, stream>>>(xh, xl, wh, wl, qkv_b, qb, kb, vb);
  k_rel<<<dim3(768), dim3(256), 0, stream>>>(qb, rph, rpw, relh, relw);
  k_attn_mfma<<<dim3(768), dim3(256), 0, stream>>>(qb, kb, vb, relh, relw, oph, opl, ml);
  k_attn_merge<<<dim3(384), dim3(256), 0, stream>>>(oph, opl, ml, o1h, o1l);
  k_proj_mfma<<<dim3(384), dim3(256), 0, stream>>>(o1h, o1l, pwh, pwl, proj_b, out);
}

// Round 9
// 129.328 us; speedup vs baseline: 3.2204x; 1.0169x over previous
//
#include <hip/hip_runtime.h>

typedef float fx4 __attribute__((ext_vector_type(4)));
typedef float fx2 __attribute__((ext_vector_type(2)));
typedef short bfrag __attribute__((ext_vector_type(8)));
typedef float ffrag __attribute__((ext_vector_type(4)));
typedef unsigned short ush;

#define NTOK  1024
#define NHEADS 12
#define HD    64
#define DIMM  768

// ---------------- bf16 helpers (bit-level, RNE) ----------------
__device__ __forceinline__ float b2f(ush u) {
  union { unsigned i; float f; } x; x.i = ((unsigned)u) << 16; return x.f;
}
__device__ __forceinline__ ush f2b(float f) {
  union { float f; unsigned i; } x; x.f = f;
  unsigned r = x.i + 0x7fff + ((x.i >> 16) & 1);
  return (ush)(r >> 16);
}

__device__ __forceinline__ void gload16(const void* g, void* l) {
  __builtin_amdgcn_global_load_lds(
      (const __attribute__((address_space(1))) unsigned*)g,
      (__attribute__((address_space(3))) unsigned*)l, 16, 0, 0);
}

__device__ __forceinline__ ffrag mfma16(bfrag a, bfrag b, ffrag c) {
  return __builtin_amdgcn_mfma_f32_16x16x32_bf16(a, b, c, 0, 0, 0);
}

// counted vmcnt wait (T4). N = outstanding VMEM ops allowed to remain.
template<int N> __device__ __forceinline__ void vwait() {
  if constexpr (N == 0)      asm volatile("s_waitcnt vmcnt(0)" ::: "memory");
  else if constexpr (N == 1) asm volatile("s_waitcnt vmcnt(1)" ::: "memory");
  else if constexpr (N == 2) asm volatile("s_waitcnt vmcnt(2)" ::: "memory");
  else if constexpr (N == 3) asm volatile("s_waitcnt vmcnt(3)" ::: "memory");
  else if constexpr (N == 4) asm volatile("s_waitcnt vmcnt(4)" ::: "memory");
  else if constexpr (N == 6) asm volatile("s_waitcnt vmcnt(6)" ::: "memory");
  else if constexpr (N == 8) asm volatile("s_waitcnt vmcnt(8)" ::: "memory");
  else                       asm volatile("s_waitcnt vmcnt(12)" ::: "memory");
}
// raw barrier (no vmcnt drain) with compiler memory fences
__device__ __forceinline__ void bar() {
  asm volatile("" ::: "memory");
  __builtin_amdgcn_s_barrier();
  asm volatile("" ::: "memory");
}
// barrier that first drains own LDS ops (for ds_write -> cross-wave read)
__device__ __forceinline__ void barL() {
  asm volatile("s_waitcnt lgkmcnt(0)" ::: "memory");
  __builtin_amdgcn_s_barrier();
  asm volatile("" ::: "memory");
}

// XOR-swizzled byte address within a [rows][128B] LDS tile (G4 fix).
__device__ __forceinline__ int swz(int row, int b) {
  return row * 128 + (b ^ ((row & 7) << 4));
}

// ---------------------------------------------------------------------------
// k_cvt3: fused fp32 -> (hi,lo) bf16 split for x, qkv_w, proj_w in ONE launch.
// ---------------------------------------------------------------------------
__global__ __launch_bounds__(256) void k_cvt3(
    const float* __restrict__ x, const float* __restrict__ w,
    const float* __restrict__ pw,
    ush* __restrict__ xh, ush* __restrict__ xl,
    ush* __restrict__ wh, ush* __restrict__ wl,
    ush* __restrict__ pwh, ush* __restrict__ pwl)
{
  int i = blockIdx.x * 256 + threadIdx.x;
  const float* src; ush *h, *l; int off;
  if (i < 393216)      { src = x;  h = xh;  l = xl;  off = i; }
  else if (i < 835584) { src = w;  h = wh;  l = wl;  off = i - 393216; }
  else                 { src = pw; h = pwh; l = pwl; off = i - 835584; }
  fx4 v = *(const fx4*)(src + (size_t)off * 4);
  ushort4 hh, ll;
  float t;
  hh.x = f2b(v[0]); t = v[0] - b2f(hh.x); ll.x = f2b(t);
  hh.y = f2b(v[1]); t = v[1] - b2f(hh.y); ll.y = f2b(t);
  hh.z = f2b(v[2]); t = v[2] - b2f(hh.z); ll.z = f2b(t);
  hh.w = f2b(v[3]); t = v[3] - b2f(hh.w); ll.w = f2b(t);
  *(ushort4*)(h + (size_t)off * 4) = hh;
  *(ushort4*)(l + (size_t)off * 4) = ll;
}

// ---------------------------------------------------------------------------
// 2-buffer counted-vmcnt bf16 NT-GEMM core.
// NTERM=3: C = Ah.Bh + Ah.Bl + Al.Bh  (full split precision, ~2^-16)
// NTERM=2: C = Ah.Bh + Al.Bh          (= A.Bh; B rounded to bf16, ~2^-9)
// Wave tile (MR*16) x (NR*16); block = 2x2 waves.
// ---------------------------------------------------------------------------
template<int MR, int NR, int NTERM>
__device__ __forceinline__ void gemm_pipe(
    const ush* __restrict__ Ah, const ush* __restrict__ Al,
    const ush* __restrict__ Bh, const ush* __restrict__ Bl,
    int row0, int col0, int K, short* lds, ffrag (&acc)[MR][NR])
{
  constexpr int F = (NTERM == 3) ? 4 * (MR + NR) : (4 * MR + 2 * NR);
  constexpr int LPS = F / 4;             // gload16 per thread per stage
  static_assert(F % 4 == 0, "frag count must be divisible by wave count");
  const int tid = threadIdx.x;
  const int lane = tid & 63, w = tid >> 6;
  const int wr = w >> 1, wc = w & 1;
  const int l15 = lane & 15, l8 = (lane >> 4) * 8;

  auto stage = [&](short* buf, int k0) {
    #pragma unroll
    for (int i = 0; i < LPS; i++) {
      int f = i * 4 + w;
      const ush* src;
      if (f < 2 * MR)
        src = Ah + (size_t)(row0 + f * 16 + l15) * K + k0 + l8;
      else if (f < 4 * MR)
        src = Al + (size_t)(row0 + (f - 2 * MR) * 16 + l15) * K + k0 + l8;
      else if (f < 4 * MR + 2 * NR)
        src = Bh + (size_t)(col0 + (f - 4 * MR) * 16 + l15) * K + k0 + l8;
      else
        src = Bl + (size_t)(col0 + (f - 4 * MR - 2 * NR) * 16 + l15) * K + k0 + l8;
      gload16(src, buf + f * 512);
    }
  };

  auto step = [&](const short* buf) {
    bfrag ah[MR], al[MR], bh[NR];
    #pragma unroll
    for (int i = 0; i < MR; i++) {
      ah[i] = *(const bfrag*)(buf + (wr * MR + i) * 512 + lane * 8);
      al[i] = *(const bfrag*)(buf + (2 * MR + wr * MR + i) * 512 + lane * 8);
    }
    #pragma unroll
    for (int j = 0; j < NR; j++)
      bh[j] = *(const bfrag*)(buf + (4 * MR + wc * NR + j) * 512 + lane * 8);
    if constexpr (NTERM == 3) {
      bfrag bl[NR];
      #pragma unroll
      for (int j = 0; j < NR; j++)
        bl[j] = *(const bfrag*)(buf + (4 * MR + 2 * NR + wc * NR + j) * 512 + lane * 8);
      #pragma unroll
      for (int i = 0; i < MR; i++)
        #pragma unroll
        for (int j = 0; j < NR; j++) {
          acc[i][j] = mfma16(ah[i], bh[j], acc[i][j]);
          acc[i][j] = mfma16(ah[i], bl[j], acc[i][j]);
          acc[i][j] = mfma16(al[i], bh[j], acc[i][j]);
        }
    } else {
      #pragma unroll
      for (int i = 0; i < MR; i++)
        #pragma unroll
        for (int j = 0; j < NR; j++) {
          acc[i][j] = mfma16(ah[i], bh[j], acc[i][j]);
          acc[i][j] = mfma16(al[i], bh[j], acc[i][j]);
        }
    }
  };

  const int nt = K / 32;
  stage(lds, 0);
  for (int t = 0; t < nt; t++) {
    bar();
    if (t + 1 < nt) {
      stage(lds + ((t + 1) & 1) * F * 512, (t + 1) * 32);
      vwait<LPS>();
    } else {
      vwait<0>();
    }
    bar();
    step(lds + (t & 1) * F * 512);
  }
}

// ---------------------------------------------------------------------------
// qkv GEMM: M=2048, N=2304, K=768; tile 64x64 (wave 32x32), 2-TERM
// (outputs round to bf16 anyway -> A.Bh precision suffices).
// grid 32x36 = 1152 (8x144 XCD-swizzle); LDS 24KB dbuf -> 6 blocks/CU.
// Each 64-col tile is head-aligned.
// ---------------------------------------------------------------------------
__global__ __launch_bounds__(256, 4) void k_qkv_mfma(
    const ush* __restrict__ xh, const ush* __restrict__ xl,
    const ush* __restrict__ wh,
    const float* __restrict__ bias,
    ush* __restrict__ qo, ush* __restrict__ ko, ush* __restrict__ vo)
{
  __shared__ short lds[2 * 12 * 512];    // 24 KB double buffer
  const int orig = blockIdx.x;
  const int bid = (orig & 7) * 144 + (orig >> 3);  // 1152 = 8*144, bijective
  const int bm = bid & 31, bn = bid >> 5;          // 32 M-tiles x 36 N-tiles
  const int row0 = bm * 64, col0 = bn * 64;
  ffrag acc[2][2] = {};
  gemm_pipe<2, 2, 2>(xh, xl, wh, wh, row0, col0, 768, lds, acc);

  const int tid = threadIdx.x, lane = tid & 63, w = tid >> 6;
  const int wr = w >> 1, wc = w & 1;
  const int l15 = lane & 15, l4 = lane >> 4;
  const int which = col0 / 768;                    // uniform per block
  const int head  = (col0 - which * 768) >> 6;     // uniform per block
  ush* base = which == 0 ? qo : (which == 1 ? ko : vo);
  #pragma unroll
  for (int mi = 0; mi < 2; mi++)
    #pragma unroll
    for (int ni = 0; ni < 2; ni++) {
      int d = wc * 32 + ni * 16 + l15;             // 0..63 within head
      float bv = bias[col0 + d];
      #pragma unroll
      for (int r = 0; r < 4; r++) {
        int row = row0 + wr * 32 + mi * 16 + l4 * 4 + r;
        int bb = row >> 10, n = row & 1023;
        base[((size_t)(bb * NHEADS + head) * NTOK + n) * HD + d] =
            f2b(acc[mi][ni][r] + bv);
      }
    }
}

// ---------------------------------------------------------------------------
// proj GEMM: tile 64x64, 3-TERM (output is final fp32 -> keep precision);
// grid 384 (8x48 XCD-swizzle).
// ---------------------------------------------------------------------------
__global__ __launch_bounds__(256) void k_proj_mfma(
    const ush* __restrict__ ah, const ush* __restrict__ al,
    const ush* __restrict__ bh, const ush* __restrict__ bl,
    const float* __restrict__ bias, float* __restrict__ out)
{
  __shared__ short lds[2 * 16 * 512];    // 32 KB double buffer
  const int orig = blockIdx.x;
  const int bid = (orig & 7) * 48 + (orig >> 3);
  const int bm = bid & 31, bn = bid >> 5;
  const int row0 = bm * 64, col0 = bn * 64;
  ffrag acc[2][2] = {};
  gemm_pipe<2, 2, 3>(ah, al, bh, bl, row0, col0, 768, lds, acc);

  const int tid = threadIdx.x, lane = tid & 63, w = tid >> 6;
  const int wr = w >> 1, wc = w & 1;
  const int l15 = lane & 15, l4 = lane >> 4;
  #pragma unroll
  for (int mi = 0; mi < 2; mi++)
    #pragma unroll
    for (int ni = 0; ni < 2; ni++) {
      int col = col0 + wc * 32 + ni * 16 + l15;
      float bv = bias[col];
      #pragma unroll
      for (int r = 0; r < 4; r++) {
        int row = row0 + wr * 32 + mi * 16 + l4 * 4 + r;
        out[(size_t)row * 768 + col] = acc[mi][ni][r] + bv;
      }
    }
}

// ---------------------------------------------------------------------------
// Kernel: rel-pos bias precompute (q bf16). Unchanged.
// ---------------------------------------------------------------------------
__global__ __launch_bounds__(256) void k_rel(
    const ush* __restrict__ qT, const float* __restrict__ rph,
    const float* __restrict__ rpw,
    float* __restrict__ relh, float* __restrict__ relw)
{
  __shared__ float Qs[32][68];
  __shared__ float RhS[32][68];
  __shared__ float RwS[63][68];
  const int bid = blockIdx.x;
  const int pair = bid >> 5;
  const int nt = bid & 31;
  const int nbase = nt * 32;
  const ush* qp = qT + (size_t)pair * NTOK * HD + (size_t)nbase * HD;
  const int tid = threadIdx.x;
  #pragma unroll
  for (int ii = 0; ii < 2; ii++) {
    int f = ii * 256 + tid;
    int r = f >> 4, k4 = f & 15;
    ushort4 t = *(const ushort4*)(qp + (size_t)r * HD + k4 * 4);
    Qs[r][k4*4+0] = b2f(t.x); Qs[r][k4*4+1] = b2f(t.y);
    Qs[r][k4*4+2] = b2f(t.z); Qs[r][k4*4+3] = b2f(t.w);
    *(fx4*)&RhS[r][k4*4] = *(const fx4*)(rph + (size_t)(nt + r) * 64 + k4 * 4);
  }
  #pragma unroll
  for (int ii = 0; ii < 4; ii++) {
    int f = ii * 256 + tid;
    if (f < 1008) {
      int r = f >> 4, k4 = f & 15;
      *(fx4*)&RwS[r][k4*4] = *(const fx4*)(rpw + (size_t)r * 64 + k4 * 4);
    }
  }
  __syncthreads();
  const int nl = tid >> 3, rem = tid & 7;
  #pragma unroll
  for (int rep = 0; rep < 8; rep++) {
    int kidx = rep * 8 + rem;
    int hw = kidx >> 5;
    int k = kidx & 31;
    const float* rrow = hw ? &RwS[nl + 31 - k][0] : &RhS[31 - k][0];
    float sum = 0.f;
    #pragma unroll
    for (int c4 = 0; c4 < 16; c4++) {
      fx4 q = *(const fx4*)&Qs[nl][c4*4];
      fx4 rv = *(const fx4*)&rrow[c4*4];
      sum = fmaf(q[0], rv[0], sum);
      sum = fmaf(q[1], rv[1], sum);
      sum = fmaf(q[2], rv[2], sum);
      sum = fmaf(q[3], rv[3], sum);
    }
    float* dst = (hw ? relw : relh) + (size_t)pair * NTOK * 32 + (size_t)(nbase + nl) * 32 + k;
    *dst = sum;
  }
}

// ---------------------------------------------------------------------------
// MFMA flash attention, SPLIT-KV. Unchanged from round 8.
// ---------------------------------------------------------------------------
__global__ __launch_bounds__(256, 3) void k_attn_mfma(
    const ush* __restrict__ qT, const ush* __restrict__ kT,
    const ush* __restrict__ vT,
    const float* __restrict__ relh, const float* __restrict__ relw,
    ush* __restrict__ oph, ush* __restrict__ opl, float* __restrict__ ml)
{
  __shared__ short Kf[2 * 8 * 512]; // double-buffered K tiles (8KB each)
  __shared__ char VTb[8192];        // V^T [64 d][64 k] bf16, XOR-swizzled rows
  __shared__ char Phb[8192];        // P hi [64 q][64 k] bf16, swizzled
  __shared__ char Plb[8192];        // P lo
  __shared__ float RhS[64][36];     // relh rows for this q-tile

  const int orig = blockIdx.x;
  const int bid = (orig & 7) * 96 + (orig >> 3);   // 768 = 8*96, bijective
  const int ks   = bid & 1;                        // KV half
  const int qt   = (bid >> 1) & 15;
  const int pair = bid >> 5;
  const int q0 = qt * 64;
  const ush* qp = qT + (size_t)pair * NTOK * HD;
  const ush* kp = kT + (size_t)pair * NTOK * HD;
  const ush* vp = vT + (size_t)pair * NTOK * HD;
  const float* rhp = relh + (size_t)pair * NTOK * 32;
  const float* rwp = relw + (size_t)pair * NTOK * 32;

  const int tid = threadIdx.x;
  const int lane = tid & 63, w = tid >> 6;
  const int l15 = lane & 15, l4 = lane >> 4;
  const int wq = w * 16;
  const int kv = tid & 63, db = tid >> 6;

  auto issueK = [&](int tt) {
    const int gt = ks * 8 + tt;
    const ush* s0 = kp + (size_t)(gt * 64 + wq + l15) * HD + l4 * 8;
    short* dst = Kf + (tt & 1) * 4096 + (w * 2) * 512;
    gload16(s0, dst);
    gload16(s0 + 32, dst + 512);
  };
  auto issueV = [&](int tt, ushort4 (&vr)[4]) {
    const int gt = ks * 8 + tt;
    #pragma unroll
    for (int j = 0; j < 4; j++)
      vr[j] = *(const ushort4*)(vp + (size_t)(gt * 64 + kv) * HD + db * 16 + j * 4);
  };
  auto writeVT = [&](ushort4 (&vr)[4]) {
    #pragma unroll
    for (int j = 0; j < 4; j++) {
      int d0 = db * 16 + j * 4;
      *(ush*)(VTb + swz(d0 + 0, 2 * kv)) = vr[j].x;
      *(ush*)(VTb + swz(d0 + 1, 2 * kv)) = vr[j].y;
      *(ush*)(VTb + swz(d0 + 2, 2 * kv)) = vr[j].z;
      *(ush*)(VTb + swz(d0 + 3, 2 * kv)) = vr[j].w;
    }
  };

  // ---- prologue ----
  {
    int row = tid >> 2, seg = tid & 3;
    const float* src = rhp + (size_t)(q0 + row) * 32 + seg * 8;
    *(fx4*)&RhS[row][seg * 8]     = *(const fx4*)src;
    *(fx4*)&RhS[row][seg * 8 + 4] = *(const fx4*)(src + 4);
  }
  bfrag qf[2];
  qf[0] = *(const bfrag*)(qp + (size_t)(q0 + wq + l15) * HD + l4 * 8);
  qf[1] = *(const bfrag*)(qp + (size_t)(q0 + wq + l15) * HD + 32 + l4 * 8);
  float rw[4][2];
  #pragma unroll
  for (int r = 0; r < 4; r++)
    #pragma unroll
    for (int h = 0; h < 2; h++)
      rw[r][h] = rwp[(size_t)(q0 + wq + l4 * 4 + r) * 32 + h * 16 + l15];

  asm volatile("" ::: "memory");
  ushort4 vrA[4], vrB[4];
  issueK(0); issueV(0, vrA); issueV(1, vrB);

  ffrag o[4] = {};
  float mrow[4] = {-3e38f, -3e38f, -3e38f, -3e38f};
  float lrow[4] = {};

  for (int tt = 0; tt < 8; tt++) {
    const int t = ks * 8 + tt;                 // global tile index (for bias)
    if (tt < 7) vwait<4>(); else vwait<0>();
    barL();   // K(tt) visible; all waves finished iteration tt-1 entirely

    if ((tt & 1) == 0) {
      writeVT(vrA);
      if (tt < 7) issueK(tt + 1);
      if (tt < 6) issueV(tt + 2, vrA);
    } else {
      writeVT(vrB);
      if (tt < 7) issueK(tt + 1);
      if (tt < 6) issueV(tt + 2, vrB);
    }

    // --- QK^T from Kf[tt&1]
    const short* kbuf = Kf + (tt & 1) * 4096;
    ffrag s[4] = {};
    #pragma unroll
    for (int kf = 0; kf < 4; kf++) {
      bfrag kf0 = *(const bfrag*)(kbuf + (kf * 2 + 0) * 512 + lane * 8);
      bfrag kf1 = *(const bfrag*)(kbuf + (kf * 2 + 1) * 512 + lane * 8);
      s[kf] = mfma16(qf[0], kf0, s[kf]);
      s[kf] = mfma16(qf[1], kf1, s[kf]);
    }

    // --- bias + online softmax
    fx2 rh2[4];
    #pragma unroll
    for (int r = 0; r < 4; r++)
      rh2[r] = *(const fx2*)&RhS[wq + l4 * 4 + r][2 * t];
    float pm[4] = {-3e38f, -3e38f, -3e38f, -3e38f};
    #pragma unroll
    for (int kf = 0; kf < 4; kf++)
      #pragma unroll
      for (int r = 0; r < 4; r++) {
        float sc = fmaf(s[kf][r], 0.125f, rh2[r][kf >> 1] + rw[r][kf & 1]);
        s[kf][r] = sc;
        pm[r] = fmaxf(pm[r], sc);
      }
    #pragma unroll
    for (int off = 1; off < 16; off <<= 1)
      #pragma unroll
      for (int r = 0; r < 4; r++)
        pm[r] = fmaxf(pm[r], __shfl_xor(pm[r], off));
    float al[4], ps[4] = {0.f, 0.f, 0.f, 0.f};
    #pragma unroll
    for (int r = 0; r < 4; r++) {
      float mnew = fmaxf(mrow[r], pm[r]);
      al[r] = __expf(mrow[r] - mnew);
      mrow[r] = mnew;
    }
    #pragma unroll
    for (int kf = 0; kf < 4; kf++)
      #pragma unroll
      for (int r = 0; r < 4; r++) {
        float p = __expf(s[kf][r] - mrow[r]);
        s[kf][r] = p;
        ps[r] += p;
      }
    #pragma unroll
    for (int off = 1; off < 16; off <<= 1)
      #pragma unroll
      for (int r = 0; r < 4; r++)
        ps[r] += __shfl_xor(ps[r], off);
    #pragma unroll
    for (int r = 0; r < 4; r++)
      lrow[r] = fmaf(lrow[r], al[r], ps[r]);

    // --- P -> bf16 hi/lo
    #pragma unroll
    for (int kf = 0; kf < 4; kf++)
      #pragma unroll
      for (int r = 0; r < 4; r++) {
        ush hi = f2b(s[kf][r]);
        float lo = s[kf][r] - b2f(hi);
        int a = swz(wq + l4 * 4 + r, kf * 32 + 2 * l15);
        *(ush*)(Phb + a) = hi;
        *(ush*)(Plb + a) = f2b(lo);
      }
    #pragma unroll
    for (int df = 0; df < 4; df++)
      #pragma unroll
      for (int r = 0; r < 4; r++)
        o[df][r] *= al[r];

    barL();   // VT + P writes visible before PV

    // --- PV
    bfrag ph[2], pl[2];
    #pragma unroll
    for (int kc = 0; kc < 2; kc++) {
      int a = swz(wq + l15, kc * 64 + l4 * 16);
      ph[kc] = *(const bfrag*)(Phb + a);
      pl[kc] = *(const bfrag*)(Plb + a);
    }
    #pragma unroll
    for (int df = 0; df < 4; df++)
      #pragma unroll
      for (int kc = 0; kc < 2; kc++) {
        bfrag vf = *(const bfrag*)(VTb + swz(df * 16 + l15, kc * 64 + l4 * 16));
        o[df] = mfma16(ph[kc], vf, o[df]);
        o[df] = mfma16(pl[kc], vf, o[df]);
      }
  }

  // --- epilogue: write UNNORMALIZED partial o + (m,l)
  const int part = ((pair << 4) | qt) * 2 + ks;
  if (l15 == 0) {
    float* mlp = ml + (size_t)part * 128;
    #pragma unroll
    for (int r = 0; r < 4; r++) {
      int row = wq + l4 * 4 + r;
      mlp[row] = mrow[r];
      mlp[64 + row] = lrow[r];
    }
  }
  const size_t pbase = (size_t)part * 4096;
  #pragma unroll
  for (int df = 0; df < 4; df++)
    #pragma unroll
    for (int r = 0; r < 4; r++) {
      float val = o[df][r];
      int row = wq + l4 * 4 + r;
      size_t idx = pbase + (size_t)row * 64 + df * 16 + l15;
      ush hi = f2b(val);
      oph[idx] = hi;
      opl[idx] = f2b(val - b2f(hi));
    }
}

// ---------------------------------------------------------------------------
// Merge the two KV-halves: standard online-softmax combine, write o1 hi/lo.
// ---------------------------------------------------------------------------
__global__ __launch_bounds__(256) void k_attn_merge(
    const ush* __restrict__ oph, const ush* __restrict__ opl,
    const float* __restrict__ ml,
    ush* __restrict__ o1h, ush* __restrict__ o1l)
{
  const int pq = blockIdx.x;              // (pair, qtile)
  const int pair = pq >> 4, qt = pq & 15;
  const int bb = pair / NHEADS, head = pair % NHEADS;
  __shared__ float M0[64], L0[64], M1[64], L1[64];
  const int tid = threadIdx.x;
  const float* mlp = ml + (size_t)pq * 256;
  if (tid < 64) {
    M0[tid] = mlp[tid];        L0[tid] = mlp[64 + tid];
    M1[tid] = mlp[128 + tid];  L1[tid] = mlp[192 + tid];
  }
  __syncthreads();
  const size_t b0 = (size_t)(pq * 2) * 4096;
  const size_t b1 = b0 + 4096;
  #pragma unroll
  for (int e = 0; e < 4; e++) {
    int q4 = e * 256 + tid;               // ushort4 index within 64x64 tile
    int row = q4 >> 4;
    int d4 = (q4 & 15) * 4;
    float m0 = M0[row], l0v = L0[row], m1 = M1[row], l1v = L1[row];
    float m = fmaxf(m0, m1);
    float a0 = __expf(m0 - m), a1 = __expf(m1 - m);
    float inv = 1.0f / (l0v * a0 + l1v * a1);
    ushort4 h0 = *(const ushort4*)(oph + b0 + (size_t)q4 * 4);
    ushort4 g0 = *(const ushort4*)(opl + b0 + (size_t)q4 * 4);
    ushort4 h1 = *(const ushort4*)(oph + b1 + (size_t)q4 * 4);
    ushort4 g1 = *(const ushort4*)(opl + b1 + (size_t)q4 * 4);
    float v0 = ((b2f(h0.x)+b2f(g0.x))*a0 + (b2f(h1.x)+b2f(g1.x))*a1) * inv;
    float v1 = ((b2f(h0.y)+b2f(g0.y))*a0 + (b2f(h1.y)+b2f(g1.y))*a1) * inv;
    float v2 = ((b2f(h0.z)+b2f(g0.z))*a0 + (b2f(h1.z)+b2f(g1.z))*a1) * inv;
    float v3 = ((b2f(h0.w)+b2f(g0.w))*a0 + (b2f(h1.w)+b2f(g1.w))*a1) * inv;
    size_t gidx = ((size_t)(bb * NTOK + qt * 64 + row)) * DIMM + head * HD + d4;
    ushort4 oh, ol;
    oh.x = f2b(v0); ol.x = f2b(v0 - b2f(oh.x));
    oh.y = f2b(v1); ol.y = f2b(v1 - b2f(oh.y));
    oh.z = f2b(v2); ol.z = f2b(v2 - b2f(oh.z));
    oh.w = f2b(v3); ol.w = f2b(v3 - b2f(oh.w));
    *(ushort4*)(o1h + gidx) = oh;
    *(ushort4*)(o1l + gidx) = ol;
  }
}

// ---------------------------------------------------------------------------
extern "C" void kernel_launch(void* const* d_in, const int* in_sizes, int n_in,
                              void* d_out, int out_size, void* d_ws, size_t ws_size,
                              hipStream_t stream)
{
  const float* x      = (const float*)d_in[0];
  const float* qkv_w  = (const float*)d_in[1];
  const float* qkv_b  = (const float*)d_in[2];
  const float* proj_w = (const float*)d_in[3];
  const float* proj_b = (const float*)d_in[4];
  const float* rph    = (const float*)d_in[5];
  const float* rpw    = (const float*)d_in[6];

  char* p = (char*)d_ws;
  ush* xh  = (ush*)p; p += 3145728;   // 2048*768*2   (xh+xl contiguous)
  ush* xl  = (ush*)p; p += 3145728;
  ush* wh  = (ush*)p; p += 3538944;   // 2304*768*2   (wh+wl contiguous)
  ush* wl  = (ush*)p; p += 3538944;
  ush* pwh = (ush*)p; p += 1179648;   // 768*768*2
  ush* pwl = (ush*)p; p += 1179648;
  ush* qb  = (ush*)p; p += 3145728;   // 24*1024*64*2
  ush* kb  = (ush*)p; p += 3145728;
  ush* vb  = (ush*)p; p += 3145728;
  float* relh = (float*)p; p += 3145728;   // 24*1024*32*4
  float* relw = (float*)p; p += 3145728;
  float* ml   = (float*)p; p += 393216;    // 768*128*4
  // Partial O: oph spans xh+xl (3,145,728 ush exact), opl spans wh+wl.
  ush* oph = xh;
  ush* opl = wh;
  // Merge output overlays qb/kb (dead after k_attn_mfma; exact fit).
  ush* o1h = qb;
  ush* o1l = kb;
  float* out = (float*)d_out;

  k_cvt3<<<dim3(3840), dim3(256), 0, stream>>>(x, qkv_w, proj_w,
                                               xh, xl, wh, wl, pwh, pwl);
  k_qkv_mfma<<<dim3(1152), dim3(256), 0, stream>>>(xh, xl, wh, qkv_b, qb, kb, vb);
  k_rel<<<dim3(768), dim3(256), 0, stream>>>(qb, rph, rpw, relh, relw);
  k_attn_mfma<<<dim3(768), dim3(256), 0, stream>>>(qb, kb, vb, relh, relw, oph, opl, ml);
  k_attn_merge<<<dim3(384), dim3(256), 0, stream>>>(oph, opl, ml, o1h, o1l);
  k_proj_mfma<<<dim3(384), dim3(256), 0, stream>>>(o1h, o1l, pwh, pwl, proj_b, out);
}

// Round 10
// 127.417 us; speedup vs baseline: 3.2687x; 1.0150x over previous
//
#include <hip/hip_runtime.h>

typedef float fx4 __attribute__((ext_vector_type(4)));
typedef float fx2 __attribute__((ext_vector_type(2)));
typedef short bfrag __attribute__((ext_vector_type(8)));
typedef float ffrag __attribute__((ext_vector_type(4)));
typedef unsigned short ush;

#define NTOK  1024
#define NHEADS 12
#define HD    64
#define DIMM  768

// ---------------- bf16 helpers (bit-level, RNE) ----------------
__device__ __forceinline__ float b2f(ush u) {
  union { unsigned i; float f; } x; x.i = ((unsigned)u) << 16; return x.f;
}
__device__ __forceinline__ ush f2b(float f) {
  union { float f; unsigned i; } x; x.f = f;
  unsigned r = x.i + 0x7fff + ((x.i >> 16) & 1);
  return (ush)(r >> 16);
}

__device__ __forceinline__ void gload16(const void* g, void* l) {
  __builtin_amdgcn_global_load_lds(
      (const __attribute__((address_space(1))) unsigned*)g,
      (__attribute__((address_space(3))) unsigned*)l, 16, 0, 0);
}

__device__ __forceinline__ ffrag mfma16(bfrag a, bfrag b, ffrag c) {
  return __builtin_amdgcn_mfma_f32_16x16x32_bf16(a, b, c, 0, 0, 0);
}

// counted vmcnt wait (T4). N = outstanding VMEM ops allowed to remain.
template<int N> __device__ __forceinline__ void vwait() {
  if constexpr (N == 0)      asm volatile("s_waitcnt vmcnt(0)" ::: "memory");
  else if constexpr (N == 1) asm volatile("s_waitcnt vmcnt(1)" ::: "memory");
  else if constexpr (N == 2) asm volatile("s_waitcnt vmcnt(2)" ::: "memory");
  else if constexpr (N == 3) asm volatile("s_waitcnt vmcnt(3)" ::: "memory");
  else if constexpr (N == 4) asm volatile("s_waitcnt vmcnt(4)" ::: "memory");
  else if constexpr (N == 6) asm volatile("s_waitcnt vmcnt(6)" ::: "memory");
  else if constexpr (N == 8) asm volatile("s_waitcnt vmcnt(8)" ::: "memory");
  else                       asm volatile("s_waitcnt vmcnt(12)" ::: "memory");
}
// raw barrier (no vmcnt drain) with compiler memory fences
__device__ __forceinline__ void bar() {
  asm volatile("" ::: "memory");
  __builtin_amdgcn_s_barrier();
  asm volatile("" ::: "memory");
}
// barrier that first drains own LDS ops (for ds_write -> cross-wave read)
__device__ __forceinline__ void barL() {
  asm volatile("s_waitcnt lgkmcnt(0)" ::: "memory");
  __builtin_amdgcn_s_barrier();
  asm volatile("" ::: "memory");
}

// XOR-swizzled byte address within a [rows][128B] LDS tile (G4 fix).
__device__ __forceinline__ int swz(int row, int b) {
  return row * 128 + (b ^ ((row & 7) << 4));
}

// ---------------------------------------------------------------------------
// k_cvt3: fused fp32 -> (hi,lo) bf16 split for x, qkv_w, proj_w in ONE launch.
// w-lo is never read (qkv is 2-term) -> skip that store.
// ---------------------------------------------------------------------------
__global__ __launch_bounds__(256) void k_cvt3(
    const float* __restrict__ x, const float* __restrict__ w,
    const float* __restrict__ pw,
    ush* __restrict__ xh, ush* __restrict__ xl,
    ush* __restrict__ wh,
    ush* __restrict__ pwh, ush* __restrict__ pwl)
{
  int i = blockIdx.x * 256 + threadIdx.x;
  const float* src; ush *h, *l; int off;
  bool wlo = true;
  if (i < 393216)      { src = x;  h = xh;  l = xl;  off = i; }
  else if (i < 835584) { src = w;  h = wh;  l = nullptr; wlo = false; off = i - 393216; }
  else                 { src = pw; h = pwh; l = pwl; off = i - 835584; }
  fx4 v = *(const fx4*)(src + (size_t)off * 4);
  ushort4 hh, ll;
  float t;
  hh.x = f2b(v[0]); t = v[0] - b2f(hh.x); ll.x = f2b(t);
  hh.y = f2b(v[1]); t = v[1] - b2f(hh.y); ll.y = f2b(t);
  hh.z = f2b(v[2]); t = v[2] - b2f(hh.z); ll.z = f2b(t);
  hh.w = f2b(v[3]); t = v[3] - b2f(hh.w); ll.w = f2b(t);
  *(ushort4*)(h + (size_t)off * 4) = hh;
  if (wlo) *(ushort4*)(l + (size_t)off * 4) = ll;
}

// ---------------------------------------------------------------------------
// 2-buffer counted-vmcnt bf16 NT-GEMM core (unchanged).
// NTERM=3: C = Ah.Bh + Ah.Bl + Al.Bh ; NTERM=2: C = (Ah+Al).Bh
// ---------------------------------------------------------------------------
template<int MR, int NR, int NTERM>
__device__ __forceinline__ void gemm_pipe(
    const ush* __restrict__ Ah, const ush* __restrict__ Al,
    const ush* __restrict__ Bh, const ush* __restrict__ Bl,
    int row0, int col0, int K, short* lds, ffrag (&acc)[MR][NR])
{
  constexpr int F = (NTERM == 3) ? 4 * (MR + NR) : (4 * MR + 2 * NR);
  constexpr int LPS = F / 4;             // gload16 per thread per stage
  static_assert(F % 4 == 0, "frag count must be divisible by wave count");
  const int tid = threadIdx.x;
  const int lane = tid & 63, w = tid >> 6;
  const int wr = w >> 1, wc = w & 1;
  const int l15 = lane & 15, l8 = (lane >> 4) * 8;

  auto stage = [&](short* buf, int k0) {
    #pragma unroll
    for (int i = 0; i < LPS; i++) {
      int f = i * 4 + w;
      const ush* src;
      if (f < 2 * MR)
        src = Ah + (size_t)(row0 + f * 16 + l15) * K + k0 + l8;
      else if (f < 4 * MR)
        src = Al + (size_t)(row0 + (f - 2 * MR) * 16 + l15) * K + k0 + l8;
      else if (f < 4 * MR + 2 * NR)
        src = Bh + (size_t)(col0 + (f - 4 * MR) * 16 + l15) * K + k0 + l8;
      else
        src = Bl + (size_t)(col0 + (f - 4 * MR - 2 * NR) * 16 + l15) * K + k0 + l8;
      gload16(src, buf + f * 512);
    }
  };

  auto step = [&](const short* buf) {
    bfrag ah[MR], al[MR], bh[NR];
    #pragma unroll
    for (int i = 0; i < MR; i++) {
      ah[i] = *(const bfrag*)(buf + (wr * MR + i) * 512 + lane * 8);
      al[i] = *(const bfrag*)(buf + (2 * MR + wr * MR + i) * 512 + lane * 8);
    }
    #pragma unroll
    for (int j = 0; j < NR; j++)
      bh[j] = *(const bfrag*)(buf + (4 * MR + wc * NR + j) * 512 + lane * 8);
    if constexpr (NTERM == 3) {
      bfrag bl[NR];
      #pragma unroll
      for (int j = 0; j < NR; j++)
        bl[j] = *(const bfrag*)(buf + (4 * MR + 2 * NR + wc * NR + j) * 512 + lane * 8);
      #pragma unroll
      for (int i = 0; i < MR; i++)
        #pragma unroll
        for (int j = 0; j < NR; j++) {
          acc[i][j] = mfma16(ah[i], bh[j], acc[i][j]);
          acc[i][j] = mfma16(ah[i], bl[j], acc[i][j]);
          acc[i][j] = mfma16(al[i], bh[j], acc[i][j]);
        }
    } else {
      #pragma unroll
      for (int i = 0; i < MR; i++)
        #pragma unroll
        for (int j = 0; j < NR; j++) {
          acc[i][j] = mfma16(ah[i], bh[j], acc[i][j]);
          acc[i][j] = mfma16(al[i], bh[j], acc[i][j]);
        }
    }
  };

  const int nt = K / 32;
  stage(lds, 0);
  for (int t = 0; t < nt; t++) {
    bar();
    if (t + 1 < nt) {
      stage(lds + ((t + 1) & 1) * F * 512, (t + 1) * 32);
      vwait<LPS>();
    } else {
      vwait<0>();
    }
    bar();
    step(lds + (t & 1) * F * 512);
  }
}

// ---------------------------------------------------------------------------
// qkv GEMM: M=2048, N=2304, K=768; tile 64x64 (wave 32x32), 2-TERM.
// grid 1152. 2D XCD partition: each XCD owns an 8(M)x18(N) tile rectangle
// -> per-XCD L2 footprint = 512 A-rows (1.57MB hi+lo) + 1152 B-cols (1.77MB)
//    = 3.34MB < 4MB L2. Minimizes cross-XCD panel re-fetch (round-9: 78MB).
// ---------------------------------------------------------------------------
__global__ __launch_bounds__(256, 4) void k_qkv_mfma(
    const ush* __restrict__ xh, const ush* __restrict__ xl,
    const ush* __restrict__ wh,
    const float* __restrict__ bias,
    ush* __restrict__ qo, ush* __restrict__ ko, ush* __restrict__ vo)
{
  __shared__ short lds[2 * 12 * 512];    // 24 KB double buffer
  const int orig = blockIdx.x;
  const int xcd = orig & 7, local = orig >> 3;     // 144 blocks per XCD
  const int lm = local & 7, ln = local >> 3;       // 8 x 18 rectangle
  const int bm = (xcd & 3) * 8 + lm;               // 0..31
  const int bn = (xcd >> 2) * 18 + ln;             // 0..35
  const int row0 = bm * 64, col0 = bn * 64;
  ffrag acc[2][2] = {};
  gemm_pipe<2, 2, 2>(xh, xl, wh, wh, row0, col0, 768, lds, acc);

  const int tid = threadIdx.x, lane = tid & 63, w = tid >> 6;
  const int wr = w >> 1, wc = w & 1;
  const int l15 = lane & 15, l4 = lane >> 4;
  const int which = col0 / 768;                    // uniform per block
  const int head  = (col0 - which * 768) >> 6;     // uniform per block
  ush* base = which == 0 ? qo : (which == 1 ? ko : vo);
  #pragma unroll
  for (int mi = 0; mi < 2; mi++)
    #pragma unroll
    for (int ni = 0; ni < 2; ni++) {
      int d = wc * 32 + ni * 16 + l15;             // 0..63 within head
      float bv = bias[col0 + d];
      #pragma unroll
      for (int r = 0; r < 4; r++) {
        int row = row0 + wr * 32 + mi * 16 + l4 * 4 + r;
        int bb = row >> 10, n = row & 1023;
        base[((size_t)(bb * NHEADS + head) * NTOK + n) * HD + d] =
            f2b(acc[mi][ni][r] + bv);
      }
    }
}

// ---------------------------------------------------------------------------
// proj GEMM: tile 64x64, 3-TERM; grid 384. 2D XCD partition: 8(M)x6(N)
// rectangle per XCD -> 2.75MB L2 footprint.
// ---------------------------------------------------------------------------
__global__ __launch_bounds__(256) void k_proj_mfma(
    const ush* __restrict__ ah, const ush* __restrict__ al,
    const ush* __restrict__ bh, const ush* __restrict__ bl,
    const float* __restrict__ bias, float* __restrict__ out)
{
  __shared__ short lds[2 * 16 * 512];    // 32 KB double buffer
  const int orig = blockIdx.x;
  const int xcd = orig & 7, local = orig >> 3;     // 48 blocks per XCD
  const int lm = local & 7, ln = local >> 3;       // 8 x 6 rectangle
  const int bm = (xcd & 3) * 8 + lm;               // 0..31
  const int bn = (xcd >> 2) * 6 + ln;              // 0..11
  const int row0 = bm * 64, col0 = bn * 64;
  ffrag acc[2][2] = {};
  gemm_pipe<2, 2, 3>(ah, al, bh, bl, row0, col0, 768, lds, acc);

  const int tid = threadIdx.x, lane = tid & 63, w = tid >> 6;
  const int wr = w >> 1, wc = w & 1;
  const int l15 = lane & 15, l4 = lane >> 4;
  #pragma unroll
  for (int mi = 0; mi < 2; mi++)
    #pragma unroll
    for (int ni = 0; ni < 2; ni++) {
      int col = col0 + wc * 32 + ni * 16 + l15;
      float bv = bias[col];
      #pragma unroll
      for (int r = 0; r < 4; r++) {
        int row = row0 + wr * 32 + mi * 16 + l4 * 4 + r;
        out[(size_t)row * 768 + col] = acc[mi][ni][r] + bv;
      }
    }
}

// ---------------------------------------------------------------------------
// Kernel: rel-pos bias precompute (q bf16). Unchanged.
// ---------------------------------------------------------------------------
__global__ __launch_bounds__(256) void k_rel(
    const ush* __restrict__ qT, const float* __restrict__ rph,
    const float* __restrict__ rpw,
    float* __restrict__ relh, float* __restrict__ relw)
{
  __shared__ float Qs[32][68];
  __shared__ float RhS[32][68];
  __shared__ float RwS[63][68];
  const int bid = blockIdx.x;
  const int pair = bid >> 5;
  const int nt = bid & 31;
  const int nbase = nt * 32;
  const ush* qp = qT + (size_t)pair * NTOK * HD + (size_t)nbase * HD;
  const int tid = threadIdx.x;
  #pragma unroll
  for (int ii = 0; ii < 2; ii++) {
    int f = ii * 256 + tid;
    int r = f >> 4, k4 = f & 15;
    ushort4 t = *(const ushort4*)(qp + (size_t)r * HD + k4 * 4);
    Qs[r][k4*4+0] = b2f(t.x); Qs[r][k4*4+1] = b2f(t.y);
    Qs[r][k4*4+2] = b2f(t.z); Qs[r][k4*4+3] = b2f(t.w);
    *(fx4*)&RhS[r][k4*4] = *(const fx4*)(rph + (size_t)(nt + r) * 64 + k4 * 4);
  }
  #pragma unroll
  for (int ii = 0; ii < 4; ii++) {
    int f = ii * 256 + tid;
    if (f < 1008) {
      int r = f >> 4, k4 = f & 15;
      *(fx4*)&RwS[r][k4*4] = *(const fx4*)(rpw + (size_t)r * 64 + k4 * 4);
    }
  }
  __syncthreads();
  const int nl = tid >> 3, rem = tid & 7;
  #pragma unroll
  for (int rep = 0; rep < 8; rep++) {
    int kidx = rep * 8 + rem;
    int hw = kidx >> 5;
    int k = kidx & 31;
    const float* rrow = hw ? &RwS[nl + 31 - k][0] : &RhS[31 - k][0];
    float sum = 0.f;
    #pragma unroll
    for (int c4 = 0; c4 < 16; c4++) {
      fx4 q = *(const fx4*)&Qs[nl][c4*4];
      fx4 rv = *(const fx4*)&rrow[c4*4];
      sum = fmaf(q[0], rv[0], sum);
      sum = fmaf(q[1], rv[1], sum);
      sum = fmaf(q[2], rv[2], sum);
      sum = fmaf(q[3], rv[3], sum);
    }
    float* dst = (hw ? relw : relh) + (size_t)pair * NTOK * 32 + (size_t)(nbase + nl) * 32 + k;
    *dst = sum;
  }
}

// ---------------------------------------------------------------------------
// MFMA flash attention, SPLIT-KV. Unchanged from round 9.
// ---------------------------------------------------------------------------
__global__ __launch_bounds__(256, 3) void k_attn_mfma(
    const ush* __restrict__ qT, const ush* __restrict__ kT,
    const ush* __restrict__ vT,
    const float* __restrict__ relh, const float* __restrict__ relw,
    ush* __restrict__ oph, ush* __restrict__ opl, float* __restrict__ ml)
{
  __shared__ short Kf[2 * 8 * 512]; // double-buffered K tiles (8KB each)
  __shared__ char VTb[8192];        // V^T [64 d][64 k] bf16, XOR-swizzled rows
  __shared__ char Phb[8192];        // P hi [64 q][64 k] bf16, swizzled
  __shared__ char Plb[8192];        // P lo
  __shared__ float RhS[64][36];     // relh rows for this q-tile

  const int orig = blockIdx.x;
  const int bid = (orig & 7) * 96 + (orig >> 3);   // 768 = 8*96, bijective
  const int ks   = bid & 1;                        // KV half
  const int qt   = (bid >> 1) & 15;
  const int pair = bid >> 5;
  const int q0 = qt * 64;
  const ush* qp = qT + (size_t)pair * NTOK * HD;
  const ush* kp = kT + (size_t)pair * NTOK * HD;
  const ush* vp = vT + (size_t)pair * NTOK * HD;
  const float* rhp = relh + (size_t)pair * NTOK * 32;
  const float* rwp = relw + (size_t)pair * NTOK * 32;

  const int tid = threadIdx.x;
  const int lane = tid & 63, w = tid >> 6;
  const int l15 = lane & 15, l4 = lane >> 4;
  const int wq = w * 16;
  const int kv = tid & 63, db = tid >> 6;

  auto issueK = [&](int tt) {
    const int gt = ks * 8 + tt;
    const ush* s0 = kp + (size_t)(gt * 64 + wq + l15) * HD + l4 * 8;
    short* dst = Kf + (tt & 1) * 4096 + (w * 2) * 512;
    gload16(s0, dst);
    gload16(s0 + 32, dst + 512);
  };
  auto issueV = [&](int tt, ushort4 (&vr)[4]) {
    const int gt = ks * 8 + tt;
    #pragma unroll
    for (int j = 0; j < 4; j++)
      vr[j] = *(const ushort4*)(vp + (size_t)(gt * 64 + kv) * HD + db * 16 + j * 4);
  };
  auto writeVT = [&](ushort4 (&vr)[4]) {
    #pragma unroll
    for (int j = 0; j < 4; j++) {
      int d0 = db * 16 + j * 4;
      *(ush*)(VTb + swz(d0 + 0, 2 * kv)) = vr[j].x;
      *(ush*)(VTb + swz(d0 + 1, 2 * kv)) = vr[j].y;
      *(ush*)(VTb + swz(d0 + 2, 2 * kv)) = vr[j].z;
      *(ush*)(VTb + swz(d0 + 3, 2 * kv)) = vr[j].w;
    }
  };

  // ---- prologue ----
  {
    int row = tid >> 2, seg = tid & 3;
    const float* src = rhp + (size_t)(q0 + row) * 32 + seg * 8;
    *(fx4*)&RhS[row][seg * 8]     = *(const fx4*)src;
    *(fx4*)&RhS[row][seg * 8 + 4] = *(const fx4*)(src + 4);
  }
  bfrag qf[2];
  qf[0] = *(const bfrag*)(qp + (size_t)(q0 + wq + l15) * HD + l4 * 8);
  qf[1] = *(const bfrag*)(qp + (size_t)(q0 + wq + l15) * HD + 32 + l4 * 8);
  float rw[4][2];
  #pragma unroll
  for (int r = 0; r < 4; r++)
    #pragma unroll
    for (int h = 0; h < 2; h++)
      rw[r][h] = rwp[(size_t)(q0 + wq + l4 * 4 + r) * 32 + h * 16 + l15];

  asm volatile("" ::: "memory");
  ushort4 vrA[4], vrB[4];
  issueK(0); issueV(0, vrA); issueV(1, vrB);

  ffrag o[4] = {};
  float mrow[4] = {-3e38f, -3e38f, -3e38f, -3e38f};
  float lrow[4] = {};

  for (int tt = 0; tt < 8; tt++) {
    const int t = ks * 8 + tt;                 // global tile index (for bias)
    if (tt < 7) vwait<4>(); else vwait<0>();
    barL();   // K(tt) visible; all waves finished iteration tt-1 entirely

    if ((tt & 1) == 0) {
      writeVT(vrA);
      if (tt < 7) issueK(tt + 1);
      if (tt < 6) issueV(tt + 2, vrA);
    } else {
      writeVT(vrB);
      if (tt < 7) issueK(tt + 1);
      if (tt < 6) issueV(tt + 2, vrB);
    }

    // --- QK^T from Kf[tt&1]
    const short* kbuf = Kf + (tt & 1) * 4096;
    ffrag s[4] = {};
    #pragma unroll
    for (int kf = 0; kf < 4; kf++) {
      bfrag kf0 = *(const bfrag*)(kbuf + (kf * 2 + 0) * 512 + lane * 8);
      bfrag kf1 = *(const bfrag*)(kbuf + (kf * 2 + 1) * 512 + lane * 8);
      s[kf] = mfma16(qf[0], kf0, s[kf]);
      s[kf] = mfma16(qf[1], kf1, s[kf]);
    }

    // --- bias + online softmax
    fx2 rh2[4];
    #pragma unroll
    for (int r = 0; r < 4; r++)
      rh2[r] = *(const fx2*)&RhS[wq + l4 * 4 + r][2 * t];
    float pm[4] = {-3e38f, -3e38f, -3e38f, -3e38f};
    #pragma unroll
    for (int kf = 0; kf < 4; kf++)
      #pragma unroll
      for (int r = 0; r < 4; r++) {
        float sc = fmaf(s[kf][r], 0.125f, rh2[r][kf >> 1] + rw[r][kf & 1]);
        s[kf][r] = sc;
        pm[r] = fmaxf(pm[r], sc);
      }
    #pragma unroll
    for (int off = 1; off < 16; off <<= 1)
      #pragma unroll
      for (int r = 0; r < 4; r++)
        pm[r] = fmaxf(pm[r], __shfl_xor(pm[r], off));
    float al[4], ps[4] = {0.f, 0.f, 0.f, 0.f};
    #pragma unroll
    for (int r = 0; r < 4; r++) {
      float mnew = fmaxf(mrow[r], pm[r]);
      al[r] = __expf(mrow[r] - mnew);
      mrow[r] = mnew;
    }
    #pragma unroll
    for (int kf = 0; kf < 4; kf++)
      #pragma unroll
      for (int r = 0; r < 4; r++) {
        float p = __expf(s[kf][r] - mrow[r]);
        s[kf][r] = p;
        ps[r] += p;
      }
    #pragma unroll
    for (int off = 1; off < 16; off <<= 1)
      #pragma unroll
      for (int r = 0; r < 4; r++)
        ps[r] += __shfl_xor(ps[r], off);
    #pragma unroll
    for (int r = 0; r < 4; r++)
      lrow[r] = fmaf(lrow[r], al[r], ps[r]);

    // --- P -> bf16 hi/lo
    #pragma unroll
    for (int kf = 0; kf < 4; kf++)
      #pragma unroll
      for (int r = 0; r < 4; r++) {
        ush hi = f2b(s[kf][r]);
        float lo = s[kf][r] - b2f(hi);
        int a = swz(wq + l4 * 4 + r, kf * 32 + 2 * l15);
        *(ush*)(Phb + a) = hi;
        *(ush*)(Plb + a) = f2b(lo);
      }
    #pragma unroll
    for (int df = 0; df < 4; df++)
      #pragma unroll
      for (int r = 0; r < 4; r++)
        o[df][r] *= al[r];

    barL();   // VT + P writes visible before PV

    // --- PV
    bfrag ph[2], pl[2];
    #pragma unroll
    for (int kc = 0; kc < 2; kc++) {
      int a = swz(wq + l15, kc * 64 + l4 * 16);
      ph[kc] = *(const bfrag*)(Phb + a);
      pl[kc] = *(const bfrag*)(Plb + a);
    }
    #pragma unroll
    for (int df = 0; df < 4; df++)
      #pragma unroll
      for (int kc = 0; kc < 2; kc++) {
        bfrag vf = *(const bfrag*)(VTb + swz(df * 16 + l15, kc * 64 + l4 * 16));
        o[df] = mfma16(ph[kc], vf, o[df]);
        o[df] = mfma16(pl[kc], vf, o[df]);
      }
  }

  // --- epilogue: write UNNORMALIZED partial o + (m,l)
  const int part = ((pair << 4) | qt) * 2 + ks;
  if (l15 == 0) {
    float* mlp = ml + (size_t)part * 128;
    #pragma unroll
    for (int r = 0; r < 4; r++) {
      int row = wq + l4 * 4 + r;
      mlp[row] = mrow[r];
      mlp[64 + row] = lrow[r];
    }
  }
  const size_t pbase = (size_t)part * 4096;
  #pragma unroll
  for (int df = 0; df < 4; df++)
    #pragma unroll
    for (int r = 0; r < 4; r++) {
      float val = o[df][r];
      int row = wq + l4 * 4 + r;
      size_t idx = pbase + (size_t)row * 64 + df * 16 + l15;
      ush hi = f2b(val);
      oph[idx] = hi;
      opl[idx] = f2b(val - b2f(hi));
    }
}

// ---------------------------------------------------------------------------
// Merge the two KV-halves: standard online-softmax combine, write o1 hi/lo.
// ---------------------------------------------------------------------------
__global__ __launch_bounds__(256) void k_attn_merge(
    const ush* __restrict__ oph, const ush* __restrict__ opl,
    const float* __restrict__ ml,
    ush* __restrict__ o1h, ush* __restrict__ o1l)
{
  const int pq = blockIdx.x;              // (pair, qtile)
  const int pair = pq >> 4, qt = pq & 15;
  const int bb = pair / NHEADS, head = pair % NHEADS;
  __shared__ float M0[64], L0[64], M1[64], L1[64];
  const int tid = threadIdx.x;
  const float* mlp = ml + (size_t)pq * 256;
  if (tid < 64) {
    M0[tid] = mlp[tid];        L0[tid] = mlp[64 + tid];
    M1[tid] = mlp[128 + tid];  L1[tid] = mlp[192 + tid];
  }
  __syncthreads();
  const size_t b0 = (size_t)(pq * 2) * 4096;
  const size_t b1 = b0 + 4096;
  #pragma unroll
  for (int e = 0; e < 4; e++) {
    int q4 = e * 256 + tid;               // ushort4 index within 64x64 tile
    int row = q4 >> 4;
    int d4 = (q4 & 15) * 4;
    float m0 = M0[row], l0v = L0[row], m1 = M1[row], l1v = L1[row];
    float m = fmaxf(m0, m1);
    float a0 = __expf(m0 - m), a1 = __expf(m1 - m);
    float inv = 1.0f / (l0v * a0 + l1v * a1);
    ushort4 h0 = *(const ushort4*)(oph + b0 + (size_t)q4 * 4);
    ushort4 g0 = *(const ushort4*)(opl + b0 + (size_t)q4 * 4);
    ushort4 h1 = *(const ushort4*)(oph + b1 + (size_t)q4 * 4);
    ushort4 g1 = *(const ushort4*)(opl + b1 + (size_t)q4 * 4);
    float v0 = ((b2f(h0.x)+b2f(g0.x))*a0 + (b2f(h1.x)+b2f(g1.x))*a1) * inv;
    float v1 = ((b2f(h0.y)+b2f(g0.y))*a0 + (b2f(h1.y)+b2f(g1.y))*a1) * inv;
    float v2 = ((b2f(h0.z)+b2f(g0.z))*a0 + (b2f(h1.z)+b2f(g1.z))*a1) * inv;
    float v3 = ((b2f(h0.w)+b2f(g0.w))*a0 + (b2f(h1.w)+b2f(g1.w))*a1) * inv;
    size_t gidx = ((size_t)(bb * NTOK + qt * 64 + row)) * DIMM + head * HD + d4;
    ushort4 oh, ol;
    oh.x = f2b(v0); ol.x = f2b(v0 - b2f(oh.x));
    oh.y = f2b(v1); ol.y = f2b(v1 - b2f(oh.y));
    oh.z = f2b(v2); ol.z = f2b(v2 - b2f(oh.z));
    oh.w = f2b(v3); ol.w = f2b(v3 - b2f(oh.w));
    *(ushort4*)(o1h + gidx) = oh;
    *(ushort4*)(o1l + gidx) = ol;
  }
}

// ---------------------------------------------------------------------------
extern "C" void kernel_launch(void* const* d_in, const int* in_sizes, int n_in,
                              void* d_out, int out_size, void* d_ws, size_t ws_size,
                              hipStream_t stream)
{
  const float* x      = (const float*)d_in[0];
  const float* qkv_w  = (const float*)d_in[1];
  const float* qkv_b  = (const float*)d_in[2];
  const float* proj_w = (const float*)d_in[3];
  const float* proj_b = (const float*)d_in[4];
  const float* rph    = (const float*)d_in[5];
  const float* rpw    = (const float*)d_in[6];

  char* p = (char*)d_ws;
  ush* xh  = (ush*)p; p += 3145728;   // 2048*768*2   (xh+xl contiguous)
  ush* xl  = (ush*)p; p += 3145728;
  ush* wh  = (ush*)p; p += 3538944;   // 2304*768*2   (wh+wl contiguous)
  ush* wl  = (ush*)p; p += 3538944;   // region reserved (opl overlay), values unused
  ush* pwh = (ush*)p; p += 1179648;   // 768*768*2
  ush* pwl = (ush*)p; p += 1179648;
  ush* qb  = (ush*)p; p += 3145728;   // 24*1024*64*2
  ush* kb  = (ush*)p; p += 3145728;
  ush* vb  = (ush*)p; p += 3145728;
  float* relh = (float*)p; p += 3145728;   // 24*1024*32*4
  float* relw = (float*)p; p += 3145728;
  float* ml   = (float*)p; p += 393216;    // 768*128*4
  (void)wl;
  // Partial O: oph spans xh+xl (3,145,728 ush exact), opl spans wh+wl.
  ush* oph = xh;
  ush* opl = wh;
  // Merge output overlays qb/kb (dead after k_attn_mfma; exact fit).
  ush* o1h = qb;
  ush* o1l = kb;
  float* out = (float*)d_out;

  k_cvt3<<<dim3(3840), dim3(256), 0, stream>>>(x, qkv_w, proj_w,
                                               xh, xl, wh, pwh, pwl);
  k_qkv_mfma<<<dim3(1152), dim3(256), 0, stream>>>(xh, xl, wh, qkv_b, qb, kb, vb);
  k_rel<<<dim3(768), dim3(256), 0, stream>>>(qb, rph, rpw, relh, relw);
  k_attn_mfma<<<dim3(768), dim3(256), 0, stream>>>(qb, kb, vb, relh, relw, oph, opl, ml);
  k_attn_merge<<<dim3(384), dim3(256), 0, stream>>>(oph, opl, ml, o1h, o1l);
  k_proj_mfma<<<dim3(384), dim3(256), 0, stream>>>(o1h, o1l, pwh, pwl, proj_b, out);
}

// Round 11
// 120.944 us; speedup vs baseline: 3.4437x; 1.0535x over previous
//
#include <hip/hip_runtime.h>

typedef float fx4 __attribute__((ext_vector_type(4)));
typedef float fx2 __attribute__((ext_vector_type(2)));
typedef short bfrag __attribute__((ext_vector_type(8)));
typedef float ffrag __attribute__((ext_vector_type(4)));
typedef unsigned short ush;

#define NTOK  1024
#define NHEADS 12
#define HD    64
#define DIMM  768

// ---------------- bf16 helpers (bit-level, RNE) ----------------
__device__ __forceinline__ float b2f(ush u) {
  union { unsigned i; float f; } x; x.i = ((unsigned)u) << 16; return x.f;
}
__device__ __forceinline__ ush f2b(float f) {
  union { float f; unsigned i; } x; x.f = f;
  unsigned r = x.i + 0x7fff + ((x.i >> 16) & 1);
  return (ush)(r >> 16);
}

__device__ __forceinline__ void gload16(const void* g, void* l) {
  __builtin_amdgcn_global_load_lds(
      (const __attribute__((address_space(1))) unsigned*)g,
      (__attribute__((address_space(3))) unsigned*)l, 16, 0, 0);
}

__device__ __forceinline__ ffrag mfma16(bfrag a, bfrag b, ffrag c) {
  return __builtin_amdgcn_mfma_f32_16x16x32_bf16(a, b, c, 0, 0, 0);
}

// counted vmcnt wait (T4). N = outstanding VMEM ops allowed to remain.
template<int N> __device__ __forceinline__ void vwait() {
  if constexpr (N == 0)      asm volatile("s_waitcnt vmcnt(0)" ::: "memory");
  else if constexpr (N == 1) asm volatile("s_waitcnt vmcnt(1)" ::: "memory");
  else if constexpr (N == 2) asm volatile("s_waitcnt vmcnt(2)" ::: "memory");
  else if constexpr (N == 3) asm volatile("s_waitcnt vmcnt(3)" ::: "memory");
  else if constexpr (N == 4) asm volatile("s_waitcnt vmcnt(4)" ::: "memory");
  else if constexpr (N == 6) asm volatile("s_waitcnt vmcnt(6)" ::: "memory");
  else if constexpr (N == 8) asm volatile("s_waitcnt vmcnt(8)" ::: "memory");
  else                       asm volatile("s_waitcnt vmcnt(12)" ::: "memory");
}
// raw barrier (no vmcnt drain) with compiler memory fences
__device__ __forceinline__ void bar() {
  asm volatile("" ::: "memory");
  __builtin_amdgcn_s_barrier();
  asm volatile("" ::: "memory");
}
// barrier that first drains own LDS ops (for ds_write -> cross-wave read)
__device__ __forceinline__ void barL() {
  asm volatile("s_waitcnt lgkmcnt(0)" ::: "memory");
  __builtin_amdgcn_s_barrier();
  asm volatile("" ::: "memory");
}

// XOR-swizzled byte address within a [rows][128B] LDS tile (G4 fix).
__device__ __forceinline__ int swz(int row, int b) {
  return row * 128 + (b ^ ((row & 7) << 4));
}

// ---------------------------------------------------------------------------
// k_cvt3: fused fp32 -> (hi,lo) bf16 split for x, qkv_w, proj_w in ONE launch.
// w-lo is never read (qkv is 2-term) -> skip that store.
// ---------------------------------------------------------------------------
__global__ __launch_bounds__(256) void k_cvt3(
    const float* __restrict__ x, const float* __restrict__ w,
    const float* __restrict__ pw,
    ush* __restrict__ xh, ush* __restrict__ xl,
    ush* __restrict__ wh,
    ush* __restrict__ pwh, ush* __restrict__ pwl)
{
  int i = blockIdx.x * 256 + threadIdx.x;
  const float* src; ush *h, *l; int off;
  bool wlo = true;
  if (i < 393216)      { src = x;  h = xh;  l = xl;  off = i; }
  else if (i < 835584) { src = w;  h = wh;  l = nullptr; wlo = false; off = i - 393216; }
  else                 { src = pw; h = pwh; l = pwl; off = i - 835584; }
  fx4 v = *(const fx4*)(src + (size_t)off * 4);
  ushort4 hh, ll;
  float t;
  hh.x = f2b(v[0]); t = v[0] - b2f(hh.x); ll.x = f2b(t);
  hh.y = f2b(v[1]); t = v[1] - b2f(hh.y); ll.y = f2b(t);
  hh.z = f2b(v[2]); t = v[2] - b2f(hh.z); ll.z = f2b(t);
  hh.w = f2b(v[3]); t = v[3] - b2f(hh.w); ll.w = f2b(t);
  *(ushort4*)(h + (size_t)off * 4) = hh;
  if (wlo) *(ushort4*)(l + (size_t)off * 4) = ll;
}

// ---------------------------------------------------------------------------
// 2-buffer counted-vmcnt bf16 NT-GEMM core (unchanged structure).
// NTERM=3: C = Ah.Bh + Ah.Bl + Al.Bh ; NTERM=2: C = (Ah+Al).Bh
// ---------------------------------------------------------------------------
template<int MR, int NR, int NTERM>
__device__ __forceinline__ void gemm_pipe(
    const ush* __restrict__ Ah, const ush* __restrict__ Al,
    const ush* __restrict__ Bh, const ush* __restrict__ Bl,
    int row0, int col0, int K, short* lds, ffrag (&acc)[MR][NR])
{
  constexpr int F = (NTERM == 3) ? 4 * (MR + NR) : (4 * MR + 2 * NR);
  constexpr int LPS = F / 4;             // gload16 per thread per stage
  static_assert(F % 4 == 0, "frag count must be divisible by wave count");
  const int tid = threadIdx.x;
  const int lane = tid & 63, w = tid >> 6;
  const int wr = w >> 1, wc = w & 1;
  const int l15 = lane & 15, l8 = (lane >> 4) * 8;

  auto stage = [&](short* buf, int k0) {
    #pragma unroll
    for (int i = 0; i < LPS; i++) {
      int f = i * 4 + w;
      const ush* src;
      if (f < 2 * MR)
        src = Ah + (size_t)(row0 + f * 16 + l15) * K + k0 + l8;
      else if (f < 4 * MR)
        src = Al + (size_t)(row0 + (f - 2 * MR) * 16 + l15) * K + k0 + l8;
      else if (f < 4 * MR + 2 * NR)
        src = Bh + (size_t)(col0 + (f - 4 * MR) * 16 + l15) * K + k0 + l8;
      else
        src = Bl + (size_t)(col0 + (f - 4 * MR - 2 * NR) * 16 + l15) * K + k0 + l8;
      gload16(src, buf + f * 512);
    }
  };

  auto step = [&](const short* buf) {
    bfrag ah[MR], al[MR], bh[NR];
    #pragma unroll
    for (int i = 0; i < MR; i++) {
      ah[i] = *(const bfrag*)(buf + (wr * MR + i) * 512 + lane * 8);
      al[i] = *(const bfrag*)(buf + (2 * MR + wr * MR + i) * 512 + lane * 8);
    }
    #pragma unroll
    for (int j = 0; j < NR; j++)
      bh[j] = *(const bfrag*)(buf + (4 * MR + wc * NR + j) * 512 + lane * 8);
    if constexpr (NTERM == 3) {
      bfrag bl[NR];
      #pragma unroll
      for (int j = 0; j < NR; j++)
        bl[j] = *(const bfrag*)(buf + (4 * MR + 2 * NR + wc * NR + j) * 512 + lane * 8);
      #pragma unroll
      for (int i = 0; i < MR; i++)
        #pragma unroll
        for (int j = 0; j < NR; j++) {
          acc[i][j] = mfma16(ah[i], bh[j], acc[i][j]);
          acc[i][j] = mfma16(ah[i], bl[j], acc[i][j]);
          acc[i][j] = mfma16(al[i], bh[j], acc[i][j]);
        }
    } else {
      #pragma unroll
      for (int i = 0; i < MR; i++)
        #pragma unroll
        for (int j = 0; j < NR; j++) {
          acc[i][j] = mfma16(ah[i], bh[j], acc[i][j]);
          acc[i][j] = mfma16(al[i], bh[j], acc[i][j]);
        }
    }
  };

  const int nt = K / 32;
  stage(lds, 0);
  for (int t = 0; t < nt; t++) {
    bar();
    if (t + 1 < nt) {
      stage(lds + ((t + 1) & 1) * F * 512, (t + 1) * 32);
      vwait<LPS>();
    } else {
      vwait<0>();
    }
    bar();
    step(lds + (t & 1) * F * 512);
  }
}

// ---------------------------------------------------------------------------
// qkv GEMM: M=2048, N=2304, K=768; tile 128x128 (wave 64x64, MR=NR=4), 2-TERM.
// Rationale (round 10): 64^2 tiles are LDS-pipe-bound (36 LDS ops / 32 MFMA
// per block-step -> 11% MfmaUtil ceiling). 128^2 halves total LDS work
// (72 ops / 128 MFMA). Round 5's 128^2 failure was the 1D-swizzle L2 thrash
// (FETCH 53MB), now fixed by the 2D XCD partition: grid 16x18=288, each XCD
// owns a 4(M)x9(N) rectangle (~4.9MB footprint).
// LDS 48KB dbuf; per-step duration ~900cyc >> L2 latency -> dist-1 prefetch OK.
// ---------------------------------------------------------------------------
__global__ __launch_bounds__(256) void k_qkv_mfma(
    const ush* __restrict__ xh, const ush* __restrict__ xl,
    const ush* __restrict__ wh,
    const float* __restrict__ bias,
    ush* __restrict__ qo, ush* __restrict__ ko, ush* __restrict__ vo)
{
  __shared__ short lds[2 * 24 * 512];    // 48 KB double buffer
  const int orig = blockIdx.x;
  const int xcd = orig & 7, local = orig >> 3;     // 36 blocks per XCD
  const int lm = local & 3, ln = local >> 2;       // 4 x 9 rectangle
  const int bm = (xcd & 3) * 4 + lm;               // 0..15
  const int bn = (xcd >> 2) * 9 + ln;              // 0..17
  const int row0 = bm * 128, col0 = bn * 128;
  ffrag acc[4][4] = {};
  gemm_pipe<4, 4, 2>(xh, xl, wh, wh, row0, col0, 768, lds, acc);

  const int tid = threadIdx.x, lane = tid & 63, w = tid >> 6;
  const int wr = w >> 1, wc = w & 1;
  const int l15 = lane & 15, l4 = lane >> 4;
  const int which = col0 / 768;                    // uniform per block
  const int base_head = (col0 - which * 768) >> 6;
  const int head = base_head + wc;                 // uniform per wave
  ush* base = which == 0 ? qo : (which == 1 ? ko : vo);
  #pragma unroll
  for (int mi = 0; mi < 4; mi++)
    #pragma unroll
    for (int ni = 0; ni < 4; ni++) {
      int d = ni * 16 + l15;                       // 0..63 within head
      float bv = bias[col0 + wc * 64 + d];
      #pragma unroll
      for (int r = 0; r < 4; r++) {
        int row = row0 + wr * 64 + mi * 16 + l4 * 4 + r;
        int bb = row >> 10, n = row & 1023;
        base[((size_t)(bb * NHEADS + head) * NTOK + n) * HD + d] =
            f2b(acc[mi][ni][r] + bv);
      }
    }
}

// ---------------------------------------------------------------------------
// proj GEMM: tile 64x64, 3-TERM; grid 384. 2D XCD partition: 8(M)x6(N)
// rectangle per XCD -> 2.75MB L2 footprint. (Unchanged from round 10.)
// ---------------------------------------------------------------------------
__global__ __launch_bounds__(256) void k_proj_mfma(
    const ush* __restrict__ ah, const ush* __restrict__ al,
    const ush* __restrict__ bh, const ush* __restrict__ bl,
    const float* __restrict__ bias, float* __restrict__ out)
{
  __shared__ short lds[2 * 16 * 512];    // 32 KB double buffer
  const int orig = blockIdx.x;
  const int xcd = orig & 7, local = orig >> 3;     // 48 blocks per XCD
  const int lm = local & 7, ln = local >> 3;       // 8 x 6 rectangle
  const int bm = (xcd & 3) * 8 + lm;               // 0..31
  const int bn = (xcd >> 2) * 6 + ln;              // 0..11
  const int row0 = bm * 64, col0 = bn * 64;
  ffrag acc[2][2] = {};
  gemm_pipe<2, 2, 3>(ah, al, bh, bl, row0, col0, 768, lds, acc);

  const int tid = threadIdx.x, lane = tid & 63, w = tid >> 6;
  const int wr = w >> 1, wc = w & 1;
  const int l15 = lane & 15, l4 = lane >> 4;
  #pragma unroll
  for (int mi = 0; mi < 2; mi++)
    #pragma unroll
    for (int ni = 0; ni < 2; ni++) {
      int col = col0 + wc * 32 + ni * 16 + l15;
      float bv = bias[col];
      #pragma unroll
      for (int r = 0; r < 4; r++) {
        int row = row0 + wr * 32 + mi * 16 + l4 * 4 + r;
        out[(size_t)row * 768 + col] = acc[mi][ni][r] + bv;
      }
    }
}

// ---------------------------------------------------------------------------
// Kernel: rel-pos bias precompute (q bf16). Unchanged.
// ---------------------------------------------------------------------------
__global__ __launch_bounds__(256) void k_rel(
    const ush* __restrict__ qT, const float* __restrict__ rph,
    const float* __restrict__ rpw,
    float* __restrict__ relh, float* __restrict__ relw)
{
  __shared__ float Qs[32][68];
  __shared__ float RhS[32][68];
  __shared__ float RwS[63][68];
  const int bid = blockIdx.x;
  const int pair = bid >> 5;
  const int nt = bid & 31;
  const int nbase = nt * 32;
  const ush* qp = qT + (size_t)pair * NTOK * HD + (size_t)nbase * HD;
  const int tid = threadIdx.x;
  #pragma unroll
  for (int ii = 0; ii < 2; ii++) {
    int f = ii * 256 + tid;
    int r = f >> 4, k4 = f & 15;
    ushort4 t = *(const ushort4*)(qp + (size_t)r * HD + k4 * 4);
    Qs[r][k4*4+0] = b2f(t.x); Qs[r][k4*4+1] = b2f(t.y);
    Qs[r][k4*4+2] = b2f(t.z); Qs[r][k4*4+3] = b2f(t.w);
    *(fx4*)&RhS[r][k4*4] = *(const fx4*)(rph + (size_t)(nt + r) * 64 + k4 * 4);
  }
  #pragma unroll
  for (int ii = 0; ii < 4; ii++) {
    int f = ii * 256 + tid;
    if (f < 1008) {
      int r = f >> 4, k4 = f & 15;
      *(fx4*)&RwS[r][k4*4] = *(const fx4*)(rpw + (size_t)r * 64 + k4 * 4);
    }
  }
  __syncthreads();
  const int nl = tid >> 3, rem = tid & 7;
  #pragma unroll
  for (int rep = 0; rep < 8; rep++) {
    int kidx = rep * 8 + rem;
    int hw = kidx >> 5;
    int k = kidx & 31;
    const float* rrow = hw ? &RwS[nl + 31 - k][0] : &RhS[31 - k][0];
    float sum = 0.f;
    #pragma unroll
    for (int c4 = 0; c4 < 16; c4++) {
      fx4 q = *(const fx4*)&Qs[nl][c4*4];
      fx4 rv = *(const fx4*)&rrow[c4*4];
      sum = fmaf(q[0], rv[0], sum);
      sum = fmaf(q[1], rv[1], sum);
      sum = fmaf(q[2], rv[2], sum);
      sum = fmaf(q[3], rv[3], sum);
    }
    float* dst = (hw ? relw : relh) + (size_t)pair * NTOK * 32 + (size_t)(nbase + nl) * 32 + k;
    *dst = sum;
  }
}

// ---------------------------------------------------------------------------
// MFMA flash attention, SPLIT-KV. Unchanged from round 10.
// ---------------------------------------------------------------------------
__global__ __launch_bounds__(256, 3) void k_attn_mfma(
    const ush* __restrict__ qT, const ush* __restrict__ kT,
    const ush* __restrict__ vT,
    const float* __restrict__ relh, const float* __restrict__ relw,
    ush* __restrict__ oph, ush* __restrict__ opl, float* __restrict__ ml)
{
  __shared__ short Kf[2 * 8 * 512]; // double-buffered K tiles (8KB each)
  __shared__ char VTb[8192];        // V^T [64 d][64 k] bf16, XOR-swizzled rows
  __shared__ char Phb[8192];        // P hi [64 q][64 k] bf16, swizzled
  __shared__ char Plb[8192];        // P lo
  __shared__ float RhS[64][36];     // relh rows for this q-tile

  const int orig = blockIdx.x;
  const int bid = (orig & 7) * 96 + (orig >> 3);   // 768 = 8*96, bijective
  const int ks   = bid & 1;                        // KV half
  const int qt   = (bid >> 1) & 15;
  const int pair = bid >> 5;
  const int q0 = qt * 64;
  const ush* qp = qT + (size_t)pair * NTOK * HD;
  const ush* kp = kT + (size_t)pair * NTOK * HD;
  const ush* vp = vT + (size_t)pair * NTOK * HD;
  const float* rhp = relh + (size_t)pair * NTOK * 32;
  const float* rwp = relw + (size_t)pair * NTOK * 32;

  const int tid = threadIdx.x;
  const int lane = tid & 63, w = tid >> 6;
  const int l15 = lane & 15, l4 = lane >> 4;
  const int wq = w * 16;
  const int kv = tid & 63, db = tid >> 6;

  auto issueK = [&](int tt) {
    const int gt = ks * 8 + tt;
    const ush* s0 = kp + (size_t)(gt * 64 + wq + l15) * HD + l4 * 8;
    short* dst = Kf + (tt & 1) * 4096 + (w * 2) * 512;
    gload16(s0, dst);
    gload16(s0 + 32, dst + 512);
  };
  auto issueV = [&](int tt, ushort4 (&vr)[4]) {
    const int gt = ks * 8 + tt;
    #pragma unroll
    for (int j = 0; j < 4; j++)
      vr[j] = *(const ushort4*)(vp + (size_t)(gt * 64 + kv) * HD + db * 16 + j * 4);
  };
  auto writeVT = [&](ushort4 (&vr)[4]) {
    #pragma unroll
    for (int j = 0; j < 4; j++) {
      int d0 = db * 16 + j * 4;
      *(ush*)(VTb + swz(d0 + 0, 2 * kv)) = vr[j].x;
      *(ush*)(VTb + swz(d0 + 1, 2 * kv)) = vr[j].y;
      *(ush*)(VTb + swz(d0 + 2, 2 * kv)) = vr[j].z;
      *(ush*)(VTb + swz(d0 + 3, 2 * kv)) = vr[j].w;
    }
  };

  // ---- prologue ----
  {
    int row = tid >> 2, seg = tid & 3;
    const float* src = rhp + (size_t)(q0 + row) * 32 + seg * 8;
    *(fx4*)&RhS[row][seg * 8]     = *(const fx4*)src;
    *(fx4*)&RhS[row][seg * 8 + 4] = *(const fx4*)(src + 4);
  }
  bfrag qf[2];
  qf[0] = *(const bfrag*)(qp + (size_t)(q0 + wq + l15) * HD + l4 * 8);
  qf[1] = *(const bfrag*)(qp + (size_t)(q0 + wq + l15) * HD + 32 + l4 * 8);
  float rw[4][2];
  #pragma unroll
  for (int r = 0; r < 4; r++)
    #pragma unroll
    for (int h = 0; h < 2; h++)
      rw[r][h] = rwp[(size_t)(q0 + wq + l4 * 4 + r) * 32 + h * 16 + l15];

  asm volatile("" ::: "memory");
  ushort4 vrA[4], vrB[4];
  issueK(0); issueV(0, vrA); issueV(1, vrB);

  ffrag o[4] = {};
  float mrow[4] = {-3e38f, -3e38f, -3e38f, -3e38f};
  float lrow[4] = {};

  for (int tt = 0; tt < 8; tt++) {
    const int t = ks * 8 + tt;                 // global tile index (for bias)
    if (tt < 7) vwait<4>(); else vwait<0>();
    barL();   // K(tt) visible; all waves finished iteration tt-1 entirely

    if ((tt & 1) == 0) {
      writeVT(vrA);
      if (tt < 7) issueK(tt + 1);
      if (tt < 6) issueV(tt + 2, vrA);
    } else {
      writeVT(vrB);
      if (tt < 7) issueK(tt + 1);
      if (tt < 6) issueV(tt + 2, vrB);
    }

    // --- QK^T from Kf[tt&1]
    const short* kbuf = Kf + (tt & 1) * 4096;
    ffrag s[4] = {};
    #pragma unroll
    for (int kf = 0; kf < 4; kf++) {
      bfrag kf0 = *(const bfrag*)(kbuf + (kf * 2 + 0) * 512 + lane * 8);
      bfrag kf1 = *(const bfrag*)(kbuf + (kf * 2 + 1) * 512 + lane * 8);
      s[kf] = mfma16(qf[0], kf0, s[kf]);
      s[kf] = mfma16(qf[1], kf1, s[kf]);
    }

    // --- bias + online softmax
    fx2 rh2[4];
    #pragma unroll
    for (int r = 0; r < 4; r++)
      rh2[r] = *(const fx2*)&RhS[wq + l4 * 4 + r][2 * t];
    float pm[4] = {-3e38f, -3e38f, -3e38f, -3e38f};
    #pragma unroll
    for (int kf = 0; kf < 4; kf++)
      #pragma unroll
      for (int r = 0; r < 4; r++) {
        float sc = fmaf(s[kf][r], 0.125f, rh2[r][kf >> 1] + rw[r][kf & 1]);
        s[kf][r] = sc;
        pm[r] = fmaxf(pm[r], sc);
      }
    #pragma unroll
    for (int off = 1; off < 16; off <<= 1)
      #pragma unroll
      for (int r = 0; r < 4; r++)
        pm[r] = fmaxf(pm[r], __shfl_xor(pm[r], off));
    float al[4], ps[4] = {0.f, 0.f, 0.f, 0.f};
    #pragma unroll
    for (int r = 0; r < 4; r++) {
      float mnew = fmaxf(mrow[r], pm[r]);
      al[r] = __expf(mrow[r] - mnew);
      mrow[r] = mnew;
    }
    #pragma unroll
    for (int kf = 0; kf < 4; kf++)
      #pragma unroll
      for (int r = 0; r < 4; r++) {
        float p = __expf(s[kf][r] - mrow[r]);
        s[kf][r] = p;
        ps[r] += p;
      }
    #pragma unroll
    for (int off = 1; off < 16; off <<= 1)
      #pragma unroll
      for (int r = 0; r < 4; r++)
        ps[r] += __shfl_xor(ps[r], off);
    #pragma unroll
    for (int r = 0; r < 4; r++)
      lrow[r] = fmaf(lrow[r], al[r], ps[r]);

    // --- P -> bf16 hi/lo
    #pragma unroll
    for (int kf = 0; kf < 4; kf++)
      #pragma unroll
      for (int r = 0; r < 4; r++) {
        ush hi = f2b(s[kf][r]);
        float lo = s[kf][r] - b2f(hi);
        int a = swz(wq + l4 * 4 + r, kf * 32 + 2 * l15);
        *(ush*)(Phb + a) = hi;
        *(ush*)(Plb + a) = f2b(lo);
      }
    #pragma unroll
    for (int df = 0; df < 4; df++)
      #pragma unroll
      for (int r = 0; r < 4; r++)
        o[df][r] *= al[r];

    barL();   // VT + P writes visible before PV

    // --- PV
    bfrag ph[2], pl[2];
    #pragma unroll
    for (int kc = 0; kc < 2; kc++) {
      int a = swz(wq + l15, kc * 64 + l4 * 16);
      ph[kc] = *(const bfrag*)(Phb + a);
      pl[kc] = *(const bfrag*)(Plb + a);
    }
    #pragma unroll
    for (int df = 0; df < 4; df++)
      #pragma unroll
      for (int kc = 0; kc < 2; kc++) {
        bfrag vf = *(const bfrag*)(VTb + swz(df * 16 + l15, kc * 64 + l4 * 16));
        o[df] = mfma16(ph[kc], vf, o[df]);
        o[df] = mfma16(pl[kc], vf, o[df]);
      }
  }

  // --- epilogue: write UNNORMALIZED partial o + (m,l)
  const int part = ((pair << 4) | qt) * 2 + ks;
  if (l15 == 0) {
    float* mlp = ml + (size_t)part * 128;
    #pragma unroll
    for (int r = 0; r < 4; r++) {
      int row = wq + l4 * 4 + r;
      mlp[row] = mrow[r];
      mlp[64 + row] = lrow[r];
    }
  }
  const size_t pbase = (size_t)part * 4096;
  #pragma unroll
  for (int df = 0; df < 4; df++)
    #pragma unroll
    for (int r = 0; r < 4; r++) {
      float val = o[df][r];
      int row = wq + l4 * 4 + r;
      size_t idx = pbase + (size_t)row * 64 + df * 16 + l15;
      ush hi = f2b(val);
      oph[idx] = hi;
      opl[idx] = f2b(val - b2f(hi));
    }
}

// ---------------------------------------------------------------------------
// Merge the two KV-halves: standard online-softmax combine, write o1 hi/lo.
// ---------------------------------------------------------------------------
__global__ __launch_bounds__(256) void k_attn_merge(
    const ush* __restrict__ oph, const ush* __restrict__ opl,
    const float* __restrict__ ml,
    ush* __restrict__ o1h, ush* __restrict__ o1l)
{
  const int pq = blockIdx.x;              // (pair, qtile)
  const int pair = pq >> 4, qt = pq & 15;
  const int bb = pair / NHEADS, head = pair % NHEADS;
  __shared__ float M0[64], L0[64], M1[64], L1[64];
  const int tid = threadIdx.x;
  const float* mlp = ml + (size_t)pq * 256;
  if (tid < 64) {
    M0[tid] = mlp[tid];        L0[tid] = mlp[64 + tid];
    M1[tid] = mlp[128 + tid];  L1[tid] = mlp[192 + tid];
  }
  __syncthreads();
  const size_t b0 = (size_t)(pq * 2) * 4096;
  const size_t b1 = b0 + 4096;
  #pragma unroll
  for (int e = 0; e < 4; e++) {
    int q4 = e * 256 + tid;               // ushort4 index within 64x64 tile
    int row = q4 >> 4;
    int d4 = (q4 & 15) * 4;
    float m0 = M0[row], l0v = L0[row], m1 = M1[row], l1v = L1[row];
    float m = fmaxf(m0, m1);
    float a0 = __expf(m0 - m), a1 = __expf(m1 - m);
    float inv = 1.0f / (l0v * a0 + l1v * a1);
    ushort4 h0 = *(const ushort4*)(oph + b0 + (size_t)q4 * 4);
    ushort4 g0 = *(const ushort4*)(opl + b0 + (size_t)q4 * 4);
    ushort4 h1 = *(const ushort4*)(oph + b1 + (size_t)q4 * 4);
    ushort4 g1 = *(const ushort4*)(opl + b1 + (size_t)q4 * 4);
    float v0 = ((b2f(h0.x)+b2f(g0.x))*a0 + (b2f(h1.x)+b2f(g1.x))*a1) * inv;
    float v1 = ((b2f(h0.y)+b2f(g0.y))*a0 + (b2f(h1.y)+b2f(g1.y))*a1) * inv;
    float v2 = ((b2f(h0.z)+b2f(g0.z))*a0 + (b2f(h1.z)+b2f(g1.z))*a1) * inv;
    float v3 = ((b2f(h0.w)+b2f(g0.w))*a0 + (b2f(h1.w)+b2f(g1.w))*a1) * inv;
    size_t gidx = ((size_t)(bb * NTOK + qt * 64 + row)) * DIMM + head * HD + d4;
    ushort4 oh, ol;
    oh.x = f2b(v0); ol.x = f2b(v0 - b2f(oh.x));
    oh.y = f2b(v1); ol.y = f2b(v1 - b2f(oh.y));
    oh.z = f2b(v2); ol.z = f2b(v2 - b2f(oh.z));
    oh.w = f2b(v3); ol.w = f2b(v3 - b2f(oh.w));
    *(ushort4*)(o1h + gidx) = oh;
    *(ushort4*)(o1l + gidx) = ol;
  }
}

// ---------------------------------------------------------------------------
extern "C" void kernel_launch(void* const* d_in, const int* in_sizes, int n_in,
                              void* d_out, int out_size, void* d_ws, size_t ws_size,
                              hipStream_t stream)
{
  const float* x      = (const float*)d_in[0];
  const float* qkv_w  = (const float*)d_in[1];
  const float* qkv_b  = (const float*)d_in[2];
  const float* proj_w = (const float*)d_in[3];
  const float* proj_b = (const float*)d_in[4];
  const float* rph    = (const float*)d_in[5];
  const float* rpw    = (const float*)d_in[6];

  char* p = (char*)d_ws;
  ush* xh  = (ush*)p; p += 3145728;   // 2048*768*2   (xh+xl contiguous)
  ush* xl  = (ush*)p; p += 3145728;
  ush* wh  = (ush*)p; p += 3538944;   // 2304*768*2   (wh+wl contiguous)
  ush* wl  = (ush*)p; p += 3538944;   // region reserved (opl overlay), values unused
  ush* pwh = (ush*)p; p += 1179648;   // 768*768*2
  ush* pwl = (ush*)p; p += 1179648;
  ush* qb  = (ush*)p; p += 3145728;   // 24*1024*64*2
  ush* kb  = (ush*)p; p += 3145728;
  ush* vb  = (ush*)p; p += 3145728;
  float* relh = (float*)p; p += 3145728;   // 24*1024*32*4
  float* relw = (float*)p; p += 3145728;
  float* ml   = (float*)p; p += 393216;    // 768*128*4
  (void)wl;
  // Partial O: oph spans xh+xl (3,145,728 ush exact), opl spans wh+wl.
  ush* oph = xh;
  ush* opl = wh;
  // Merge output overlays qb/kb (dead after k_attn_mfma; exact fit).
  ush* o1h = qb;
  ush* o1l = kb;
  float* out = (float*)d_out;

  k_cvt3<<<dim3(3840), dim3(256), 0, stream>>>(x, qkv_w, proj_w,
                                               xh, xl, wh, pwh, pwl);
  k_qkv_mfma<<<dim3(288), dim3(256), 0, stream>>>(xh, xl, wh, qkv_b, qb, kb, vb);
  k_rel<<<dim3(768), dim3(256), 0, stream>>>(qb, rph, rpw, relh, relw);
  k_attn_mfma<<<dim3(768), dim3(256), 0, stream>>>(qb, kb, vb, relh, relw, oph, opl, ml);
  k_attn_merge<<<dim3(384), dim3(256), 0, stream>>>(oph, opl, ml, o1h, o1l);
  k_proj_mfma<<<dim3(384), dim3(256), 0, stream>>>(o1h, o1l, pwh, pwl, proj_b, out);
}